// Round 1
// baseline (2040.131 us; speedup 1.0000x reference)
//
#include <hip/hip_runtime.h>

#define S_LEN 1024
#define B_SZ 8
#define F_IN_D 256
#define E_DIM 512
#define INNER_D 1024
#define NH_D 4
#define DH_D 256
#define NROW (B_SZ * S_LEN)   // 8192

// ---------------------------------------------------------------------------
// Generic NT GEMM: C[M,N] = A[M,K] @ B[N,K]^T (+ bias[n]); M%64==0, N%64==0, K%16==0
// ---------------------------------------------------------------------------
#define BM 64
#define BN 64
#define BK 16
__global__ __launch_bounds__(256) void gemm_nt_kernel(
    const float* __restrict__ A, const float* __restrict__ B,
    const float* __restrict__ bias, float* __restrict__ C,
    int M, int N, int K)
{
  __shared__ __align__(16) float As[BK][BM + 4];
  __shared__ __align__(16) float Bs[BK][BN + 4];
  const int tid = threadIdx.x;
  const int bm = blockIdx.y * BM;
  const int bn = blockIdx.x * BN;
  const int lr = tid >> 2;          // 0..63 row within tile
  const int lk = (tid & 3) << 2;    // 0,4,8,12 k within tile
  const int tx = tid & 15;
  const int ty = tid >> 4;
  float acc[4][4] = {};
  const float* Ap = A + (size_t)(bm + lr) * K + lk;
  const float* Bp = B + (size_t)(bn + lr) * K + lk;
  for (int k0 = 0; k0 < K; k0 += BK) {
    float4 a4 = *(const float4*)(Ap + k0);
    float4 b4 = *(const float4*)(Bp + k0);
    __syncthreads();
    As[lk + 0][lr] = a4.x; As[lk + 1][lr] = a4.y; As[lk + 2][lr] = a4.z; As[lk + 3][lr] = a4.w;
    Bs[lk + 0][lr] = b4.x; Bs[lk + 1][lr] = b4.y; Bs[lk + 2][lr] = b4.z; Bs[lk + 3][lr] = b4.w;
    __syncthreads();
#pragma unroll
    for (int kk = 0; kk < BK; ++kk) {
      float4 av = *(const float4*)(&As[kk][ty << 2]);
      float4 bv = *(const float4*)(&Bs[kk][tx << 2]);
      acc[0][0] += av.x * bv.x; acc[0][1] += av.x * bv.y; acc[0][2] += av.x * bv.z; acc[0][3] += av.x * bv.w;
      acc[1][0] += av.y * bv.x; acc[1][1] += av.y * bv.y; acc[1][2] += av.y * bv.z; acc[1][3] += av.y * bv.w;
      acc[2][0] += av.z * bv.x; acc[2][1] += av.z * bv.y; acc[2][2] += av.z * bv.z; acc[2][3] += av.z * bv.w;
      acc[3][0] += av.w * bv.x; acc[3][1] += av.w * bv.y; acc[3][2] += av.w * bv.z; acc[3][3] += av.w * bv.w;
    }
  }
  float4 bvv = {0.f, 0.f, 0.f, 0.f};
  if (bias) bvv = *(const float4*)(bias + bn + (tx << 2));
#pragma unroll
  for (int i = 0; i < 4; ++i) {
    float4 o;
    o.x = acc[i][0] + bvv.x; o.y = acc[i][1] + bvv.y;
    o.z = acc[i][2] + bvv.z; o.w = acc[i][3] + bvv.w;
    *(float4*)(C + (size_t)(bm + (ty << 2) + i) * N + bn + (tx << 2)) = o;
  }
}

// ---------------------------------------------------------------------------
// Block reduction helper (256 threads = 4 waves)
// ---------------------------------------------------------------------------
__device__ __forceinline__ float block_sum4(float v, float* red, int tid) {
#pragma unroll
  for (int off = 32; off; off >>= 1) v += __shfl_xor(v, off);
  if ((tid & 63) == 0) red[tid >> 6] = v;
  __syncthreads();
  float t = red[0] + red[1] + red[2] + red[3];
  __syncthreads();
  return t;
}

// LN over 512 with weight: out = (x-mean)*rstd*w
__global__ __launch_bounds__(256) void ln_mul_kernel(
    const float* __restrict__ in, const float* __restrict__ w,
    float* __restrict__ out)
{
  __shared__ float red[4];
  const int row = blockIdx.x;
  const int tid = threadIdx.x;
  const float* p = in + (size_t)row * E_DIM;
  float v0 = p[tid], v1 = p[tid + 256];
  float mean = block_sum4(v0 + v1, red, tid) * (1.f / E_DIM);
  float d0 = v0 - mean, d1 = v1 - mean;
  float var = block_sum4(d0 * d0 + d1 * d1, red, tid) * (1.f / E_DIM);
  float rstd = rsqrtf(var + 1e-5f);
  out[(size_t)row * E_DIM + tid] = d0 * rstd * w[tid];
  out[(size_t)row * E_DIM + tid + 256] = d1 * rstd * w[tid + 256];
}

// final: out = LN(res + y) * w
__global__ __launch_bounds__(256) void final_ln_kernel(
    const float* __restrict__ res, const float* __restrict__ y,
    const float* __restrict__ w, float* __restrict__ out)
{
  __shared__ float red[4];
  const int row = blockIdx.x;
  const int tid = threadIdx.x;
  const size_t base = (size_t)row * E_DIM;
  float v0 = res[base + tid] + y[base + tid];
  float v1 = res[base + tid + 256] + y[base + tid + 256];
  float mean = block_sum4(v0 + v1, red, tid) * (1.f / E_DIM);
  float d0 = v0 - mean, d1 = v1 - mean;
  float var = block_sum4(d0 * d0 + d1 * d1, red, tid) * (1.f / E_DIM);
  float rstd = rsqrtf(var + 1e-5f);
  out[base + tid] = d0 * rstd * w[tid];
  out[base + tid + 256] = d1 * rstd * w[tid + 256];
}

// ---------------------------------------------------------------------------
// Depthwise causal conv (KS=4) + SiLU.  x_m = up[..., :INNER]
// ---------------------------------------------------------------------------
__global__ __launch_bounds__(256) void conv_silu_kernel(
    const float* __restrict__ up, const float* __restrict__ cw,
    const float* __restrict__ cb, float* __restrict__ xc)
{
  const int idx = blockIdx.x * 256 + threadIdx.x;   // over NROW*INNER
  const int c = idx & (INNER_D - 1);
  const int row = idx >> 10;
  const int s = row & (S_LEN - 1);
  const float* base = up + (size_t)row * (2 * INNER_D) + c;
  const float w0 = cw[c * 4 + 0], w1 = cw[c * 4 + 1], w2 = cw[c * 4 + 2], w3 = cw[c * 4 + 3];
  float acc = cb[c];
  if (s >= 3) acc += w0 * base[-3 * 2 * INNER_D];
  if (s >= 2) acc += w1 * base[-2 * 2 * INNER_D];
  if (s >= 1) acc += w2 * base[-1 * 2 * INNER_D];
  acc += w3 * base[0];
  float sig = 1.f / (1.f + __expf(-acc));
  xc[idx] = acc * sig;
}

// ---------------------------------------------------------------------------
// Headwise 4x4 block-diagonal transforms: q,k from xc; v from x_m (=up[:,:1024])
// ---------------------------------------------------------------------------
__global__ __launch_bounds__(256) void headwise_kernel(
    const float* __restrict__ xc, const float* __restrict__ up,
    const float* __restrict__ Wq, const float* __restrict__ Wk,
    const float* __restrict__ Wv,
    float* __restrict__ q, float* __restrict__ k, float* __restrict__ v)
{
  const int idx = blockIdx.x * 256 + threadIdx.x;   // over NROW*256
  const int n = idx & 255;
  const int row = idx >> 8;
  float4 xcv = *(const float4*)(xc + (size_t)row * INNER_D + n * 4);
  float4 xmv = *(const float4*)(up + (size_t)row * (2 * INNER_D) + n * 4);
  const float* wq = Wq + n * 16;
  const float* wk = Wk + n * 16;
  const float* wv = Wv + n * 16;
  float4 qo, ko, vo;
  qo.x = wq[0] * xcv.x + wq[1] * xcv.y + wq[2] * xcv.z + wq[3] * xcv.w;
  qo.y = wq[4] * xcv.x + wq[5] * xcv.y + wq[6] * xcv.z + wq[7] * xcv.w;
  qo.z = wq[8] * xcv.x + wq[9] * xcv.y + wq[10] * xcv.z + wq[11] * xcv.w;
  qo.w = wq[12] * xcv.x + wq[13] * xcv.y + wq[14] * xcv.z + wq[15] * xcv.w;
  ko.x = wk[0] * xcv.x + wk[1] * xcv.y + wk[2] * xcv.z + wk[3] * xcv.w;
  ko.y = wk[4] * xcv.x + wk[5] * xcv.y + wk[6] * xcv.z + wk[7] * xcv.w;
  ko.z = wk[8] * xcv.x + wk[9] * xcv.y + wk[10] * xcv.z + wk[11] * xcv.w;
  ko.w = wk[12] * xcv.x + wk[13] * xcv.y + wk[14] * xcv.z + wk[15] * xcv.w;
  vo.x = wv[0] * xmv.x + wv[1] * xmv.y + wv[2] * xmv.z + wv[3] * xmv.w;
  vo.y = wv[4] * xmv.x + wv[5] * xmv.y + wv[6] * xmv.z + wv[7] * xmv.w;
  vo.z = wv[8] * xmv.x + wv[9] * xmv.y + wv[10] * xmv.z + wv[11] * xmv.w;
  vo.w = wv[12] * xmv.x + wv[13] * xmv.y + wv[14] * xmv.z + wv[15] * xmv.w;
  *(float4*)(q + (size_t)row * INNER_D + n * 4) = qo;
  *(float4*)(k + (size_t)row * INNER_D + n * 4) = ko;
  *(float4*)(v + (size_t)row * INNER_D + n * 4) = vo;
}

// ---------------------------------------------------------------------------
// Gates: ig/fg[b,h,s] = [q|k|v](b,s,:) . W[h,:] + bias[h]
// ---------------------------------------------------------------------------
__global__ __launch_bounds__(256) void gates_kernel(
    const float* __restrict__ q, const float* __restrict__ k,
    const float* __restrict__ v,
    const float* __restrict__ Wig, const float* __restrict__ big,
    const float* __restrict__ Wfg, const float* __restrict__ bfg,
    float* __restrict__ ig, float* __restrict__ fg)
{
  __shared__ float red[4][8];
  const int row = blockIdx.x;   // b*S + s
  const int tid = threadIdx.x;
  float4 qv = *(const float4*)(q + (size_t)row * INNER_D + tid * 4);
  float4 kv = *(const float4*)(k + (size_t)row * INNER_D + tid * 4);
  float4 vv = *(const float4*)(v + (size_t)row * INNER_D + tid * 4);
  float vals[8];
#pragma unroll
  for (int h = 0; h < 4; ++h) {
    const float* wi = Wig + h * 3072 + tid * 4;
    const float* wf = Wfg + h * 3072 + tid * 4;
    float4 w1 = *(const float4*)(wi);
    float4 w2 = *(const float4*)(wi + 1024);
    float4 w3 = *(const float4*)(wi + 2048);
    vals[h] = qv.x * w1.x + qv.y * w1.y + qv.z * w1.z + qv.w * w1.w
            + kv.x * w2.x + kv.y * w2.y + kv.z * w2.z + kv.w * w2.w
            + vv.x * w3.x + vv.y * w3.y + vv.z * w3.z + vv.w * w3.w;
    float4 f1 = *(const float4*)(wf);
    float4 f2 = *(const float4*)(wf + 1024);
    float4 f3 = *(const float4*)(wf + 2048);
    vals[4 + h] = qv.x * f1.x + qv.y * f1.y + qv.z * f1.z + qv.w * f1.w
                + kv.x * f2.x + kv.y * f2.y + kv.z * f2.z + kv.w * f2.w
                + vv.x * f3.x + vv.y * f3.y + vv.z * f3.z + vv.w * f3.w;
  }
  const int lane = tid & 63, wid = tid >> 6;
#pragma unroll
  for (int i = 0; i < 8; ++i) {
    float x = vals[i];
#pragma unroll
    for (int off = 32; off; off >>= 1) x += __shfl_xor(x, off);
    vals[i] = x;
  }
  if (lane == 0) {
#pragma unroll
    for (int i = 0; i < 8; ++i) red[wid][i] = vals[i];
  }
  __syncthreads();
  if (tid < 8) {
    float sm = red[0][tid] + red[1][tid] + red[2][tid] + red[3][tid];
    const int h = tid & 3;
    const int b = row >> 10, s = row & (S_LEN - 1);
    const size_t oidx = (size_t)(b * NH_D + h) * S_LEN + s;
    if (tid < 4) ig[oidx] = sm + big[h];
    else         fg[oidx] = sm + bfg[h];
  }
}

// ---------------------------------------------------------------------------
// Per-(b,h) scan: a = cumsum(logsigmoid(fg)); m[t]=ig[t]-a[t+1];
// rmax[s]=max_{t<=s} m[t]; maxd[s]=a[s+1]+rmax[s]
// ---------------------------------------------------------------------------
__device__ __forceinline__ float logsigf(float x) {
  return fminf(x, 0.f) - log1pf(__expf(-fabsf(x)));
}

__global__ __launch_bounds__(256) void scan_kernel(
    const float* __restrict__ ig, const float* __restrict__ fg,
    float* __restrict__ m_, float* __restrict__ rmax_, float* __restrict__ maxd_)
{
  __shared__ float sc[256];
  const int bh = blockIdx.x;
  const int tid = threadIdx.x;
  const size_t base = (size_t)bh * S_LEN + tid * 4;
  float4 f4 = *(const float4*)(fg + base);
  float4 i4 = *(const float4*)(ig + base);
  float l0 = logsigf(f4.x), l1 = logsigf(f4.y), l2 = logsigf(f4.z), l3 = logsigf(f4.w);
  float p0 = l0, p1 = p0 + l1, p2 = p1 + l2, p3 = p2 + l3;
  sc[tid] = p3;
  __syncthreads();
  for (int off = 1; off < 256; off <<= 1) {
    float o = (tid >= off) ? sc[tid - off] : 0.f;
    __syncthreads();
    sc[tid] += o;
    __syncthreads();
  }
  float aoff = (tid == 0) ? 0.f : sc[tid - 1];
  __syncthreads();
  float a0 = aoff + p0, a1 = aoff + p1, a2 = aoff + p2, a3 = aoff + p3;  // a[t+1]
  float m0 = i4.x - a0, m1 = i4.y - a1, m2 = i4.z - a2, m3 = i4.w - a3;
  float x0 = m0, x1 = fmaxf(x0, m1), x2 = fmaxf(x1, m2), x3 = fmaxf(x2, m3);
  sc[tid] = x3;
  __syncthreads();
  for (int off = 1; off < 256; off <<= 1) {
    float o = (tid >= off) ? sc[tid - off] : -1e30f;
    __syncthreads();
    sc[tid] = fmaxf(sc[tid], o);
    __syncthreads();
  }
  float moff = (tid == 0) ? -1e30f : sc[tid - 1];
  float r0 = fmaxf(moff, x0), r1 = fmaxf(moff, x1), r2 = fmaxf(moff, x2), r3 = fmaxf(moff, x3);
  float4 mo = {m0, m1, m2, m3};
  float4 ro = {r0, r1, r2, r3};
  float4 dd = {a0 + r0, a1 + r1, a2 + r2, a3 + r3};
  *(float4*)(m_ + base) = mo;
  *(float4*)(rmax_ + base) = ro;
  *(float4*)(maxd_ + base) = dd;
}

// ---------------------------------------------------------------------------
// Attention: one wave per output row s of head (b,h). 64 lanes x float4 = 256 d.
// Fused epilogue: per-head LN + (hn + skip*xc)*silu(z) -> hstate
// ---------------------------------------------------------------------------
__global__ __launch_bounds__(256) void attn_kernel(
    const float* __restrict__ q, const float* __restrict__ k,
    const float* __restrict__ v,
    const float* __restrict__ m_, const float* __restrict__ rmax_,
    const float* __restrict__ maxd_,
    const float* __restrict__ mhln_w, const float* __restrict__ skip,
    const float* __restrict__ xc, const float* __restrict__ up,
    float* __restrict__ hstate)
{
  const int tid = threadIdx.x;
  const int lane = tid & 63;
  const int wid = tid >> 6;
  const int gw = blockIdx.x * 4 + wid;     // 0..B*NH*S-1
  const int s = gw & (S_LEN - 1);
  const int bh = gw >> 10;                 // b*NH + h
  const int h = bh & 3;
  const int b = bh >> 2;
  const int row = b * S_LEN + s;
  const int coff = h * DH_D + lane * 4;
  float4 qv = *(const float4*)(q + (size_t)row * INNER_D + coff);
  const float rm = rmax_[(size_t)bh * S_LEN + s];
  const float md = maxd_[(size_t)bh * S_LEN + s];
  const float scale = 0.0625f;  // DH^-0.5
  const float* mp = m_ + (size_t)bh * S_LEN;
  const float* kbase = k + (size_t)(b * S_LEN) * INNER_D + coff;
  const float* vbase = v + (size_t)(b * S_LEN) * INNER_D + coff;
  float4 acc = {0.f, 0.f, 0.f, 0.f};
  float rowsum = 0.f;
  for (int t = 0; t <= s; ++t) {
    float4 kv = *(const float4*)(kbase + (size_t)t * INNER_D);
    float d = qv.x * kv.x + qv.y * kv.y + qv.z * kv.z + qv.w * kv.w;
    d += __shfl_xor(d, 1); d += __shfl_xor(d, 2); d += __shfl_xor(d, 4);
    d += __shfl_xor(d, 8); d += __shfl_xor(d, 16); d += __shfl_xor(d, 32);
    float c = d * scale * __expf(mp[t] - rm);
    rowsum += c;
    float4 vv = *(const float4*)(vbase + (size_t)t * INNER_D);
    acc.x += c * vv.x; acc.y += c * vv.y; acc.z += c * vv.z; acc.w += c * vv.w;
  }
  float n = fmaxf(fabsf(rowsum), __expf(-md));
  float inv = 1.f / (n + 1e-6f);
  acc.x *= inv; acc.y *= inv; acc.z *= inv; acc.w *= inv;
  // per-head LN over 256 within the wave
  float ssum = acc.x + acc.y + acc.z + acc.w;
#pragma unroll
  for (int off = 32; off; off >>= 1) ssum += __shfl_xor(ssum, off);
  float mean = ssum * (1.f / DH_D);
  float dx = acc.x - mean, dy = acc.y - mean, dz = acc.z - mean, dw = acc.w - mean;
  float sq = dx * dx + dy * dy + dz * dz + dw * dw;
#pragma unroll
  for (int off = 32; off; off >>= 1) sq += __shfl_xor(sq, off);
  float rstd = rsqrtf(sq * (1.f / DH_D) + 1e-5f);
  float4 wv = *(const float4*)(mhln_w + coff);
  float4 sk = *(const float4*)(skip + coff);
  float4 xcv = *(const float4*)(xc + (size_t)row * INNER_D + coff);
  float4 zv = *(const float4*)(up + (size_t)row * (2 * INNER_D) + INNER_D + coff);
  float4 o;
  float z0 = zv.x / (1.f + __expf(-zv.x));
  float z1 = zv.y / (1.f + __expf(-zv.y));
  float z2 = zv.z / (1.f + __expf(-zv.z));
  float z3 = zv.w / (1.f + __expf(-zv.w));
  o.x = (dx * rstd * wv.x + sk.x * xcv.x) * z0;
  o.y = (dy * rstd * wv.y + sk.y * xcv.y) * z1;
  o.z = (dz * rstd * wv.z + sk.z * xcv.z) * z2;
  o.w = (dw * rstd * wv.w + sk.w * xcv.w) * z3;
  *(float4*)(hstate + (size_t)row * INNER_D + coff) = o;
}

// ---------------------------------------------------------------------------
extern "C" void kernel_launch(void* const* d_in, const int* in_sizes, int n_in,
                              void* d_out, int out_size, void* d_ws, size_t ws_size,
                              hipStream_t stream)
{
  const float* x      = (const float*)d_in[0];
  const float* W_in   = (const float*)d_in[1];
  const float* b_in   = (const float*)d_in[2];
  const float* ln1_w  = (const float*)d_in[3];
  const float* W_up   = (const float*)d_in[4];
  const float* conv_w = (const float*)d_in[5];
  const float* conv_b = (const float*)d_in[6];
  const float* Wq     = (const float*)d_in[7];
  const float* Wk     = (const float*)d_in[8];
  const float* Wv     = (const float*)d_in[9];
  const float* W_ig   = (const float*)d_in[10];
  const float* b_ig   = (const float*)d_in[11];
  const float* W_fg   = (const float*)d_in[12];
  const float* b_fg   = (const float*)d_in[13];
  const float* mhln_w = (const float*)d_in[14];
  const float* skip   = (const float*)d_in[15];
  const float* W_down = (const float*)d_in[16];
  const float* ln_post_w = (const float*)d_in[17];
  float* out = (float*)d_out;

  float* ws = (float*)d_ws;
  size_t o = 0;
  float* xp     = ws + o; o += (size_t)NROW * E_DIM;        // residual, kept to end
  float* hbuf   = ws + o; o += (size_t)NROW * E_DIM;        // h, later gates, later y
  float* up     = ws + o; o += (size_t)NROW * 2 * INNER_D;
  float* xc     = ws + o; o += (size_t)NROW * INNER_D;
  float* qb     = ws + o; o += (size_t)NROW * INNER_D;
  float* kb     = ws + o; o += (size_t)NROW * INNER_D;
  float* vb     = ws + o; o += (size_t)NROW * INNER_D;
  float* hstate = ws + o; o += (size_t)NROW * INNER_D;
  // gates live in hbuf (dead between up-GEMM and down-GEMM)
  const int GSZ = B_SZ * NH_D * S_LEN;  // 32768
  float* igb   = hbuf;
  float* fgb   = hbuf + GSZ;
  float* mb    = hbuf + 2 * GSZ;
  float* rmaxb = hbuf + 3 * GSZ;
  float* maxdb = hbuf + 4 * GSZ;
  float* yb    = hbuf;  // down-proj output overwrites gates (dead by then)

  dim3 blk(256);
  // 1. xp = x @ W_in^T + b_in
  gemm_nt_kernel<<<dim3(E_DIM / BN, NROW / BM), blk, 0, stream>>>(
      x, W_in, b_in, xp, NROW, E_DIM, F_IN_D);
  // 2. h = LN(xp) * ln1_w
  ln_mul_kernel<<<NROW, blk, 0, stream>>>(xp, ln1_w, hbuf);
  // 3. up = h @ W_up^T
  gemm_nt_kernel<<<dim3(2 * INNER_D / BN, NROW / BM), blk, 0, stream>>>(
      hbuf, W_up, nullptr, up, NROW, 2 * INNER_D, E_DIM);
  // 4. xc = silu(causal_conv(x_m))
  conv_silu_kernel<<<(NROW * INNER_D) / 256, blk, 0, stream>>>(up, conv_w, conv_b, xc);
  // 5. q,k from xc; v from x_m
  headwise_kernel<<<(NROW * 256) / 256, blk, 0, stream>>>(xc, up, Wq, Wk, Wv, qb, kb, vb);
  // 6. ig/fg
  gates_kernel<<<NROW, blk, 0, stream>>>(qb, kb, vb, W_ig, b_ig, W_fg, b_fg, igb, fgb);
  // 7. decay scans
  scan_kernel<<<B_SZ * NH_D, blk, 0, stream>>>(igb, fgb, mb, rmaxb, maxdb);
  // 8. attention + fused mhln/skip/silu-gate -> hstate
  attn_kernel<<<(B_SZ * NH_D * S_LEN) / 4, blk, 0, stream>>>(
      qb, kb, vb, mb, rmaxb, maxdb, mhln_w, skip, xc, up, hstate);
  // 9. y = hstate @ W_down^T
  gemm_nt_kernel<<<dim3(E_DIM / BN, NROW / BM), blk, 0, stream>>>(
      hstate, W_down, nullptr, yb, NROW, E_DIM, INNER_D);
  // 10. out = LN(xp + y) * ln_post_w
  final_ln_kernel<<<NROW, blk, 0, stream>>>(xp, yb, ln_post_w, out);
}

// Round 3
// 919.475 us; speedup vs baseline: 2.2188x; 2.2188x over previous
//
#include <hip/hip_runtime.h>

#define S_LEN 1024
#define B_SZ 8
#define F_IN_D 256
#define E_DIM 512
#define INNER_D 1024
#define NH_D 4
#define DH_D 256
#define NROW (B_SZ * S_LEN)   // 8192

typedef _Float16 half8 __attribute__((ext_vector_type(8)));
typedef _Float16 half4_t __attribute__((ext_vector_type(4)));
typedef float v4f __attribute__((ext_vector_type(4)));

// ---------------------------------------------------------------------------
// Generic NT GEMM: C[M,N] = A[M,K] @ B[N,K]^T (+ bias[n]); M%64==0, N%64==0, K%16==0
// ---------------------------------------------------------------------------
#define BM 64
#define BN 64
#define BK 16
__global__ __launch_bounds__(256) void gemm_nt_kernel(
    const float* __restrict__ A, const float* __restrict__ B,
    const float* __restrict__ bias, float* __restrict__ C,
    int M, int N, int K)
{
  __shared__ __align__(16) float As[BK][BM + 4];
  __shared__ __align__(16) float Bs[BK][BN + 4];
  const int tid = threadIdx.x;
  const int bm = blockIdx.y * BM;
  const int bn = blockIdx.x * BN;
  const int lr = tid >> 2;
  const int lk = (tid & 3) << 2;
  const int tx = tid & 15;
  const int ty = tid >> 4;
  float acc[4][4] = {};
  const float* Ap = A + (size_t)(bm + lr) * K + lk;
  const float* Bp = B + (size_t)(bn + lr) * K + lk;
  for (int k0 = 0; k0 < K; k0 += BK) {
    float4 a4 = *(const float4*)(Ap + k0);
    float4 b4 = *(const float4*)(Bp + k0);
    __syncthreads();
    As[lk + 0][lr] = a4.x; As[lk + 1][lr] = a4.y; As[lk + 2][lr] = a4.z; As[lk + 3][lr] = a4.w;
    Bs[lk + 0][lr] = b4.x; Bs[lk + 1][lr] = b4.y; Bs[lk + 2][lr] = b4.z; Bs[lk + 3][lr] = b4.w;
    __syncthreads();
#pragma unroll
    for (int kk = 0; kk < BK; ++kk) {
      float4 av = *(const float4*)(&As[kk][ty << 2]);
      float4 bv = *(const float4*)(&Bs[kk][tx << 2]);
      acc[0][0] += av.x * bv.x; acc[0][1] += av.x * bv.y; acc[0][2] += av.x * bv.z; acc[0][3] += av.x * bv.w;
      acc[1][0] += av.y * bv.x; acc[1][1] += av.y * bv.y; acc[1][2] += av.y * bv.z; acc[1][3] += av.y * bv.w;
      acc[2][0] += av.z * bv.x; acc[2][1] += av.z * bv.y; acc[2][2] += av.z * bv.z; acc[2][3] += av.z * bv.w;
      acc[3][0] += av.w * bv.x; acc[3][1] += av.w * bv.y; acc[3][2] += av.w * bv.z; acc[3][3] += av.w * bv.w;
    }
  }
  float4 bvv = {0.f, 0.f, 0.f, 0.f};
  if (bias) bvv = *(const float4*)(bias + bn + (tx << 2));
#pragma unroll
  for (int i = 0; i < 4; ++i) {
    float4 o;
    o.x = acc[i][0] + bvv.x; o.y = acc[i][1] + bvv.y;
    o.z = acc[i][2] + bvv.z; o.w = acc[i][3] + bvv.w;
    *(float4*)(C + (size_t)(bm + (ty << 2) + i) * N + bn + (tx << 2)) = o;
  }
}

// ---------------------------------------------------------------------------
__device__ __forceinline__ float block_sum4(float v, float* red, int tid) {
#pragma unroll
  for (int off = 32; off; off >>= 1) v += __shfl_xor(v, off);
  if ((tid & 63) == 0) red[tid >> 6] = v;
  __syncthreads();
  float t = red[0] + red[1] + red[2] + red[3];
  __syncthreads();
  return t;
}

__global__ __launch_bounds__(256) void ln_mul_kernel(
    const float* __restrict__ in, const float* __restrict__ w,
    float* __restrict__ out)
{
  __shared__ float red[4];
  const int row = blockIdx.x;
  const int tid = threadIdx.x;
  const float* p = in + (size_t)row * E_DIM;
  float v0 = p[tid], v1 = p[tid + 256];
  float mean = block_sum4(v0 + v1, red, tid) * (1.f / E_DIM);
  float d0 = v0 - mean, d1 = v1 - mean;
  float var = block_sum4(d0 * d0 + d1 * d1, red, tid) * (1.f / E_DIM);
  float rstd = rsqrtf(var + 1e-5f);
  out[(size_t)row * E_DIM + tid] = d0 * rstd * w[tid];
  out[(size_t)row * E_DIM + tid + 256] = d1 * rstd * w[tid + 256];
}

__global__ __launch_bounds__(256) void final_ln_kernel(
    const float* __restrict__ res, const float* __restrict__ y,
    const float* __restrict__ w, float* __restrict__ out)
{
  __shared__ float red[4];
  const int row = blockIdx.x;
  const int tid = threadIdx.x;
  const size_t base = (size_t)row * E_DIM;
  float v0 = res[base + tid] + y[base + tid];
  float v1 = res[base + tid + 256] + y[base + tid + 256];
  float mean = block_sum4(v0 + v1, red, tid) * (1.f / E_DIM);
  float d0 = v0 - mean, d1 = v1 - mean;
  float var = block_sum4(d0 * d0 + d1 * d1, red, tid) * (1.f / E_DIM);
  float rstd = rsqrtf(var + 1e-5f);
  out[base + tid] = d0 * rstd * w[tid];
  out[base + tid + 256] = d1 * rstd * w[tid + 256];
}

// ---------------------------------------------------------------------------
__global__ __launch_bounds__(256) void conv_silu_kernel(
    const float* __restrict__ up, const float* __restrict__ cw,
    const float* __restrict__ cb, float* __restrict__ xc)
{
  const int idx = blockIdx.x * 256 + threadIdx.x;
  const int c = idx & (INNER_D - 1);
  const int row = idx >> 10;
  const int s = row & (S_LEN - 1);
  const float* base = up + (size_t)row * (2 * INNER_D) + c;
  const float w0 = cw[c * 4 + 0], w1 = cw[c * 4 + 1], w2 = cw[c * 4 + 2], w3 = cw[c * 4 + 3];
  float acc = cb[c];
  if (s >= 3) acc += w0 * base[-3 * 2 * INNER_D];
  if (s >= 2) acc += w1 * base[-2 * 2 * INNER_D];
  if (s >= 1) acc += w2 * base[-1 * 2 * INNER_D];
  acc += w3 * base[0];
  float sig = 1.f / (1.f + __expf(-acc));
  xc[idx] = acc * sig;
}

// ---------------------------------------------------------------------------
__global__ __launch_bounds__(256) void headwise_kernel(
    const float* __restrict__ xc, const float* __restrict__ up,
    const float* __restrict__ Wq, const float* __restrict__ Wk,
    const float* __restrict__ Wv,
    float* __restrict__ q, float* __restrict__ k, float* __restrict__ v)
{
  const int idx = blockIdx.x * 256 + threadIdx.x;
  const int n = idx & 255;
  const int row = idx >> 8;
  float4 xcv = *(const float4*)(xc + (size_t)row * INNER_D + n * 4);
  float4 xmv = *(const float4*)(up + (size_t)row * (2 * INNER_D) + n * 4);
  const float* wq = Wq + n * 16;
  const float* wk = Wk + n * 16;
  const float* wv = Wv + n * 16;
  float4 qo, ko, vo;
  qo.x = wq[0] * xcv.x + wq[1] * xcv.y + wq[2] * xcv.z + wq[3] * xcv.w;
  qo.y = wq[4] * xcv.x + wq[5] * xcv.y + wq[6] * xcv.z + wq[7] * xcv.w;
  qo.z = wq[8] * xcv.x + wq[9] * xcv.y + wq[10] * xcv.z + wq[11] * xcv.w;
  qo.w = wq[12] * xcv.x + wq[13] * xcv.y + wq[14] * xcv.z + wq[15] * xcv.w;
  ko.x = wk[0] * xcv.x + wk[1] * xcv.y + wk[2] * xcv.z + wk[3] * xcv.w;
  ko.y = wk[4] * xcv.x + wk[5] * xcv.y + wk[6] * xcv.z + wk[7] * xcv.w;
  ko.z = wk[8] * xcv.x + wk[9] * xcv.y + wk[10] * xcv.z + wk[11] * xcv.w;
  ko.w = wk[12] * xcv.x + wk[13] * xcv.y + wk[14] * xcv.z + wk[15] * xcv.w;
  vo.x = wv[0] * xmv.x + wv[1] * xmv.y + wv[2] * xmv.z + wv[3] * xmv.w;
  vo.y = wv[4] * xmv.x + wv[5] * xmv.y + wv[6] * xmv.z + wv[7] * xmv.w;
  vo.z = wv[8] * xmv.x + wv[9] * xmv.y + wv[10] * xmv.z + wv[11] * xmv.w;
  vo.w = wv[12] * xmv.x + wv[13] * xmv.y + wv[14] * xmv.z + wv[15] * xmv.w;
  *(float4*)(q + (size_t)row * INNER_D + n * 4) = qo;
  *(float4*)(k + (size_t)row * INNER_D + n * 4) = ko;
  *(float4*)(v + (size_t)row * INNER_D + n * 4) = vo;
}

// ---------------------------------------------------------------------------
__global__ __launch_bounds__(256) void gates_kernel(
    const float* __restrict__ q, const float* __restrict__ k,
    const float* __restrict__ v,
    const float* __restrict__ Wig, const float* __restrict__ big,
    const float* __restrict__ Wfg, const float* __restrict__ bfg,
    float* __restrict__ ig, float* __restrict__ fg)
{
  __shared__ float red[4][8];
  const int row = blockIdx.x;
  const int tid = threadIdx.x;
  float4 qv = *(const float4*)(q + (size_t)row * INNER_D + tid * 4);
  float4 kv = *(const float4*)(k + (size_t)row * INNER_D + tid * 4);
  float4 vv = *(const float4*)(v + (size_t)row * INNER_D + tid * 4);
  float vals[8];
#pragma unroll
  for (int h = 0; h < 4; ++h) {
    const float* wi = Wig + h * 3072 + tid * 4;
    const float* wf = Wfg + h * 3072 + tid * 4;
    float4 w1 = *(const float4*)(wi);
    float4 w2 = *(const float4*)(wi + 1024);
    float4 w3 = *(const float4*)(wi + 2048);
    vals[h] = qv.x * w1.x + qv.y * w1.y + qv.z * w1.z + qv.w * w1.w
            + kv.x * w2.x + kv.y * w2.y + kv.z * w2.z + kv.w * w2.w
            + vv.x * w3.x + vv.y * w3.y + vv.z * w3.z + vv.w * w3.w;
    float4 f1 = *(const float4*)(wf);
    float4 f2 = *(const float4*)(wf + 1024);
    float4 f3 = *(const float4*)(wf + 2048);
    vals[4 + h] = qv.x * f1.x + qv.y * f1.y + qv.z * f1.z + qv.w * f1.w
                + kv.x * f2.x + kv.y * f2.y + kv.z * f2.z + kv.w * f2.w
                + vv.x * f3.x + vv.y * f3.y + vv.z * f3.z + vv.w * f3.w;
  }
  const int lane = tid & 63, wid = tid >> 6;
#pragma unroll
  for (int i = 0; i < 8; ++i) {
    float x = vals[i];
#pragma unroll
    for (int off = 32; off; off >>= 1) x += __shfl_xor(x, off);
    vals[i] = x;
  }
  if (lane == 0) {
#pragma unroll
    for (int i = 0; i < 8; ++i) red[wid][i] = vals[i];
  }
  __syncthreads();
  if (tid < 8) {
    float sm = red[0][tid] + red[1][tid] + red[2][tid] + red[3][tid];
    const int h = tid & 3;
    const int b = row >> 10, s = row & (S_LEN - 1);
    const size_t oidx = (size_t)(b * NH_D + h) * S_LEN + s;
    if (tid < 4) ig[oidx] = sm + big[h];
    else         fg[oidx] = sm + bfg[h];
  }
}

// ---------------------------------------------------------------------------
// Scan: m[t]=ig[t]-a[t+1]; rmax[s]=running max m; maxd[s]=a[s+1]+rmax[s];
// em[t] = scale * exp(m[t] - rmax[t|63])   (per-64-tile-max factored exp)
// ---------------------------------------------------------------------------
__device__ __forceinline__ float logsigf(float x) {
  return fminf(x, 0.f) - log1pf(__expf(-fabsf(x)));
}

__global__ __launch_bounds__(256) void scan_kernel(
    const float* __restrict__ ig, const float* __restrict__ fg,
    float* __restrict__ m_, float* __restrict__ rmax_, float* __restrict__ maxd_,
    float* __restrict__ em_)
{
  __shared__ float sc[256];
  const int bh = blockIdx.x;
  const int tid = threadIdx.x;
  const size_t base = (size_t)bh * S_LEN + tid * 4;
  float4 f4 = *(const float4*)(fg + base);
  float4 i4 = *(const float4*)(ig + base);
  float l0 = logsigf(f4.x), l1 = logsigf(f4.y), l2 = logsigf(f4.z), l3 = logsigf(f4.w);
  float p0 = l0, p1 = p0 + l1, p2 = p1 + l2, p3 = p2 + l3;
  sc[tid] = p3;
  __syncthreads();
  for (int off = 1; off < 256; off <<= 1) {
    float o = (tid >= off) ? sc[tid - off] : 0.f;
    __syncthreads();
    sc[tid] += o;
    __syncthreads();
  }
  float aoff = (tid == 0) ? 0.f : sc[tid - 1];
  __syncthreads();
  float a0 = aoff + p0, a1 = aoff + p1, a2 = aoff + p2, a3 = aoff + p3;
  float m0 = i4.x - a0, m1 = i4.y - a1, m2 = i4.z - a2, m3 = i4.w - a3;
  float x0 = m0, x1 = fmaxf(x0, m1), x2 = fmaxf(x1, m2), x3 = fmaxf(x2, m3);
  sc[tid] = x3;
  __syncthreads();
  for (int off = 1; off < 256; off <<= 1) {
    float o = (tid >= off) ? sc[tid - off] : -1e30f;
    __syncthreads();
    sc[tid] = fmaxf(sc[tid], o);
    __syncthreads();
  }
  float moff = (tid == 0) ? -1e30f : sc[tid - 1];
  float tmax = sc[tid | 15];   // rmax at end of this 64-wide t-tile
  float r0 = fmaxf(moff, x0), r1 = fmaxf(moff, x1), r2 = fmaxf(moff, x2), r3 = fmaxf(moff, x3);
  const float scale = 0.0625f;  // DH^-0.5
  float4 mo = {m0, m1, m2, m3};
  float4 ro = {r0, r1, r2, r3};
  float4 dd = {a0 + r0, a1 + r1, a2 + r2, a3 + r3};
  float4 eo = {scale * __expf(m0 - tmax), scale * __expf(m1 - tmax),
               scale * __expf(m2 - tmax), scale * __expf(m3 - tmax)};
  *(float4*)(m_ + base) = mo;
  *(float4*)(rmax_ + base) = ro;
  *(float4*)(maxd_ + base) = dd;
  *(float4*)(em_ + base) = eo;
}

// ---------------------------------------------------------------------------
// Cast k (f32 [row][1024]) -> f16 into the dead x_m half of `up`
// (dest row stride 4096 halves = 8KB). One block per row.
// ---------------------------------------------------------------------------
__global__ __launch_bounds__(256) void kcast_kernel(
    const float* __restrict__ kb, _Float16* __restrict__ kh)
{
  const int row = blockIdx.x;
  const int d4 = threadIdx.x * 4;
  float4 v = *(const float4*)(kb + (size_t)row * INNER_D + d4);
  half4_t o = {(_Float16)v.x, (_Float16)v.y, (_Float16)v.z, (_Float16)v.w};
  *(half4_t*)(kh + (size_t)row * 4096 + d4) = o;
}

// ---------------------------------------------------------------------------
// Transpose v f32 [b][s][d] -> f16 vt [b][d][s]
// ---------------------------------------------------------------------------
__global__ __launch_bounds__(256) void vtrans_kernel(
    const float* __restrict__ vb, _Float16* __restrict__ vt)
{
  __shared__ _Float16 tile[64][65];
  const int b = blockIdx.z, dt = blockIdx.x, st = blockIdx.y;
  const int c = threadIdx.x & 63, rb = threadIdx.x >> 6;
  const int s0 = st * 64, d0 = dt * 64;
#pragma unroll
  for (int i = 0; i < 16; ++i) {
    int r = rb * 16 + i;
    tile[r][c] = (_Float16)vb[((size_t)(b * S_LEN + s0 + r)) * INNER_D + d0 + c];
  }
  __syncthreads();
#pragma unroll
  for (int i = 0; i < 16; ++i) {
    int r = rb * 16 + i;
    vt[((size_t)(b * INNER_D + d0 + r)) * S_LEN + s0 + c] = tile[c][r];
  }
}

// ---------------------------------------------------------------------------
// MFMA attention. One wave per 16 s-rows; wave handles row-set p and 63-p.
// Interior t-tiles use the factored weights em[t]*exp(rtile - rmax_row)
// (both exponents <= 0, safe). The DIAGONAL tile computes weights directly
// as scale*exp(m[t]-rmax_row) with the causal mask (exponent <= 0 for t<=s).
// Fused epilogue: normalize, per-head LN, (hn + skip*xc)*silu(z) -> hstate.
// ---------------------------------------------------------------------------
__global__ __launch_bounds__(256) void attn_mfma_kernel(
    const float* __restrict__ qb, const _Float16* __restrict__ kh,
    const _Float16* __restrict__ vt,
    const float* __restrict__ m_, const float* __restrict__ em,
    const float* __restrict__ rmax_, const float* __restrict__ maxd_,
    const float* __restrict__ mhln_w, const float* __restrict__ skip,
    const float* __restrict__ xc, const float* __restrict__ up,
    float* __restrict__ hstate)
{
  __shared__ _Float16 plds[4][16][72];
  const int tid = threadIdx.x;
  const int lane = tid & 63, wid = tid >> 6;
  const int quad = lane >> 4, l16 = lane & 15;
  const int gw = blockIdx.x * 4 + wid;   // 0..1023
  const int bh = gw >> 5, p = gw & 31;
  const int h = bh & 3, b = bh >> 2;
  _Float16 (*P)[72] = plds[wid];
  const float* rmaxp = rmax_ + (size_t)bh * S_LEN;
  const float* emp = em + (size_t)bh * S_LEN;
  const float* mp = m_ + (size_t)bh * S_LEN;
  const float* maxdp = maxd_ + (size_t)bh * S_LEN;
  const float scale = 0.0625f;  // DH^-0.5

  for (int pass = 0; pass < 2; ++pass) {
    const int ss = pass ? (63 - p) : p;
    const int s0 = ss * 16;
    // ---- Q fragments (A-layout: m = l16, k = c*32 + quad*8 + j) ----
    half8 qf[8];
    const float* qrow = qb + ((size_t)(b * S_LEN + s0 + l16)) * INNER_D + h * DH_D + quad * 8;
#pragma unroll
    for (int c = 0; c < 8; ++c) {
      float4 q0 = *(const float4*)(qrow + c * 32);
      float4 q1 = *(const float4*)(qrow + c * 32 + 4);
      half8 qq = {(_Float16)q0.x, (_Float16)q0.y, (_Float16)q0.z, (_Float16)q0.w,
                  (_Float16)q1.x, (_Float16)q1.y, (_Float16)q1.z, (_Float16)q1.w};
      qf[c] = qq;
    }
    v4f acc[16];
#pragma unroll
    for (int nc = 0; nc < 16; ++nc) acc[nc] = (v4f){0.f, 0.f, 0.f, 0.f};
    float rsum[4] = {0.f, 0.f, 0.f, 0.f};
    float rmax_row[4];
#pragma unroll
    for (int r = 0; r < 4; ++r) rmax_row[r] = rmaxp[s0 + quad * 4 + r];

    const int ntile = (ss >> 2) + 1;
    for (int tt = 0; tt < ntile; ++tt) {
      const int t0 = tt * 64;
      const bool diag = (tt == ntile - 1);   // diagonal ALWAYS in last tile
      float rowfac[4];
      if (!diag) {
        const float rtile = rmaxp[t0 + 63];
#pragma unroll
        for (int r = 0; r < 4; ++r) rowfac[r] = __expf(rtile - rmax_row[r]);  // <= 1
      }
      // ---- QK^T: S_sub[16 x 64] ----
#pragma unroll
      for (int sub = 0; sub < 4; ++sub) {
        v4f sacc = (v4f){0.f, 0.f, 0.f, 0.f};
        const _Float16* krow = kh + ((size_t)(b * S_LEN + t0 + sub * 16 + l16)) * 4096
                                  + h * DH_D + quad * 8;
#pragma unroll
        for (int c = 0; c < 8; ++c) {
          half8 kf = *(const half8*)(krow + c * 32);
          sacc = __builtin_amdgcn_mfma_f32_16x16x32_f16(qf[c], kf, sacc, 0, 0, 0);
        }
        const int t = t0 + sub * 16 + l16;
        if (diag) {
          const float mt = mp[t];
#pragma unroll
          for (int r = 0; r < 4; ++r) {
            const int srow = s0 + quad * 4 + r;
            float cc = (t <= srow) ? sacc[r] * scale * __expf(mt - rmax_row[r]) : 0.f;
            rsum[r] += cc;
            P[quad * 4 + r][sub * 16 + l16] = (_Float16)cc;
          }
        } else {
          const float emv = emp[t];
#pragma unroll
          for (int r = 0; r < 4; ++r) {
            float cc = sacc[r] * emv * rowfac[r];
            rsum[r] += cc;
            P[quad * 4 + r][sub * 16 + l16] = (_Float16)cc;
          }
        }
      }
      asm volatile("s_waitcnt lgkmcnt(0)" ::: "memory");
      // ---- PV: acc[16 x 256] += P[16 x 64] @ V[64 x 256] ----
      half8 pf0 = *(const half8*)(&P[l16][quad * 8]);
      half8 pf1 = *(const half8*)(&P[l16][32 + quad * 8]);
      const _Float16* vrow = vt + ((size_t)(b * INNER_D + h * DH_D + l16)) * S_LEN + t0 + quad * 8;
#pragma unroll
      for (int nc = 0; nc < 16; ++nc) {
        half8 vf0 = *(const half8*)(vrow + (size_t)nc * 16 * S_LEN);
        half8 vf1 = *(const half8*)(vrow + (size_t)nc * 16 * S_LEN + 32);
        acc[nc] = __builtin_amdgcn_mfma_f32_16x16x32_f16(pf0, vf0, acc[nc], 0, 0, 0);
        acc[nc] = __builtin_amdgcn_mfma_f32_16x16x32_f16(pf1, vf1, acc[nc], 0, 0, 0);
      }
      asm volatile("s_waitcnt lgkmcnt(0)" ::: "memory");
    }
    // ---- epilogue: normalize, LN, gate, store ----
    float inv[4];
#pragma unroll
    for (int r = 0; r < 4; ++r) {
      float rs = rsum[r];
      rs += __shfl_xor(rs, 1); rs += __shfl_xor(rs, 2);
      rs += __shfl_xor(rs, 4); rs += __shfl_xor(rs, 8);
      float md = maxdp[s0 + quad * 4 + r];
      float n = fmaxf(fabsf(rs), __expf(-md));
      inv[r] = 1.f / (n + 1e-6f);
    }
#pragma unroll
    for (int nc = 0; nc < 16; ++nc) {
#pragma unroll
      for (int r = 0; r < 4; ++r) acc[nc][r] *= inv[r];
    }
    float mean[4], rstd[4];
#pragma unroll
    for (int r = 0; r < 4; ++r) {
      float sm = 0.f;
#pragma unroll
      for (int nc = 0; nc < 16; ++nc) sm += acc[nc][r];
      sm += __shfl_xor(sm, 1); sm += __shfl_xor(sm, 2);
      sm += __shfl_xor(sm, 4); sm += __shfl_xor(sm, 8);
      mean[r] = sm * (1.f / DH_D);
    }
#pragma unroll
    for (int r = 0; r < 4; ++r) {
      float sq = 0.f;
#pragma unroll
      for (int nc = 0; nc < 16; ++nc) { float d = acc[nc][r] - mean[r]; sq += d * d; }
      sq += __shfl_xor(sq, 1); sq += __shfl_xor(sq, 2);
      sq += __shfl_xor(sq, 4); sq += __shfl_xor(sq, 8);
      rstd[r] = rsqrtf(sq * (1.f / DH_D) + 1e-5f);
    }
#pragma unroll
    for (int nc = 0; nc < 16; ++nc) {
      const int d = h * DH_D + nc * 16 + l16;
      const float w = mhln_w[d];
      const float sk = skip[d];
#pragma unroll
      for (int r = 0; r < 4; ++r) {
        const size_t row = (size_t)(b * S_LEN + s0 + quad * 4 + r);
        float xcv = xc[row * INNER_D + d];
        float zv = up[row * 2 * INNER_D + INNER_D + d];
        float sz = zv / (1.f + __expf(-zv));
        float o = ((acc[nc][r] - mean[r]) * rstd[r] * w + sk * xcv) * sz;
        hstate[row * INNER_D + d] = o;
      }
    }
  }
}

// ---------------------------------------------------------------------------
extern "C" void kernel_launch(void* const* d_in, const int* in_sizes, int n_in,
                              void* d_out, int out_size, void* d_ws, size_t ws_size,
                              hipStream_t stream)
{
  const float* x      = (const float*)d_in[0];
  const float* W_in   = (const float*)d_in[1];
  const float* b_in   = (const float*)d_in[2];
  const float* ln1_w  = (const float*)d_in[3];
  const float* W_up   = (const float*)d_in[4];
  const float* conv_w = (const float*)d_in[5];
  const float* conv_b = (const float*)d_in[6];
  const float* Wq     = (const float*)d_in[7];
  const float* Wk     = (const float*)d_in[8];
  const float* Wv     = (const float*)d_in[9];
  const float* W_ig   = (const float*)d_in[10];
  const float* b_ig   = (const float*)d_in[11];
  const float* W_fg   = (const float*)d_in[12];
  const float* b_fg   = (const float*)d_in[13];
  const float* mhln_w = (const float*)d_in[14];
  const float* skip   = (const float*)d_in[15];
  const float* W_down = (const float*)d_in[16];
  const float* ln_post_w = (const float*)d_in[17];
  float* out = (float*)d_out;

  float* ws = (float*)d_ws;
  size_t o = 0;
  float* xp     = ws + o; o += (size_t)NROW * E_DIM;
  float* hbuf   = ws + o; o += (size_t)NROW * E_DIM;
  float* up     = ws + o; o += (size_t)NROW * 2 * INNER_D;
  float* xc     = ws + o; o += (size_t)NROW * INNER_D;
  float* qb     = ws + o; o += (size_t)NROW * INNER_D;
  float* kb     = ws + o; o += (size_t)NROW * INNER_D;
  float* vb     = ws + o; o += (size_t)NROW * INNER_D;
  float* hstate = ws + o; o += (size_t)NROW * INNER_D;
  const int GSZ = B_SZ * NH_D * S_LEN;  // 32768
  float* igb   = hbuf;
  float* fgb   = hbuf + GSZ;
  float* mb    = hbuf + 2 * GSZ;
  float* rmaxb = hbuf + 3 * GSZ;
  float* maxdb = hbuf + 4 * GSZ;
  float* emb   = hbuf + 5 * GSZ;
  float* yb    = hbuf;                         // down-proj output (gates dead by then)
  _Float16* kh16 = (_Float16*)up;              // strided into dead x_m half of up
  _Float16* vt16 = (_Float16*)kb;              // kb f32 dead after kcast

  dim3 blk(256);
  gemm_nt_kernel<<<dim3(E_DIM / BN, NROW / BM), blk, 0, stream>>>(
      x, W_in, b_in, xp, NROW, E_DIM, F_IN_D);
  ln_mul_kernel<<<NROW, blk, 0, stream>>>(xp, ln1_w, hbuf);
  gemm_nt_kernel<<<dim3(2 * INNER_D / BN, NROW / BM), blk, 0, stream>>>(
      hbuf, W_up, nullptr, up, NROW, 2 * INNER_D, E_DIM);
  conv_silu_kernel<<<(NROW * INNER_D) / 256, blk, 0, stream>>>(up, conv_w, conv_b, xc);
  headwise_kernel<<<(NROW * 256) / 256, blk, 0, stream>>>(xc, up, Wq, Wk, Wv, qb, kb, vb);
  gates_kernel<<<NROW, blk, 0, stream>>>(qb, kb, vb, W_ig, b_ig, W_fg, b_fg, igb, fgb);
  scan_kernel<<<B_SZ * NH_D, blk, 0, stream>>>(igb, fgb, mb, rmaxb, maxdb, emb);
  kcast_kernel<<<NROW, blk, 0, stream>>>(kb, kh16);
  vtrans_kernel<<<dim3(16, 16, 8), blk, 0, stream>>>(vb, vt16);
  attn_mfma_kernel<<<256, blk, 0, stream>>>(
      qb, kh16, vt16, mb, emb, rmaxb, maxdb, mhln_w, skip, xc, up, hstate);
  gemm_nt_kernel<<<dim3(E_DIM / BN, NROW / BM), blk, 0, stream>>>(
      hstate, W_down, nullptr, yb, NROW, E_DIM, INNER_D);
  final_ln_kernel<<<NROW, blk, 0, stream>>>(xp, yb, ln_post_w, out);
}

// Round 4
// 594.066 us; speedup vs baseline: 3.4342x; 1.5478x over previous
//
#include <hip/hip_runtime.h>

#define S_LEN 1024
#define B_SZ 8
#define F_IN_D 256
#define E_DIM 512
#define INNER_D 1024
#define NH_D 4
#define DH_D 256
#define NROW (B_SZ * S_LEN)   // 8192

typedef _Float16 half8 __attribute__((ext_vector_type(8)));
typedef _Float16 half4_t __attribute__((ext_vector_type(4)));
typedef float v4f __attribute__((ext_vector_type(4)));

// ---------------------------------------------------------------------------
// MFMA NT GEMM: C[M,N] = A[M,K] @ B[N,K]^T (+ bias[n])
// f32 inputs staged to f16 LDS, fp32 accumulate. 128x128 tile, BK=32.
// 256 threads = 4 waves in 2x2; each wave computes 64x64 via 4x4 mfma grid.
// M%128==0, N%128==0, K%32==0.
// ---------------------------------------------------------------------------
#define GBM 128
#define GBN 128
#define GBK 32
#define LDK (GBK + 8)   // 40 halves = 80 B row stride (16B-multiple)

__global__ __launch_bounds__(256) void gemm_nt_mfma(
    const float* __restrict__ A, const float* __restrict__ B,
    const float* __restrict__ bias, float* __restrict__ C,
    int M, int N, int K)
{
  __shared__ __align__(16) _Float16 As[GBM][LDK];
  __shared__ __align__(16) _Float16 Bs[GBN][LDK];
  const int tid = threadIdx.x;
  const int lane = tid & 63, w = tid >> 6;
  const int wr = w >> 1, wc = w & 1;
  const int quad = lane >> 4, l16 = lane & 15;
  const int bm = blockIdx.y * GBM, bn = blockIdx.x * GBN;
  const int srow = tid >> 3;        // 0..31
  const int scol = (tid & 7) * 4;   // 0..28 step 4

  v4f acc[4][4];
#pragma unroll
  for (int i = 0; i < 4; ++i)
#pragma unroll
    for (int j = 0; j < 4; ++j) acc[i][j] = (v4f){0.f, 0.f, 0.f, 0.f};

  float4 ar[4], br[4];
#pragma unroll
  for (int i = 0; i < 4; ++i) {
    ar[i] = *(const float4*)(A + (size_t)(bm + srow + i * 32) * K + scol);
    br[i] = *(const float4*)(B + (size_t)(bn + srow + i * 32) * K + scol);
  }

  for (int k0 = 0; k0 < K; k0 += GBK) {
    __syncthreads();
#pragma unroll
    for (int i = 0; i < 4; ++i) {
      half4_t av = {(_Float16)ar[i].x, (_Float16)ar[i].y, (_Float16)ar[i].z, (_Float16)ar[i].w};
      half4_t bv = {(_Float16)br[i].x, (_Float16)br[i].y, (_Float16)br[i].z, (_Float16)br[i].w};
      *(half4_t*)(&As[srow + i * 32][scol]) = av;
      *(half4_t*)(&Bs[srow + i * 32][scol]) = bv;
    }
    __syncthreads();
    if (k0 + GBK < K) {
      const int kn = k0 + GBK;
#pragma unroll
      for (int i = 0; i < 4; ++i) {
        ar[i] = *(const float4*)(A + (size_t)(bm + srow + i * 32) * K + kn + scol);
        br[i] = *(const float4*)(B + (size_t)(bn + srow + i * 32) * K + kn + scol);
      }
    }
    half8 af[4], bf[4];
#pragma unroll
    for (int i = 0; i < 4; ++i)
      af[i] = *(const half8*)(&As[wr * 64 + i * 16 + l16][quad * 8]);
#pragma unroll
    for (int j = 0; j < 4; ++j)
      bf[j] = *(const half8*)(&Bs[wc * 64 + j * 16 + l16][quad * 8]);
#pragma unroll
    for (int i = 0; i < 4; ++i)
#pragma unroll
      for (int j = 0; j < 4; ++j)
        acc[i][j] = __builtin_amdgcn_mfma_f32_16x16x32_f16(af[i], bf[j], acc[i][j], 0, 0, 0);
  }

#pragma unroll
  for (int j = 0; j < 4; ++j) {
    const int col = bn + wc * 64 + j * 16 + l16;
    const float bv = bias ? bias[col] : 0.f;
#pragma unroll
    for (int i = 0; i < 4; ++i) {
      const int row0 = bm + wr * 64 + i * 16 + quad * 4;
#pragma unroll
      for (int r = 0; r < 4; ++r)
        C[(size_t)(row0 + r) * N + col] = acc[i][j][r] + bv;
    }
  }
}

// ---------------------------------------------------------------------------
__device__ __forceinline__ float block_sum4(float v, float* red, int tid) {
#pragma unroll
  for (int off = 32; off; off >>= 1) v += __shfl_xor(v, off);
  if ((tid & 63) == 0) red[tid >> 6] = v;
  __syncthreads();
  float t = red[0] + red[1] + red[2] + red[3];
  __syncthreads();
  return t;
}

__global__ __launch_bounds__(256) void ln_mul_kernel(
    const float* __restrict__ in, const float* __restrict__ w,
    float* __restrict__ out)
{
  __shared__ float red[4];
  const int row = blockIdx.x;
  const int tid = threadIdx.x;
  const float* p = in + (size_t)row * E_DIM;
  float v0 = p[tid], v1 = p[tid + 256];
  float mean = block_sum4(v0 + v1, red, tid) * (1.f / E_DIM);
  float d0 = v0 - mean, d1 = v1 - mean;
  float var = block_sum4(d0 * d0 + d1 * d1, red, tid) * (1.f / E_DIM);
  float rstd = rsqrtf(var + 1e-5f);
  out[(size_t)row * E_DIM + tid] = d0 * rstd * w[tid];
  out[(size_t)row * E_DIM + tid + 256] = d1 * rstd * w[tid + 256];
}

__global__ __launch_bounds__(256) void final_ln_kernel(
    const float* __restrict__ res, const float* __restrict__ y,
    const float* __restrict__ w, float* __restrict__ out)
{
  __shared__ float red[4];
  const int row = blockIdx.x;
  const int tid = threadIdx.x;
  const size_t base = (size_t)row * E_DIM;
  float v0 = res[base + tid] + y[base + tid];
  float v1 = res[base + tid + 256] + y[base + tid + 256];
  float mean = block_sum4(v0 + v1, red, tid) * (1.f / E_DIM);
  float d0 = v0 - mean, d1 = v1 - mean;
  float var = block_sum4(d0 * d0 + d1 * d1, red, tid) * (1.f / E_DIM);
  float rstd = rsqrtf(var + 1e-5f);
  out[base + tid] = d0 * rstd * w[tid];
  out[base + tid + 256] = d1 * rstd * w[tid + 256];
}

// ---------------------------------------------------------------------------
__global__ __launch_bounds__(256) void conv_silu_kernel(
    const float* __restrict__ up, const float* __restrict__ cw,
    const float* __restrict__ cb, float* __restrict__ xc)
{
  const int idx = blockIdx.x * 256 + threadIdx.x;
  const int c = idx & (INNER_D - 1);
  const int row = idx >> 10;
  const int s = row & (S_LEN - 1);
  const float* base = up + (size_t)row * (2 * INNER_D) + c;
  const float w0 = cw[c * 4 + 0], w1 = cw[c * 4 + 1], w2 = cw[c * 4 + 2], w3 = cw[c * 4 + 3];
  float acc = cb[c];
  if (s >= 3) acc += w0 * base[-3 * 2 * INNER_D];
  if (s >= 2) acc += w1 * base[-2 * 2 * INNER_D];
  if (s >= 1) acc += w2 * base[-1 * 2 * INNER_D];
  acc += w3 * base[0];
  float sig = 1.f / (1.f + __expf(-acc));
  xc[idx] = acc * sig;
}

// ---------------------------------------------------------------------------
__global__ __launch_bounds__(256) void headwise_kernel(
    const float* __restrict__ xc, const float* __restrict__ up,
    const float* __restrict__ Wq, const float* __restrict__ Wk,
    const float* __restrict__ Wv,
    float* __restrict__ q, float* __restrict__ k, float* __restrict__ v)
{
  const int idx = blockIdx.x * 256 + threadIdx.x;
  const int n = idx & 255;
  const int row = idx >> 8;
  float4 xcv = *(const float4*)(xc + (size_t)row * INNER_D + n * 4);
  float4 xmv = *(const float4*)(up + (size_t)row * (2 * INNER_D) + n * 4);
  const float* wq = Wq + n * 16;
  const float* wk = Wk + n * 16;
  const float* wv = Wv + n * 16;
  float4 qo, ko, vo;
  qo.x = wq[0] * xcv.x + wq[1] * xcv.y + wq[2] * xcv.z + wq[3] * xcv.w;
  qo.y = wq[4] * xcv.x + wq[5] * xcv.y + wq[6] * xcv.z + wq[7] * xcv.w;
  qo.z = wq[8] * xcv.x + wq[9] * xcv.y + wq[10] * xcv.z + wq[11] * xcv.w;
  qo.w = wq[12] * xcv.x + wq[13] * xcv.y + wq[14] * xcv.z + wq[15] * xcv.w;
  ko.x = wk[0] * xcv.x + wk[1] * xcv.y + wk[2] * xcv.z + wk[3] * xcv.w;
  ko.y = wk[4] * xcv.x + wk[5] * xcv.y + wk[6] * xcv.z + wk[7] * xcv.w;
  ko.z = wk[8] * xcv.x + wk[9] * xcv.y + wk[10] * xcv.z + wk[11] * xcv.w;
  ko.w = wk[12] * xcv.x + wk[13] * xcv.y + wk[14] * xcv.z + wk[15] * xcv.w;
  vo.x = wv[0] * xmv.x + wv[1] * xmv.y + wv[2] * xmv.z + wv[3] * xmv.w;
  vo.y = wv[4] * xmv.x + wv[5] * xmv.y + wv[6] * xmv.z + wv[7] * xmv.w;
  vo.z = wv[8] * xmv.x + wv[9] * xmv.y + wv[10] * xmv.z + wv[11] * xmv.w;
  vo.w = wv[12] * xmv.x + wv[13] * xmv.y + wv[14] * xmv.z + wv[15] * xmv.w;
  *(float4*)(q + (size_t)row * INNER_D + n * 4) = qo;
  *(float4*)(k + (size_t)row * INNER_D + n * 4) = ko;
  *(float4*)(v + (size_t)row * INNER_D + n * 4) = vo;
}

// ---------------------------------------------------------------------------
__global__ __launch_bounds__(256) void gates_kernel(
    const float* __restrict__ q, const float* __restrict__ k,
    const float* __restrict__ v,
    const float* __restrict__ Wig, const float* __restrict__ big,
    const float* __restrict__ Wfg, const float* __restrict__ bfg,
    float* __restrict__ ig, float* __restrict__ fg)
{
  __shared__ float red[4][8];
  const int row = blockIdx.x;
  const int tid = threadIdx.x;
  float4 qv = *(const float4*)(q + (size_t)row * INNER_D + tid * 4);
  float4 kv = *(const float4*)(k + (size_t)row * INNER_D + tid * 4);
  float4 vv = *(const float4*)(v + (size_t)row * INNER_D + tid * 4);
  float vals[8];
#pragma unroll
  for (int h = 0; h < 4; ++h) {
    const float* wi = Wig + h * 3072 + tid * 4;
    const float* wf = Wfg + h * 3072 + tid * 4;
    float4 w1 = *(const float4*)(wi);
    float4 w2 = *(const float4*)(wi + 1024);
    float4 w3 = *(const float4*)(wi + 2048);
    vals[h] = qv.x * w1.x + qv.y * w1.y + qv.z * w1.z + qv.w * w1.w
            + kv.x * w2.x + kv.y * w2.y + kv.z * w2.z + kv.w * w2.w
            + vv.x * w3.x + vv.y * w3.y + vv.z * w3.z + vv.w * w3.w;
    float4 f1 = *(const float4*)(wf);
    float4 f2 = *(const float4*)(wf + 1024);
    float4 f3 = *(const float4*)(wf + 2048);
    vals[4 + h] = qv.x * f1.x + qv.y * f1.y + qv.z * f1.z + qv.w * f1.w
                + kv.x * f2.x + kv.y * f2.y + kv.z * f2.z + kv.w * f2.w
                + vv.x * f3.x + vv.y * f3.y + vv.z * f3.z + vv.w * f3.w;
  }
  const int lane = tid & 63, wid = tid >> 6;
#pragma unroll
  for (int i = 0; i < 8; ++i) {
    float x = vals[i];
#pragma unroll
    for (int off = 32; off; off >>= 1) x += __shfl_xor(x, off);
    vals[i] = x;
  }
  if (lane == 0) {
#pragma unroll
    for (int i = 0; i < 8; ++i) red[wid][i] = vals[i];
  }
  __syncthreads();
  if (tid < 8) {
    float sm = red[0][tid] + red[1][tid] + red[2][tid] + red[3][tid];
    const int h = tid & 3;
    const int b = row >> 10, s = row & (S_LEN - 1);
    const size_t oidx = (size_t)(b * NH_D + h) * S_LEN + s;
    if (tid < 4) ig[oidx] = sm + big[h];
    else         fg[oidx] = sm + bfg[h];
  }
}

// ---------------------------------------------------------------------------
// Scan: m[t]=ig[t]-a[t+1]; rmax[s]=running max m; maxd[s]=a[s+1]+rmax[s];
// em[t] = scale * exp(m[t] - rmax[t|63])   (per-64-tile-max factored exp)
// ---------------------------------------------------------------------------
__device__ __forceinline__ float logsigf(float x) {
  return fminf(x, 0.f) - log1pf(__expf(-fabsf(x)));
}

__global__ __launch_bounds__(256) void scan_kernel(
    const float* __restrict__ ig, const float* __restrict__ fg,
    float* __restrict__ m_, float* __restrict__ rmax_, float* __restrict__ maxd_,
    float* __restrict__ em_)
{
  __shared__ float sc[256];
  const int bh = blockIdx.x;
  const int tid = threadIdx.x;
  const size_t base = (size_t)bh * S_LEN + tid * 4;
  float4 f4 = *(const float4*)(fg + base);
  float4 i4 = *(const float4*)(ig + base);
  float l0 = logsigf(f4.x), l1 = logsigf(f4.y), l2 = logsigf(f4.z), l3 = logsigf(f4.w);
  float p0 = l0, p1 = p0 + l1, p2 = p1 + l2, p3 = p2 + l3;
  sc[tid] = p3;
  __syncthreads();
  for (int off = 1; off < 256; off <<= 1) {
    float o = (tid >= off) ? sc[tid - off] : 0.f;
    __syncthreads();
    sc[tid] += o;
    __syncthreads();
  }
  float aoff = (tid == 0) ? 0.f : sc[tid - 1];
  __syncthreads();
  float a0 = aoff + p0, a1 = aoff + p1, a2 = aoff + p2, a3 = aoff + p3;
  float m0 = i4.x - a0, m1 = i4.y - a1, m2 = i4.z - a2, m3 = i4.w - a3;
  float x0 = m0, x1 = fmaxf(x0, m1), x2 = fmaxf(x1, m2), x3 = fmaxf(x2, m3);
  sc[tid] = x3;
  __syncthreads();
  for (int off = 1; off < 256; off <<= 1) {
    float o = (tid >= off) ? sc[tid - off] : -1e30f;
    __syncthreads();
    sc[tid] = fmaxf(sc[tid], o);
    __syncthreads();
  }
  float moff = (tid == 0) ? -1e30f : sc[tid - 1];
  float tmax = sc[tid | 15];   // rmax at end of this 64-wide t-tile
  float r0 = fmaxf(moff, x0), r1 = fmaxf(moff, x1), r2 = fmaxf(moff, x2), r3 = fmaxf(moff, x3);
  const float scale = 0.0625f;  // DH^-0.5
  float4 mo = {m0, m1, m2, m3};
  float4 ro = {r0, r1, r2, r3};
  float4 dd = {a0 + r0, a1 + r1, a2 + r2, a3 + r3};
  float4 eo = {scale * __expf(m0 - tmax), scale * __expf(m1 - tmax),
               scale * __expf(m2 - tmax), scale * __expf(m3 - tmax)};
  *(float4*)(m_ + base) = mo;
  *(float4*)(rmax_ + base) = ro;
  *(float4*)(maxd_ + base) = dd;
  *(float4*)(em_ + base) = eo;
}

// ---------------------------------------------------------------------------
__global__ __launch_bounds__(256) void kcast_kernel(
    const float* __restrict__ kb, _Float16* __restrict__ kh)
{
  const int row = blockIdx.x;
  const int d4 = threadIdx.x * 4;
  float4 v = *(const float4*)(kb + (size_t)row * INNER_D + d4);
  half4_t o = {(_Float16)v.x, (_Float16)v.y, (_Float16)v.z, (_Float16)v.w};
  *(half4_t*)(kh + (size_t)row * 4096 + d4) = o;
}

// ---------------------------------------------------------------------------
__global__ __launch_bounds__(256) void vtrans_kernel(
    const float* __restrict__ vb, _Float16* __restrict__ vt)
{
  __shared__ _Float16 tile[64][65];
  const int b = blockIdx.z, dt = blockIdx.x, st = blockIdx.y;
  const int c = threadIdx.x & 63, rb = threadIdx.x >> 6;
  const int s0 = st * 64, d0 = dt * 64;
#pragma unroll
  for (int i = 0; i < 16; ++i) {
    int r = rb * 16 + i;
    tile[r][c] = (_Float16)vb[((size_t)(b * S_LEN + s0 + r)) * INNER_D + d0 + c];
  }
  __syncthreads();
#pragma unroll
  for (int i = 0; i < 16; ++i) {
    int r = rb * 16 + i;
    vt[((size_t)(b * INNER_D + d0 + r)) * S_LEN + s0 + c] = tile[c][r];
  }
}

// ---------------------------------------------------------------------------
// MFMA attention. One wave per 16-row s-block (2048 waves / 512 blocks for
// occupancy). Interior t-tiles use factored weights em[t]*exp(rtile-rmax_row)
// (both exponents <= 0). Diagonal tile computes scale*exp(m[t]-rmax_row)
// directly with the causal mask. Fused epilogue: normalize, per-head LN,
// (hn + skip*xc)*silu(z) -> hstate.
// ---------------------------------------------------------------------------
__global__ __launch_bounds__(256) void attn_mfma_kernel(
    const float* __restrict__ qb, const _Float16* __restrict__ kh,
    const _Float16* __restrict__ vt,
    const float* __restrict__ m_, const float* __restrict__ em,
    const float* __restrict__ rmax_, const float* __restrict__ maxd_,
    const float* __restrict__ mhln_w, const float* __restrict__ skip,
    const float* __restrict__ xc, const float* __restrict__ up,
    float* __restrict__ hstate)
{
  __shared__ _Float16 plds[4][16][72];
  const int tid = threadIdx.x;
  const int lane = tid & 63, wid = tid >> 6;
  const int quad = lane >> 4, l16 = lane & 15;
  const int gw = blockIdx.x * 4 + wid;   // 0..2047
  const int bh = gw >> 6, ss = gw & 63;
  const int h = bh & 3, b = bh >> 2;
  _Float16 (*P)[72] = plds[wid];
  const float* rmaxp = rmax_ + (size_t)bh * S_LEN;
  const float* emp = em + (size_t)bh * S_LEN;
  const float* mp = m_ + (size_t)bh * S_LEN;
  const float* maxdp = maxd_ + (size_t)bh * S_LEN;
  const float scale = 0.0625f;  // DH^-0.5
  const int s0 = ss * 16;

  // ---- Q fragments (A-layout: m = l16, k = c*32 + quad*8 + j) ----
  half8 qf[8];
  const float* qrow = qb + ((size_t)(b * S_LEN + s0 + l16)) * INNER_D + h * DH_D + quad * 8;
#pragma unroll
  for (int c = 0; c < 8; ++c) {
    float4 q0 = *(const float4*)(qrow + c * 32);
    float4 q1 = *(const float4*)(qrow + c * 32 + 4);
    half8 qq = {(_Float16)q0.x, (_Float16)q0.y, (_Float16)q0.z, (_Float16)q0.w,
                (_Float16)q1.x, (_Float16)q1.y, (_Float16)q1.z, (_Float16)q1.w};
    qf[c] = qq;
  }
  v4f acc[16];
#pragma unroll
  for (int nc = 0; nc < 16; ++nc) acc[nc] = (v4f){0.f, 0.f, 0.f, 0.f};
  float rsum[4] = {0.f, 0.f, 0.f, 0.f};
  float rmax_row[4];
#pragma unroll
  for (int r = 0; r < 4; ++r) rmax_row[r] = rmaxp[s0 + quad * 4 + r];

  const int ntile = (ss >> 2) + 1;
  for (int tt = 0; tt < ntile; ++tt) {
    const int t0 = tt * 64;
    const bool diag = (tt == ntile - 1);   // diagonal ALWAYS in last tile
    float rowfac[4];
    if (!diag) {
      const float rtile = rmaxp[t0 + 63];
#pragma unroll
      for (int r = 0; r < 4; ++r) rowfac[r] = __expf(rtile - rmax_row[r]);  // <= 1
    }
    // ---- QK^T: S_sub[16 x 64] ----
#pragma unroll
    for (int sub = 0; sub < 4; ++sub) {
      v4f sacc = (v4f){0.f, 0.f, 0.f, 0.f};
      const _Float16* krow = kh + ((size_t)(b * S_LEN + t0 + sub * 16 + l16)) * 4096
                                + h * DH_D + quad * 8;
#pragma unroll
      for (int c = 0; c < 8; ++c) {
        half8 kf = *(const half8*)(krow + c * 32);
        sacc = __builtin_amdgcn_mfma_f32_16x16x32_f16(qf[c], kf, sacc, 0, 0, 0);
      }
      const int t = t0 + sub * 16 + l16;
      if (diag) {
        const float mt = mp[t];
#pragma unroll
        for (int r = 0; r < 4; ++r) {
          const int srow = s0 + quad * 4 + r;
          float cc = (t <= srow) ? sacc[r] * scale * __expf(mt - rmax_row[r]) : 0.f;
          rsum[r] += cc;
          P[quad * 4 + r][sub * 16 + l16] = (_Float16)cc;
        }
      } else {
        const float emv = emp[t];
#pragma unroll
        for (int r = 0; r < 4; ++r) {
          float cc = sacc[r] * emv * rowfac[r];
          rsum[r] += cc;
          P[quad * 4 + r][sub * 16 + l16] = (_Float16)cc;
        }
      }
    }
    asm volatile("s_waitcnt lgkmcnt(0)" ::: "memory");
    // ---- PV: acc[16 x 256] += P[16 x 64] @ V[64 x 256] ----
    half8 pf0 = *(const half8*)(&P[l16][quad * 8]);
    half8 pf1 = *(const half8*)(&P[l16][32 + quad * 8]);
    const _Float16* vrow = vt + ((size_t)(b * INNER_D + h * DH_D + l16)) * S_LEN + t0 + quad * 8;
#pragma unroll
    for (int nc = 0; nc < 16; ++nc) {
      half8 vf0 = *(const half8*)(vrow + (size_t)nc * 16 * S_LEN);
      half8 vf1 = *(const half8*)(vrow + (size_t)nc * 16 * S_LEN + 32);
      acc[nc] = __builtin_amdgcn_mfma_f32_16x16x32_f16(pf0, vf0, acc[nc], 0, 0, 0);
      acc[nc] = __builtin_amdgcn_mfma_f32_16x16x32_f16(pf1, vf1, acc[nc], 0, 0, 0);
    }
    asm volatile("s_waitcnt lgkmcnt(0)" ::: "memory");
  }
  // ---- epilogue: normalize, LN, gate, store ----
  float inv[4];
#pragma unroll
  for (int r = 0; r < 4; ++r) {
    float rs = rsum[r];
    rs += __shfl_xor(rs, 1); rs += __shfl_xor(rs, 2);
    rs += __shfl_xor(rs, 4); rs += __shfl_xor(rs, 8);
    float md = maxdp[s0 + quad * 4 + r];
    float n = fmaxf(fabsf(rs), __expf(-md));
    inv[r] = 1.f / (n + 1e-6f);
  }
#pragma unroll
  for (int nc = 0; nc < 16; ++nc) {
#pragma unroll
    for (int r = 0; r < 4; ++r) acc[nc][r] *= inv[r];
  }
  float mean[4], rstd[4];
#pragma unroll
  for (int r = 0; r < 4; ++r) {
    float sm = 0.f;
#pragma unroll
    for (int nc = 0; nc < 16; ++nc) sm += acc[nc][r];
    sm += __shfl_xor(sm, 1); sm += __shfl_xor(sm, 2);
    sm += __shfl_xor(sm, 4); sm += __shfl_xor(sm, 8);
    mean[r] = sm * (1.f / DH_D);
  }
#pragma unroll
  for (int r = 0; r < 4; ++r) {
    float sq = 0.f;
#pragma unroll
    for (int nc = 0; nc < 16; ++nc) { float d = acc[nc][r] - mean[r]; sq += d * d; }
    sq += __shfl_xor(sq, 1); sq += __shfl_xor(sq, 2);
    sq += __shfl_xor(sq, 4); sq += __shfl_xor(sq, 8);
    rstd[r] = rsqrtf(sq * (1.f / DH_D) + 1e-5f);
  }
#pragma unroll
  for (int nc = 0; nc < 16; ++nc) {
    const int d = h * DH_D + nc * 16 + l16;
    const float w = mhln_w[d];
    const float sk = skip[d];
#pragma unroll
    for (int r = 0; r < 4; ++r) {
      const size_t row = (size_t)(b * S_LEN + s0 + quad * 4 + r);
      float xcv = xc[row * INNER_D + d];
      float zv = up[row * 2 * INNER_D + INNER_D + d];
      float sz = zv / (1.f + __expf(-zv));
      float o = ((acc[nc][r] - mean[r]) * rstd[r] * w + sk * xcv) * sz;
      hstate[row * INNER_D + d] = o;
    }
  }
}

// ---------------------------------------------------------------------------
extern "C" void kernel_launch(void* const* d_in, const int* in_sizes, int n_in,
                              void* d_out, int out_size, void* d_ws, size_t ws_size,
                              hipStream_t stream)
{
  const float* x      = (const float*)d_in[0];
  const float* W_in   = (const float*)d_in[1];
  const float* b_in   = (const float*)d_in[2];
  const float* ln1_w  = (const float*)d_in[3];
  const float* W_up   = (const float*)d_in[4];
  const float* conv_w = (const float*)d_in[5];
  const float* conv_b = (const float*)d_in[6];
  const float* Wq     = (const float*)d_in[7];
  const float* Wk     = (const float*)d_in[8];
  const float* Wv     = (const float*)d_in[9];
  const float* W_ig   = (const float*)d_in[10];
  const float* b_ig   = (const float*)d_in[11];
  const float* W_fg   = (const float*)d_in[12];
  const float* b_fg   = (const float*)d_in[13];
  const float* mhln_w = (const float*)d_in[14];
  const float* skip   = (const float*)d_in[15];
  const float* W_down = (const float*)d_in[16];
  const float* ln_post_w = (const float*)d_in[17];
  float* out = (float*)d_out;

  float* ws = (float*)d_ws;
  size_t o = 0;
  float* xp     = ws + o; o += (size_t)NROW * E_DIM;
  float* hbuf   = ws + o; o += (size_t)NROW * E_DIM;
  float* up     = ws + o; o += (size_t)NROW * 2 * INNER_D;
  float* xc     = ws + o; o += (size_t)NROW * INNER_D;
  float* qb     = ws + o; o += (size_t)NROW * INNER_D;
  float* kb     = ws + o; o += (size_t)NROW * INNER_D;
  float* vb     = ws + o; o += (size_t)NROW * INNER_D;
  float* hstate = ws + o; o += (size_t)NROW * INNER_D;
  const int GSZ = B_SZ * NH_D * S_LEN;  // 32768
  float* igb   = hbuf;
  float* fgb   = hbuf + GSZ;
  float* mb    = hbuf + 2 * GSZ;
  float* rmaxb = hbuf + 3 * GSZ;
  float* maxdb = hbuf + 4 * GSZ;
  float* emb   = hbuf + 5 * GSZ;
  float* yb    = hbuf;                         // down-proj output (gates dead by then)
  _Float16* kh16 = (_Float16*)up;              // strided into dead x_m half of up
  _Float16* vt16 = (_Float16*)kb;              // kb f32 dead after kcast

  dim3 blk(256);
  gemm_nt_mfma<<<dim3(E_DIM / GBN, NROW / GBM), blk, 0, stream>>>(
      x, W_in, b_in, xp, NROW, E_DIM, F_IN_D);
  ln_mul_kernel<<<NROW, blk, 0, stream>>>(xp, ln1_w, hbuf);
  gemm_nt_mfma<<<dim3(2 * INNER_D / GBN, NROW / GBM), blk, 0, stream>>>(
      hbuf, W_up, nullptr, up, NROW, 2 * INNER_D, E_DIM);
  conv_silu_kernel<<<(NROW * INNER_D) / 256, blk, 0, stream>>>(up, conv_w, conv_b, xc);
  headwise_kernel<<<(NROW * 256) / 256, blk, 0, stream>>>(xc, up, Wq, Wk, Wv, qb, kb, vb);
  gates_kernel<<<NROW, blk, 0, stream>>>(qb, kb, vb, W_ig, b_ig, W_fg, b_fg, igb, fgb);
  scan_kernel<<<B_SZ * NH_D, blk, 0, stream>>>(igb, fgb, mb, rmaxb, maxdb, emb);
  kcast_kernel<<<NROW, blk, 0, stream>>>(kb, kh16);
  vtrans_kernel<<<dim3(16, 16, 8), blk, 0, stream>>>(vb, vt16);
  attn_mfma_kernel<<<512, blk, 0, stream>>>(
      qb, kh16, vt16, mb, emb, rmaxb, maxdb, mhln_w, skip, xc, up, hstate);
  gemm_nt_mfma<<<dim3(E_DIM / GBN, NROW / GBM), blk, 0, stream>>>(
      hstate, W_down, nullptr, yb, NROW, E_DIM, INNER_D);
  final_ln_kernel<<<NROW, blk, 0, stream>>>(xp, yb, ln_post_w, out);
}

// Round 5
// 431.474 us; speedup vs baseline: 4.7283x; 1.3768x over previous
//
#include <hip/hip_runtime.h>

#define S_LEN 1024
#define B_SZ 8
#define F_IN_D 256
#define E_DIM 512
#define INNER_D 1024
#define NH_D 4
#define DH_D 256
#define NROW (B_SZ * S_LEN)   // 8192

typedef _Float16 half8 __attribute__((ext_vector_type(8)));
typedef _Float16 half4_t __attribute__((ext_vector_type(4)));
typedef float v4f __attribute__((ext_vector_type(4)));

// ---------------------------------------------------------------------------
// MFMA NT GEMM: C[M,N] = A[M,K] @ B[N,K]^T (+ bias[n])
// ---------------------------------------------------------------------------
#define GBM 128
#define GBN 128
#define GBK 32
#define LDKG (GBK + 8)

__global__ __launch_bounds__(256) void gemm_nt_mfma(
    const float* __restrict__ A, const float* __restrict__ B,
    const float* __restrict__ bias, float* __restrict__ C,
    int M, int N, int K)
{
  __shared__ __align__(16) _Float16 As[GBM][LDKG];
  __shared__ __align__(16) _Float16 Bs[GBN][LDKG];
  const int tid = threadIdx.x;
  const int lane = tid & 63, w = tid >> 6;
  const int wr = w >> 1, wc = w & 1;
  const int quad = lane >> 4, l16 = lane & 15;
  const int bm = blockIdx.y * GBM, bn = blockIdx.x * GBN;
  const int srow = tid >> 3;
  const int scol = (tid & 7) * 4;

  v4f acc[4][4];
#pragma unroll
  for (int i = 0; i < 4; ++i)
#pragma unroll
    for (int j = 0; j < 4; ++j) acc[i][j] = (v4f){0.f, 0.f, 0.f, 0.f};

  float4 ar[4], br[4];
#pragma unroll
  for (int i = 0; i < 4; ++i) {
    ar[i] = *(const float4*)(A + (size_t)(bm + srow + i * 32) * K + scol);
    br[i] = *(const float4*)(B + (size_t)(bn + srow + i * 32) * K + scol);
  }

  for (int k0 = 0; k0 < K; k0 += GBK) {
    __syncthreads();
#pragma unroll
    for (int i = 0; i < 4; ++i) {
      half4_t av = {(_Float16)ar[i].x, (_Float16)ar[i].y, (_Float16)ar[i].z, (_Float16)ar[i].w};
      half4_t bv = {(_Float16)br[i].x, (_Float16)br[i].y, (_Float16)br[i].z, (_Float16)br[i].w};
      *(half4_t*)(&As[srow + i * 32][scol]) = av;
      *(half4_t*)(&Bs[srow + i * 32][scol]) = bv;
    }
    __syncthreads();
    if (k0 + GBK < K) {
      const int kn = k0 + GBK;
#pragma unroll
      for (int i = 0; i < 4; ++i) {
        ar[i] = *(const float4*)(A + (size_t)(bm + srow + i * 32) * K + kn + scol);
        br[i] = *(const float4*)(B + (size_t)(bn + srow + i * 32) * K + kn + scol);
      }
    }
    half8 af[4], bf[4];
#pragma unroll
    for (int i = 0; i < 4; ++i)
      af[i] = *(const half8*)(&As[wr * 64 + i * 16 + l16][quad * 8]);
#pragma unroll
    for (int j = 0; j < 4; ++j)
      bf[j] = *(const half8*)(&Bs[wc * 64 + j * 16 + l16][quad * 8]);
#pragma unroll
    for (int i = 0; i < 4; ++i)
#pragma unroll
      for (int j = 0; j < 4; ++j)
        acc[i][j] = __builtin_amdgcn_mfma_f32_16x16x32_f16(af[i], bf[j], acc[i][j], 0, 0, 0);
  }

#pragma unroll
  for (int j = 0; j < 4; ++j) {
    const int col = bn + wc * 64 + j * 16 + l16;
    const float bv = bias ? bias[col] : 0.f;
#pragma unroll
    for (int i = 0; i < 4; ++i) {
      const int row0 = bm + wr * 64 + i * 16 + quad * 4;
#pragma unroll
      for (int r = 0; r < 4; ++r)
        C[(size_t)(row0 + r) * N + col] = acc[i][j][r] + bv;
    }
  }
}

// ---------------------------------------------------------------------------
__device__ __forceinline__ float block_sum4(float v, float* red, int tid) {
#pragma unroll
  for (int off = 32; off; off >>= 1) v += __shfl_xor(v, off);
  if ((tid & 63) == 0) red[tid >> 6] = v;
  __syncthreads();
  float t = red[0] + red[1] + red[2] + red[3];
  __syncthreads();
  return t;
}

__global__ __launch_bounds__(256) void ln_mul_kernel(
    const float* __restrict__ in, const float* __restrict__ w,
    float* __restrict__ out)
{
  __shared__ float red[4];
  const int row = blockIdx.x;
  const int tid = threadIdx.x;
  const float* p = in + (size_t)row * E_DIM;
  float v0 = p[tid], v1 = p[tid + 256];
  float mean = block_sum4(v0 + v1, red, tid) * (1.f / E_DIM);
  float d0 = v0 - mean, d1 = v1 - mean;
  float var = block_sum4(d0 * d0 + d1 * d1, red, tid) * (1.f / E_DIM);
  float rstd = rsqrtf(var + 1e-5f);
  out[(size_t)row * E_DIM + tid] = d0 * rstd * w[tid];
  out[(size_t)row * E_DIM + tid + 256] = d1 * rstd * w[tid + 256];
}

__global__ __launch_bounds__(256) void final_ln_kernel(
    const float* __restrict__ res, const float* __restrict__ y,
    const float* __restrict__ w, float* __restrict__ out)
{
  __shared__ float red[4];
  const int row = blockIdx.x;
  const int tid = threadIdx.x;
  const size_t base = (size_t)row * E_DIM;
  float v0 = res[base + tid] + y[base + tid];
  float v1 = res[base + tid + 256] + y[base + tid + 256];
  float mean = block_sum4(v0 + v1, red, tid) * (1.f / E_DIM);
  float d0 = v0 - mean, d1 = v1 - mean;
  float var = block_sum4(d0 * d0 + d1 * d1, red, tid) * (1.f / E_DIM);
  float rstd = rsqrtf(var + 1e-5f);
  out[base + tid] = d0 * rstd * w[tid];
  out[base + tid + 256] = d1 * rstd * w[tid + 256];
}

// ---------------------------------------------------------------------------
__global__ __launch_bounds__(256) void conv_silu_kernel(
    const float* __restrict__ up, const float* __restrict__ cw,
    const float* __restrict__ cb, float* __restrict__ xc)
{
  const int idx = blockIdx.x * 256 + threadIdx.x;
  const int c = idx & (INNER_D - 1);
  const int row = idx >> 10;
  const int s = row & (S_LEN - 1);
  const float* base = up + (size_t)row * (2 * INNER_D) + c;
  const float w0 = cw[c * 4 + 0], w1 = cw[c * 4 + 1], w2 = cw[c * 4 + 2], w3 = cw[c * 4 + 3];
  float acc = cb[c];
  if (s >= 3) acc += w0 * base[-3 * 2 * INNER_D];
  if (s >= 2) acc += w1 * base[-2 * 2 * INNER_D];
  if (s >= 1) acc += w2 * base[-1 * 2 * INNER_D];
  acc += w3 * base[0];
  float sig = 1.f / (1.f + __expf(-acc));
  xc[idx] = acc * sig;
}

// ---------------------------------------------------------------------------
__global__ __launch_bounds__(256) void headwise_kernel(
    const float* __restrict__ xc, const float* __restrict__ up,
    const float* __restrict__ Wq, const float* __restrict__ Wk,
    const float* __restrict__ Wv,
    float* __restrict__ q, float* __restrict__ k, float* __restrict__ v)
{
  const int idx = blockIdx.x * 256 + threadIdx.x;
  const int n = idx & 255;
  const int row = idx >> 8;
  float4 xcv = *(const float4*)(xc + (size_t)row * INNER_D + n * 4);
  float4 xmv = *(const float4*)(up + (size_t)row * (2 * INNER_D) + n * 4);
  const float* wq = Wq + n * 16;
  const float* wk = Wk + n * 16;
  const float* wv = Wv + n * 16;
  float4 qo, ko, vo;
  qo.x = wq[0] * xcv.x + wq[1] * xcv.y + wq[2] * xcv.z + wq[3] * xcv.w;
  qo.y = wq[4] * xcv.x + wq[5] * xcv.y + wq[6] * xcv.z + wq[7] * xcv.w;
  qo.z = wq[8] * xcv.x + wq[9] * xcv.y + wq[10] * xcv.z + wq[11] * xcv.w;
  qo.w = wq[12] * xcv.x + wq[13] * xcv.y + wq[14] * xcv.z + wq[15] * xcv.w;
  ko.x = wk[0] * xcv.x + wk[1] * xcv.y + wk[2] * xcv.z + wk[3] * xcv.w;
  ko.y = wk[4] * xcv.x + wk[5] * xcv.y + wk[6] * xcv.z + wk[7] * xcv.w;
  ko.z = wk[8] * xcv.x + wk[9] * xcv.y + wk[10] * xcv.z + wk[11] * xcv.w;
  ko.w = wk[12] * xcv.x + wk[13] * xcv.y + wk[14] * xcv.z + wk[15] * xcv.w;
  vo.x = wv[0] * xmv.x + wv[1] * xmv.y + wv[2] * xmv.z + wv[3] * xmv.w;
  vo.y = wv[4] * xmv.x + wv[5] * xmv.y + wv[6] * xmv.z + wv[7] * xmv.w;
  vo.z = wv[8] * xmv.x + wv[9] * xmv.y + wv[10] * xmv.z + wv[11] * xmv.w;
  vo.w = wv[12] * xmv.x + wv[13] * xmv.y + wv[14] * xmv.z + wv[15] * xmv.w;
  *(float4*)(q + (size_t)row * INNER_D + n * 4) = qo;
  *(float4*)(k + (size_t)row * INNER_D + n * 4) = ko;
  *(float4*)(v + (size_t)row * INNER_D + n * 4) = vo;
}

// ---------------------------------------------------------------------------
__global__ __launch_bounds__(256) void gates_kernel(
    const float* __restrict__ q, const float* __restrict__ k,
    const float* __restrict__ v,
    const float* __restrict__ Wig, const float* __restrict__ big,
    const float* __restrict__ Wfg, const float* __restrict__ bfg,
    float* __restrict__ ig, float* __restrict__ fg)
{
  __shared__ float red[4][8];
  const int row = blockIdx.x;
  const int tid = threadIdx.x;
  float4 qv = *(const float4*)(q + (size_t)row * INNER_D + tid * 4);
  float4 kv = *(const float4*)(k + (size_t)row * INNER_D + tid * 4);
  float4 vv = *(const float4*)(v + (size_t)row * INNER_D + tid * 4);
  float vals[8];
#pragma unroll
  for (int h = 0; h < 4; ++h) {
    const float* wi = Wig + h * 3072 + tid * 4;
    const float* wf = Wfg + h * 3072 + tid * 4;
    float4 w1 = *(const float4*)(wi);
    float4 w2 = *(const float4*)(wi + 1024);
    float4 w3 = *(const float4*)(wi + 2048);
    vals[h] = qv.x * w1.x + qv.y * w1.y + qv.z * w1.z + qv.w * w1.w
            + kv.x * w2.x + kv.y * w2.y + kv.z * w2.z + kv.w * w2.w
            + vv.x * w3.x + vv.y * w3.y + vv.z * w3.z + vv.w * w3.w;
    float4 f1 = *(const float4*)(wf);
    float4 f2 = *(const float4*)(wf + 1024);
    float4 f3 = *(const float4*)(wf + 2048);
    vals[4 + h] = qv.x * f1.x + qv.y * f1.y + qv.z * f1.z + qv.w * f1.w
                + kv.x * f2.x + kv.y * f2.y + kv.z * f2.z + kv.w * f2.w
                + vv.x * f3.x + vv.y * f3.y + vv.z * f3.z + vv.w * f3.w;
  }
  const int lane = tid & 63, wid = tid >> 6;
#pragma unroll
  for (int i = 0; i < 8; ++i) {
    float x = vals[i];
#pragma unroll
    for (int off = 32; off; off >>= 1) x += __shfl_xor(x, off);
    vals[i] = x;
  }
  if (lane == 0) {
#pragma unroll
    for (int i = 0; i < 8; ++i) red[wid][i] = vals[i];
  }
  __syncthreads();
  if (tid < 8) {
    float sm = red[0][tid] + red[1][tid] + red[2][tid] + red[3][tid];
    const int h = tid & 3;
    const int b = row >> 10, s = row & (S_LEN - 1);
    const size_t oidx = (size_t)(b * NH_D + h) * S_LEN + s;
    if (tid < 4) ig[oidx] = sm + big[h];
    else         fg[oidx] = sm + bfg[h];
  }
}

// ---------------------------------------------------------------------------
__device__ __forceinline__ float logsigf(float x) {
  return fminf(x, 0.f) - log1pf(__expf(-fabsf(x)));
}

__global__ __launch_bounds__(256) void scan_kernel(
    const float* __restrict__ ig, const float* __restrict__ fg,
    float* __restrict__ m_, float* __restrict__ rmax_, float* __restrict__ maxd_,
    float* __restrict__ em_)
{
  __shared__ float sc[256];
  const int bh = blockIdx.x;
  const int tid = threadIdx.x;
  const size_t base = (size_t)bh * S_LEN + tid * 4;
  float4 f4 = *(const float4*)(fg + base);
  float4 i4 = *(const float4*)(ig + base);
  float l0 = logsigf(f4.x), l1 = logsigf(f4.y), l2 = logsigf(f4.z), l3 = logsigf(f4.w);
  float p0 = l0, p1 = p0 + l1, p2 = p1 + l2, p3 = p2 + l3;
  sc[tid] = p3;
  __syncthreads();
  for (int off = 1; off < 256; off <<= 1) {
    float o = (tid >= off) ? sc[tid - off] : 0.f;
    __syncthreads();
    sc[tid] += o;
    __syncthreads();
  }
  float aoff = (tid == 0) ? 0.f : sc[tid - 1];
  __syncthreads();
  float a0 = aoff + p0, a1 = aoff + p1, a2 = aoff + p2, a3 = aoff + p3;
  float m0 = i4.x - a0, m1 = i4.y - a1, m2 = i4.z - a2, m3 = i4.w - a3;
  float x0 = m0, x1 = fmaxf(x0, m1), x2 = fmaxf(x1, m2), x3 = fmaxf(x2, m3);
  sc[tid] = x3;
  __syncthreads();
  for (int off = 1; off < 256; off <<= 1) {
    float o = (tid >= off) ? sc[tid - off] : -1e30f;
    __syncthreads();
    sc[tid] = fmaxf(sc[tid], o);
    __syncthreads();
  }
  float moff = (tid == 0) ? -1e30f : sc[tid - 1];
  float tmax = sc[tid | 15];
  float r0 = fmaxf(moff, x0), r1 = fmaxf(moff, x1), r2 = fmaxf(moff, x2), r3 = fmaxf(moff, x3);
  const float scale = 0.0625f;
  float4 mo = {m0, m1, m2, m3};
  float4 ro = {r0, r1, r2, r3};
  float4 dd = {a0 + r0, a1 + r1, a2 + r2, a3 + r3};
  float4 eo = {scale * __expf(m0 - tmax), scale * __expf(m1 - tmax),
               scale * __expf(m2 - tmax), scale * __expf(m3 - tmax)};
  *(float4*)(m_ + base) = mo;
  *(float4*)(rmax_ + base) = ro;
  *(float4*)(maxd_ + base) = dd;
  *(float4*)(em_ + base) = eo;
}

// ---------------------------------------------------------------------------
__global__ __launch_bounds__(256) void kcast_kernel(
    const float* __restrict__ kb, _Float16* __restrict__ kh)
{
  const int row = blockIdx.x;
  const int d4 = threadIdx.x * 4;
  float4 v = *(const float4*)(kb + (size_t)row * INNER_D + d4);
  half4_t o = {(_Float16)v.x, (_Float16)v.y, (_Float16)v.z, (_Float16)v.w};
  *(half4_t*)(kh + (size_t)row * 4096 + d4) = o;
}

// ---------------------------------------------------------------------------
__global__ __launch_bounds__(256) void vtrans_kernel(
    const float* __restrict__ vb, _Float16* __restrict__ vt)
{
  __shared__ _Float16 tile[64][65];
  const int b = blockIdx.z, dt = blockIdx.x, st = blockIdx.y;
  const int c = threadIdx.x & 63, rb = threadIdx.x >> 6;
  const int s0 = st * 64, d0 = dt * 64;
#pragma unroll
  for (int i = 0; i < 16; ++i) {
    int r = rb * 16 + i;
    tile[r][c] = (_Float16)vb[((size_t)(b * S_LEN + s0 + r)) * INNER_D + d0 + c];
  }
  __syncthreads();
#pragma unroll
  for (int i = 0; i < 16; ++i) {
    int r = rb * 16 + i;
    vt[((size_t)(b * INNER_D + d0 + r)) * S_LEN + s0 + c] = tile[c][r];
  }
}

// ---------------------------------------------------------------------------
// Block-cooperative LDS-staged MFMA attention.
// Block = 4 waves = 64 s-rows of one (b,h). Processes s-block p then 15-p
// (uniform 17 t-tiles). Per t-tile: K[64x256] and V^T[256x64] staged to LDS
// with coalesced loads, double-buffered (reg prefetch of t+1 during compute).
// Fragments read from padded LDS (stride%32dw==4 -> 2-way, free).
// ---------------------------------------------------------------------------
#define KP 264   // K LDS row stride (halves)
#define VP 72    // V LDS row stride (halves)

__global__ __launch_bounds__(256, 1) void attn_blk_kernel(
    const float* __restrict__ qb, const _Float16* __restrict__ kh,
    const _Float16* __restrict__ vt,
    const float* __restrict__ m_, const float* __restrict__ em,
    const float* __restrict__ rmax_, const float* __restrict__ maxd_,
    const float* __restrict__ mhln_w, const float* __restrict__ skip,
    const float* __restrict__ xc, const float* __restrict__ up,
    float* __restrict__ hstate)
{
  __shared__ __align__(16) _Float16 Ks[2][64][KP];
  __shared__ __align__(16) _Float16 Vs[2][256][VP];
  __shared__ _Float16 plds[4][16][72];
  const int tid = threadIdx.x;
  const int lane = tid & 63, wid = tid >> 6;
  const int quad = lane >> 4, l16 = lane & 15;
  const int bh = blockIdx.x >> 3, p = blockIdx.x & 7;
  const int h = bh & 3, b = bh >> 2;
  _Float16 (*P)[72] = plds[wid];
  const float* rmaxp = rmax_ + (size_t)bh * S_LEN;
  const float* emp = em + (size_t)bh * S_LEN;
  const float* mp = m_ + (size_t)bh * S_LEN;
  const float* maxdp = maxd_ + (size_t)bh * S_LEN;
  const float scale = 0.0625f;  // DH^-0.5

  // staging source bases / per-thread coords
  const _Float16* kg = kh + ((size_t)(b * S_LEN)) * 4096 + h * DH_D;
  const _Float16* vg = vt + ((size_t)(b * INNER_D + h * DH_D)) * S_LEN;
  const int krow_s = tid >> 5;          // 0..7  (+8i)
  const int kcol_s = (tid & 31) * 8;    // 0..248
  const int vrow_s = tid >> 3;          // 0..31 (+32i)
  const int vcol_s = (tid & 7) * 8;     // 0..56

  for (int pass = 0; pass < 2; ++pass) {
    const int sblk = pass ? (15 - p) : p;       // 64-row block index
    const int ntile = sblk + 1;
    const int s0 = sblk * 64 + wid * 16;        // this wave's 16 rows

    // ---- prologue: stage tile 0 into buffer 0 ----
#pragma unroll
    for (int i = 0; i < 8; ++i) {
      const int kr = i * 8 + krow_s;
      *(half8*)(&Ks[0][kr][kcol_s]) = *(const half8*)(kg + (size_t)kr * 4096 + kcol_s);
      const int vr = i * 32 + vrow_s;
      *(half8*)(&Vs[0][vr][vcol_s]) = *(const half8*)(vg + (size_t)vr * S_LEN + vcol_s);
    }

    // ---- Q fragments ----
    half8 qf[8];
    const float* qrow = qb + ((size_t)(b * S_LEN + s0 + l16)) * INNER_D + h * DH_D + quad * 8;
#pragma unroll
    for (int c = 0; c < 8; ++c) {
      float4 q0 = *(const float4*)(qrow + c * 32);
      float4 q1 = *(const float4*)(qrow + c * 32 + 4);
      half8 qq = {(_Float16)q0.x, (_Float16)q0.y, (_Float16)q0.z, (_Float16)q0.w,
                  (_Float16)q1.x, (_Float16)q1.y, (_Float16)q1.z, (_Float16)q1.w};
      qf[c] = qq;
    }
    v4f acc[16];
#pragma unroll
    for (int nc = 0; nc < 16; ++nc) acc[nc] = (v4f){0.f, 0.f, 0.f, 0.f};
    float rsum[4] = {0.f, 0.f, 0.f, 0.f};
    float rmax_row[4];
#pragma unroll
    for (int r = 0; r < 4; ++r) rmax_row[r] = rmaxp[s0 + quad * 4 + r];

    __syncthreads();

    for (int tt = 0; tt < ntile; ++tt) {
      const int cur = tt & 1;
      const int t0 = tt * 64;
      const bool last = (tt + 1 == ntile);
      // ---- prefetch next tile into registers ----
      half8 kpre[8], vpre[8];
      if (!last) {
        const int tn = t0 + 64;
#pragma unroll
        for (int i = 0; i < 8; ++i) {
          kpre[i] = *(const half8*)(kg + (size_t)(tn + i * 8 + krow_s) * 4096 + kcol_s);
          vpre[i] = *(const half8*)(vg + (size_t)(i * 32 + vrow_s) * S_LEN + tn + vcol_s);
        }
      }
      const bool diag = last;
      float rowfac[4];
      if (!diag) {
        const float rtile = rmaxp[t0 + 63];
#pragma unroll
        for (int r = 0; r < 4; ++r) rowfac[r] = __expf(rtile - rmax_row[r]);
      }
      // ---- QK^T from LDS ----
#pragma unroll
      for (int sub = 0; sub < 4; ++sub) {
        v4f sacc = (v4f){0.f, 0.f, 0.f, 0.f};
#pragma unroll
        for (int c = 0; c < 8; ++c) {
          half8 kf = *(const half8*)(&Ks[cur][sub * 16 + l16][c * 32 + quad * 8]);
          sacc = __builtin_amdgcn_mfma_f32_16x16x32_f16(qf[c], kf, sacc, 0, 0, 0);
        }
        const int t = t0 + sub * 16 + l16;
        if (diag) {
          const float mt = mp[t];
#pragma unroll
          for (int r = 0; r < 4; ++r) {
            const int srow = s0 + quad * 4 + r;
            float cc = (t <= srow) ? sacc[r] * scale * __expf(mt - rmax_row[r]) : 0.f;
            rsum[r] += cc;
            P[quad * 4 + r][sub * 16 + l16] = (_Float16)cc;
          }
        } else {
          const float emv = emp[t];
#pragma unroll
          for (int r = 0; r < 4; ++r) {
            float cc = sacc[r] * emv * rowfac[r];
            rsum[r] += cc;
            P[quad * 4 + r][sub * 16 + l16] = (_Float16)cc;
          }
        }
      }
      asm volatile("s_waitcnt lgkmcnt(0)" ::: "memory");
      // ---- PV from LDS ----
      half8 pf0 = *(const half8*)(&P[l16][quad * 8]);
      half8 pf1 = *(const half8*)(&P[l16][32 + quad * 8]);
#pragma unroll
      for (int nc = 0; nc < 16; ++nc) {
        half8 vf0 = *(const half8*)(&Vs[cur][nc * 16 + l16][quad * 8]);
        half8 vf1 = *(const half8*)(&Vs[cur][nc * 16 + l16][32 + quad * 8]);
        acc[nc] = __builtin_amdgcn_mfma_f32_16x16x32_f16(pf0, vf0, acc[nc], 0, 0, 0);
        acc[nc] = __builtin_amdgcn_mfma_f32_16x16x32_f16(pf1, vf1, acc[nc], 0, 0, 0);
      }
      // ---- write prefetched regs to the other buffer ----
      if (!last) {
        const int nxt = 1 - cur;
#pragma unroll
        for (int i = 0; i < 8; ++i) {
          *(half8*)(&Ks[nxt][i * 8 + krow_s][kcol_s]) = kpre[i];
          *(half8*)(&Vs[nxt][i * 32 + vrow_s][vcol_s]) = vpre[i];
        }
      }
      __syncthreads();
    }

    // ---- epilogue ----
    float inv[4];
#pragma unroll
    for (int r = 0; r < 4; ++r) {
      float rs = rsum[r];
      rs += __shfl_xor(rs, 1); rs += __shfl_xor(rs, 2);
      rs += __shfl_xor(rs, 4); rs += __shfl_xor(rs, 8);
      float md = maxdp[s0 + quad * 4 + r];
      float n = fmaxf(fabsf(rs), __expf(-md));
      inv[r] = 1.f / (n + 1e-6f);
    }
#pragma unroll
    for (int nc = 0; nc < 16; ++nc) {
#pragma unroll
      for (int r = 0; r < 4; ++r) acc[nc][r] *= inv[r];
    }
    float mean[4], rstd[4];
#pragma unroll
    for (int r = 0; r < 4; ++r) {
      float sm = 0.f;
#pragma unroll
      for (int nc = 0; nc < 16; ++nc) sm += acc[nc][r];
      sm += __shfl_xor(sm, 1); sm += __shfl_xor(sm, 2);
      sm += __shfl_xor(sm, 4); sm += __shfl_xor(sm, 8);
      mean[r] = sm * (1.f / DH_D);
    }
#pragma unroll
    for (int r = 0; r < 4; ++r) {
      float sq = 0.f;
#pragma unroll
      for (int nc = 0; nc < 16; ++nc) { float d = acc[nc][r] - mean[r]; sq += d * d; }
      sq += __shfl_xor(sq, 1); sq += __shfl_xor(sq, 2);
      sq += __shfl_xor(sq, 4); sq += __shfl_xor(sq, 8);
      rstd[r] = rsqrtf(sq * (1.f / DH_D) + 1e-5f);
    }
#pragma unroll
    for (int nc = 0; nc < 16; ++nc) {
      const int d = h * DH_D + nc * 16 + l16;
      const float w = mhln_w[d];
      const float sk = skip[d];
#pragma unroll
      for (int r = 0; r < 4; ++r) {
        const size_t row = (size_t)(b * S_LEN + s0 + quad * 4 + r);
        float xcv = xc[row * INNER_D + d];
        float zv = up[row * 2 * INNER_D + INNER_D + d];
        float sz = zv / (1.f + __expf(-zv));
        float o = ((acc[nc][r] - mean[r]) * rstd[r] * w + sk * xcv) * sz;
        hstate[row * INNER_D + d] = o;
      }
    }
    __syncthreads();   // protect LDS before next pass restages buffer 0
  }
}

// ---------------------------------------------------------------------------
extern "C" void kernel_launch(void* const* d_in, const int* in_sizes, int n_in,
                              void* d_out, int out_size, void* d_ws, size_t ws_size,
                              hipStream_t stream)
{
  const float* x      = (const float*)d_in[0];
  const float* W_in   = (const float*)d_in[1];
  const float* b_in   = (const float*)d_in[2];
  const float* ln1_w  = (const float*)d_in[3];
  const float* W_up   = (const float*)d_in[4];
  const float* conv_w = (const float*)d_in[5];
  const float* conv_b = (const float*)d_in[6];
  const float* Wq     = (const float*)d_in[7];
  const float* Wk     = (const float*)d_in[8];
  const float* Wv     = (const float*)d_in[9];
  const float* W_ig   = (const float*)d_in[10];
  const float* b_ig   = (const float*)d_in[11];
  const float* W_fg   = (const float*)d_in[12];
  const float* b_fg   = (const float*)d_in[13];
  const float* mhln_w = (const float*)d_in[14];
  const float* skip   = (const float*)d_in[15];
  const float* W_down = (const float*)d_in[16];
  const float* ln_post_w = (const float*)d_in[17];
  float* out = (float*)d_out;

  float* ws = (float*)d_ws;
  size_t o = 0;
  float* xp     = ws + o; o += (size_t)NROW * E_DIM;
  float* hbuf   = ws + o; o += (size_t)NROW * E_DIM;
  float* up     = ws + o; o += (size_t)NROW * 2 * INNER_D;
  float* xc     = ws + o; o += (size_t)NROW * INNER_D;
  float* qb     = ws + o; o += (size_t)NROW * INNER_D;
  float* kb     = ws + o; o += (size_t)NROW * INNER_D;
  float* vb     = ws + o; o += (size_t)NROW * INNER_D;
  float* hstate = ws + o; o += (size_t)NROW * INNER_D;
  const int GSZ = B_SZ * NH_D * S_LEN;  // 32768
  float* igb   = hbuf;
  float* fgb   = hbuf + GSZ;
  float* mb    = hbuf + 2 * GSZ;
  float* rmaxb = hbuf + 3 * GSZ;
  float* maxdb = hbuf + 4 * GSZ;
  float* emb   = hbuf + 5 * GSZ;
  float* yb    = hbuf;
  _Float16* kh16 = (_Float16*)up;
  _Float16* vt16 = (_Float16*)kb;

  dim3 blk(256);
  gemm_nt_mfma<<<dim3(E_DIM / GBN, NROW / GBM), blk, 0, stream>>>(
      x, W_in, b_in, xp, NROW, E_DIM, F_IN_D);
  ln_mul_kernel<<<NROW, blk, 0, stream>>>(xp, ln1_w, hbuf);
  gemm_nt_mfma<<<dim3(2 * INNER_D / GBN, NROW / GBM), blk, 0, stream>>>(
      hbuf, W_up, nullptr, up, NROW, 2 * INNER_D, E_DIM);
  conv_silu_kernel<<<(NROW * INNER_D) / 256, blk, 0, stream>>>(up, conv_w, conv_b, xc);
  headwise_kernel<<<(NROW * 256) / 256, blk, 0, stream>>>(xc, up, Wq, Wk, Wv, qb, kb, vb);
  gates_kernel<<<NROW, blk, 0, stream>>>(qb, kb, vb, W_ig, b_ig, W_fg, b_fg, igb, fgb);
  scan_kernel<<<B_SZ * NH_D, blk, 0, stream>>>(igb, fgb, mb, rmaxb, maxdb, emb);
  kcast_kernel<<<NROW, blk, 0, stream>>>(kb, kh16);
  vtrans_kernel<<<dim3(16, 16, 8), blk, 0, stream>>>(vb, vt16);
  attn_blk_kernel<<<256, blk, 0, stream>>>(
      qb, kh16, vt16, mb, emb, rmaxb, maxdb, mhln_w, skip, xc, up, hstate);
  gemm_nt_mfma<<<dim3(E_DIM / GBN, NROW / GBM), blk, 0, stream>>>(
      hstate, W_down, nullptr, yb, NROW, E_DIM, INNER_D);
  final_ln_kernel<<<NROW, blk, 0, stream>>>(xp, yb, ln_post_w, out);
}

// Round 6
// 397.762 us; speedup vs baseline: 5.1290x; 1.0848x over previous
//
#include <hip/hip_runtime.h>

#define S_LEN 1024
#define B_SZ 8
#define F_IN_D 256
#define E_DIM 512
#define INNER_D 1024
#define NH_D 4
#define DH_D 256
#define NROW (B_SZ * S_LEN)   // 8192

typedef _Float16 half8 __attribute__((ext_vector_type(8)));
typedef _Float16 half4_t __attribute__((ext_vector_type(4)));
typedef float v4f __attribute__((ext_vector_type(4)));

// ---------------------------------------------------------------------------
// MFMA NT GEMM: C[M,N] = A[M,K] @ B[N,K]^T (+ bias[n])
// ---------------------------------------------------------------------------
#define GBM 128
#define GBN 128
#define GBK 32
#define LDKG (GBK + 8)

__global__ __launch_bounds__(256) void gemm_nt_mfma(
    const float* __restrict__ A, const float* __restrict__ B,
    const float* __restrict__ bias, float* __restrict__ C,
    int M, int N, int K)
{
  __shared__ __align__(16) _Float16 As[GBM][LDKG];
  __shared__ __align__(16) _Float16 Bs[GBN][LDKG];
  const int tid = threadIdx.x;
  const int lane = tid & 63, w = tid >> 6;
  const int wr = w >> 1, wc = w & 1;
  const int quad = lane >> 4, l16 = lane & 15;
  const int bm = blockIdx.y * GBM, bn = blockIdx.x * GBN;
  const int srow = tid >> 3;
  const int scol = (tid & 7) * 4;

  v4f acc[4][4];
#pragma unroll
  for (int i = 0; i < 4; ++i)
#pragma unroll
    for (int j = 0; j < 4; ++j) acc[i][j] = (v4f){0.f, 0.f, 0.f, 0.f};

  float4 ar[4], br[4];
#pragma unroll
  for (int i = 0; i < 4; ++i) {
    ar[i] = *(const float4*)(A + (size_t)(bm + srow + i * 32) * K + scol);
    br[i] = *(const float4*)(B + (size_t)(bn + srow + i * 32) * K + scol);
  }

  for (int k0 = 0; k0 < K; k0 += GBK) {
    __syncthreads();
#pragma unroll
    for (int i = 0; i < 4; ++i) {
      half4_t av = {(_Float16)ar[i].x, (_Float16)ar[i].y, (_Float16)ar[i].z, (_Float16)ar[i].w};
      half4_t bv = {(_Float16)br[i].x, (_Float16)br[i].y, (_Float16)br[i].z, (_Float16)br[i].w};
      *(half4_t*)(&As[srow + i * 32][scol]) = av;
      *(half4_t*)(&Bs[srow + i * 32][scol]) = bv;
    }
    __syncthreads();
    if (k0 + GBK < K) {
      const int kn = k0 + GBK;
#pragma unroll
      for (int i = 0; i < 4; ++i) {
        ar[i] = *(const float4*)(A + (size_t)(bm + srow + i * 32) * K + kn + scol);
        br[i] = *(const float4*)(B + (size_t)(bn + srow + i * 32) * K + kn + scol);
      }
    }
    half8 af[4], bf[4];
#pragma unroll
    for (int i = 0; i < 4; ++i)
      af[i] = *(const half8*)(&As[wr * 64 + i * 16 + l16][quad * 8]);
#pragma unroll
    for (int j = 0; j < 4; ++j)
      bf[j] = *(const half8*)(&Bs[wc * 64 + j * 16 + l16][quad * 8]);
#pragma unroll
    for (int i = 0; i < 4; ++i)
#pragma unroll
      for (int j = 0; j < 4; ++j)
        acc[i][j] = __builtin_amdgcn_mfma_f32_16x16x32_f16(af[i], bf[j], acc[i][j], 0, 0, 0);
  }

#pragma unroll
  for (int j = 0; j < 4; ++j) {
    const int col = bn + wc * 64 + j * 16 + l16;
    const float bv = bias ? bias[col] : 0.f;
#pragma unroll
    for (int i = 0; i < 4; ++i) {
      const int row0 = bm + wr * 64 + i * 16 + quad * 4;
#pragma unroll
      for (int r = 0; r < 4; ++r)
        C[(size_t)(row0 + r) * N + col] = acc[i][j][r] + bv;
    }
  }
}

// ---------------------------------------------------------------------------
__device__ __forceinline__ float block_sum4(float v, float* red, int tid) {
#pragma unroll
  for (int off = 32; off; off >>= 1) v += __shfl_xor(v, off);
  if ((tid & 63) == 0) red[tid >> 6] = v;
  __syncthreads();
  float t = red[0] + red[1] + red[2] + red[3];
  __syncthreads();
  return t;
}

__global__ __launch_bounds__(256) void ln_mul_kernel(
    const float* __restrict__ in, const float* __restrict__ w,
    float* __restrict__ out)
{
  __shared__ float red[4];
  const int row = blockIdx.x;
  const int tid = threadIdx.x;
  const float* p = in + (size_t)row * E_DIM;
  float v0 = p[tid], v1 = p[tid + 256];
  float mean = block_sum4(v0 + v1, red, tid) * (1.f / E_DIM);
  float d0 = v0 - mean, d1 = v1 - mean;
  float var = block_sum4(d0 * d0 + d1 * d1, red, tid) * (1.f / E_DIM);
  float rstd = rsqrtf(var + 1e-5f);
  out[(size_t)row * E_DIM + tid] = d0 * rstd * w[tid];
  out[(size_t)row * E_DIM + tid + 256] = d1 * rstd * w[tid + 256];
}

__global__ __launch_bounds__(256) void final_ln_kernel(
    const float* __restrict__ res, const float* __restrict__ y,
    const float* __restrict__ w, float* __restrict__ out)
{
  __shared__ float red[4];
  const int row = blockIdx.x;
  const int tid = threadIdx.x;
  const size_t base = (size_t)row * E_DIM;
  float v0 = res[base + tid] + y[base + tid];
  float v1 = res[base + tid + 256] + y[base + tid + 256];
  float mean = block_sum4(v0 + v1, red, tid) * (1.f / E_DIM);
  float d0 = v0 - mean, d1 = v1 - mean;
  float var = block_sum4(d0 * d0 + d1 * d1, red, tid) * (1.f / E_DIM);
  float rstd = rsqrtf(var + 1e-5f);
  out[base + tid] = d0 * rstd * w[tid];
  out[base + tid + 256] = d1 * rstd * w[tid + 256];
}

// ---------------------------------------------------------------------------
__global__ __launch_bounds__(256) void conv_silu_kernel(
    const float* __restrict__ up, const float* __restrict__ cw,
    const float* __restrict__ cb, float* __restrict__ xc)
{
  const int idx = blockIdx.x * 256 + threadIdx.x;
  const int c = idx & (INNER_D - 1);
  const int row = idx >> 10;
  const int s = row & (S_LEN - 1);
  const float* base = up + (size_t)row * (2 * INNER_D) + c;
  const float w0 = cw[c * 4 + 0], w1 = cw[c * 4 + 1], w2 = cw[c * 4 + 2], w3 = cw[c * 4 + 3];
  float acc = cb[c];
  if (s >= 3) acc += w0 * base[-3 * 2 * INNER_D];
  if (s >= 2) acc += w1 * base[-2 * 2 * INNER_D];
  if (s >= 1) acc += w2 * base[-1 * 2 * INNER_D];
  acc += w3 * base[0];
  float sig = 1.f / (1.f + __expf(-acc));
  xc[idx] = acc * sig;
}

// ---------------------------------------------------------------------------
__global__ __launch_bounds__(256) void headwise_kernel(
    const float* __restrict__ xc, const float* __restrict__ up,
    const float* __restrict__ Wq, const float* __restrict__ Wk,
    const float* __restrict__ Wv,
    float* __restrict__ q, float* __restrict__ k, float* __restrict__ v)
{
  const int idx = blockIdx.x * 256 + threadIdx.x;
  const int n = idx & 255;
  const int row = idx >> 8;
  float4 xcv = *(const float4*)(xc + (size_t)row * INNER_D + n * 4);
  float4 xmv = *(const float4*)(up + (size_t)row * (2 * INNER_D) + n * 4);
  const float* wq = Wq + n * 16;
  const float* wk = Wk + n * 16;
  const float* wv = Wv + n * 16;
  float4 qo, ko, vo;
  qo.x = wq[0] * xcv.x + wq[1] * xcv.y + wq[2] * xcv.z + wq[3] * xcv.w;
  qo.y = wq[4] * xcv.x + wq[5] * xcv.y + wq[6] * xcv.z + wq[7] * xcv.w;
  qo.z = wq[8] * xcv.x + wq[9] * xcv.y + wq[10] * xcv.z + wq[11] * xcv.w;
  qo.w = wq[12] * xcv.x + wq[13] * xcv.y + wq[14] * xcv.z + wq[15] * xcv.w;
  ko.x = wk[0] * xcv.x + wk[1] * xcv.y + wk[2] * xcv.z + wk[3] * xcv.w;
  ko.y = wk[4] * xcv.x + wk[5] * xcv.y + wk[6] * xcv.z + wk[7] * xcv.w;
  ko.z = wk[8] * xcv.x + wk[9] * xcv.y + wk[10] * xcv.z + wk[11] * xcv.w;
  ko.w = wk[12] * xcv.x + wk[13] * xcv.y + wk[14] * xcv.z + wk[15] * xcv.w;
  vo.x = wv[0] * xmv.x + wv[1] * xmv.y + wv[2] * xmv.z + wv[3] * xmv.w;
  vo.y = wv[4] * xmv.x + wv[5] * xmv.y + wv[6] * xmv.z + wv[7] * xmv.w;
  vo.z = wv[8] * xmv.x + wv[9] * xmv.y + wv[10] * xmv.z + wv[11] * xmv.w;
  vo.w = wv[12] * xmv.x + wv[13] * xmv.y + wv[14] * xmv.z + wv[15] * xmv.w;
  *(float4*)(q + (size_t)row * INNER_D + n * 4) = qo;
  *(float4*)(k + (size_t)row * INNER_D + n * 4) = ko;
  *(float4*)(v + (size_t)row * INNER_D + n * 4) = vo;
}

// ---------------------------------------------------------------------------
__global__ __launch_bounds__(256) void gates_kernel(
    const float* __restrict__ q, const float* __restrict__ k,
    const float* __restrict__ v,
    const float* __restrict__ Wig, const float* __restrict__ big,
    const float* __restrict__ Wfg, const float* __restrict__ bfg,
    float* __restrict__ ig, float* __restrict__ fg)
{
  __shared__ float red[4][8];
  const int row = blockIdx.x;
  const int tid = threadIdx.x;
  float4 qv = *(const float4*)(q + (size_t)row * INNER_D + tid * 4);
  float4 kv = *(const float4*)(k + (size_t)row * INNER_D + tid * 4);
  float4 vv = *(const float4*)(v + (size_t)row * INNER_D + tid * 4);
  float vals[8];
#pragma unroll
  for (int h = 0; h < 4; ++h) {
    const float* wi = Wig + h * 3072 + tid * 4;
    const float* wf = Wfg + h * 3072 + tid * 4;
    float4 w1 = *(const float4*)(wi);
    float4 w2 = *(const float4*)(wi + 1024);
    float4 w3 = *(const float4*)(wi + 2048);
    vals[h] = qv.x * w1.x + qv.y * w1.y + qv.z * w1.z + qv.w * w1.w
            + kv.x * w2.x + kv.y * w2.y + kv.z * w2.z + kv.w * w2.w
            + vv.x * w3.x + vv.y * w3.y + vv.z * w3.z + vv.w * w3.w;
    float4 f1 = *(const float4*)(wf);
    float4 f2 = *(const float4*)(wf + 1024);
    float4 f3 = *(const float4*)(wf + 2048);
    vals[4 + h] = qv.x * f1.x + qv.y * f1.y + qv.z * f1.z + qv.w * f1.w
                + kv.x * f2.x + kv.y * f2.y + kv.z * f2.z + kv.w * f2.w
                + vv.x * f3.x + vv.y * f3.y + vv.z * f3.z + vv.w * f3.w;
  }
  const int lane = tid & 63, wid = tid >> 6;
#pragma unroll
  for (int i = 0; i < 8; ++i) {
    float x = vals[i];
#pragma unroll
    for (int off = 32; off; off >>= 1) x += __shfl_xor(x, off);
    vals[i] = x;
  }
  if (lane == 0) {
#pragma unroll
    for (int i = 0; i < 8; ++i) red[wid][i] = vals[i];
  }
  __syncthreads();
  if (tid < 8) {
    float sm = red[0][tid] + red[1][tid] + red[2][tid] + red[3][tid];
    const int h = tid & 3;
    const int b = row >> 10, s = row & (S_LEN - 1);
    const size_t oidx = (size_t)(b * NH_D + h) * S_LEN + s;
    if (tid < 4) ig[oidx] = sm + big[h];
    else         fg[oidx] = sm + bfg[h];
  }
}

// ---------------------------------------------------------------------------
__device__ __forceinline__ float logsigf(float x) {
  return fminf(x, 0.f) - log1pf(__expf(-fabsf(x)));
}

__global__ __launch_bounds__(256) void scan_kernel(
    const float* __restrict__ ig, const float* __restrict__ fg,
    float* __restrict__ m_, float* __restrict__ rmax_, float* __restrict__ maxd_,
    float* __restrict__ em_)
{
  __shared__ float sc[256];
  const int bh = blockIdx.x;
  const int tid = threadIdx.x;
  const size_t base = (size_t)bh * S_LEN + tid * 4;
  float4 f4 = *(const float4*)(fg + base);
  float4 i4 = *(const float4*)(ig + base);
  float l0 = logsigf(f4.x), l1 = logsigf(f4.y), l2 = logsigf(f4.z), l3 = logsigf(f4.w);
  float p0 = l0, p1 = p0 + l1, p2 = p1 + l2, p3 = p2 + l3;
  sc[tid] = p3;
  __syncthreads();
  for (int off = 1; off < 256; off <<= 1) {
    float o = (tid >= off) ? sc[tid - off] : 0.f;
    __syncthreads();
    sc[tid] += o;
    __syncthreads();
  }
  float aoff = (tid == 0) ? 0.f : sc[tid - 1];
  __syncthreads();
  float a0 = aoff + p0, a1 = aoff + p1, a2 = aoff + p2, a3 = aoff + p3;
  float m0 = i4.x - a0, m1 = i4.y - a1, m2 = i4.z - a2, m3 = i4.w - a3;
  float x0 = m0, x1 = fmaxf(x0, m1), x2 = fmaxf(x1, m2), x3 = fmaxf(x2, m3);
  sc[tid] = x3;
  __syncthreads();
  for (int off = 1; off < 256; off <<= 1) {
    float o = (tid >= off) ? sc[tid - off] : -1e30f;
    __syncthreads();
    sc[tid] = fmaxf(sc[tid], o);
    __syncthreads();
  }
  float moff = (tid == 0) ? -1e30f : sc[tid - 1];
  float tmax = sc[tid | 15];
  float r0 = fmaxf(moff, x0), r1 = fmaxf(moff, x1), r2 = fmaxf(moff, x2), r3 = fmaxf(moff, x3);
  const float scale = 0.0625f;
  float4 mo = {m0, m1, m2, m3};
  float4 ro = {r0, r1, r2, r3};
  float4 dd = {a0 + r0, a1 + r1, a2 + r2, a3 + r3};
  float4 eo = {scale * __expf(m0 - tmax), scale * __expf(m1 - tmax),
               scale * __expf(m2 - tmax), scale * __expf(m3 - tmax)};
  *(float4*)(m_ + base) = mo;
  *(float4*)(rmax_ + base) = ro;
  *(float4*)(maxd_ + base) = dd;
  *(float4*)(em_ + base) = eo;
}

// ---------------------------------------------------------------------------
__global__ __launch_bounds__(256) void kcast_kernel(
    const float* __restrict__ kb, _Float16* __restrict__ kh)
{
  const int row = blockIdx.x;
  const int d4 = threadIdx.x * 4;
  float4 v = *(const float4*)(kb + (size_t)row * INNER_D + d4);
  half4_t o = {(_Float16)v.x, (_Float16)v.y, (_Float16)v.z, (_Float16)v.w};
  *(half4_t*)(kh + (size_t)row * 4096 + d4) = o;
}

// ---------------------------------------------------------------------------
__global__ __launch_bounds__(256) void vtrans_kernel(
    const float* __restrict__ vb, _Float16* __restrict__ vt)
{
  __shared__ _Float16 tile[64][65];
  const int b = blockIdx.z, dt = blockIdx.x, st = blockIdx.y;
  const int c = threadIdx.x & 63, rb = threadIdx.x >> 6;
  const int s0 = st * 64, d0 = dt * 64;
#pragma unroll
  for (int i = 0; i < 16; ++i) {
    int r = rb * 16 + i;
    tile[r][c] = (_Float16)vb[((size_t)(b * S_LEN + s0 + r)) * INNER_D + d0 + c];
  }
  __syncthreads();
#pragma unroll
  for (int i = 0; i < 16; ++i) {
    int r = rb * 16 + i;
    vt[((size_t)(b * INNER_D + d0 + r)) * S_LEN + s0 + c] = tile[c][r];
  }
}

// ---------------------------------------------------------------------------
// Block-cooperative LDS-staged MFMA attention, single-buffered for 2 blocks/CU.
// Grid 512: bid = pp*32 + bh (bh in low bits -> all 16 blocks of one (b,h)
// land on the same XCD under the %8 heuristic); sblk = 15-pp so long blocks
// launch first. Per tile: stage K[64x256]+V^T[256x64] regs->LDS, then issue
// next tile's global loads (stay in flight over compute), then QK/P/PV.
// ---------------------------------------------------------------------------
#define KP 264   // K LDS row stride (halves)
#define VP 72    // V LDS row stride (halves)

__global__ __launch_bounds__(256, 2) void attn_blk_kernel(
    const float* __restrict__ qb, const _Float16* __restrict__ kh,
    const _Float16* __restrict__ vt,
    const float* __restrict__ m_, const float* __restrict__ em,
    const float* __restrict__ rmax_, const float* __restrict__ maxd_,
    const float* __restrict__ mhln_w, const float* __restrict__ skip,
    const float* __restrict__ xc, const float* __restrict__ up,
    float* __restrict__ hstate)
{
  __shared__ __align__(16) _Float16 Ks[64][KP];    // 33.8 KB
  __shared__ __align__(16) _Float16 Vs[256][VP];   // 36.9 KB
  __shared__ _Float16 plds[4][16][72];             // 9.2 KB  => 79.9 KB total
  const int tid = threadIdx.x;
  const int lane = tid & 63, wid = tid >> 6;
  const int quad = lane >> 4, l16 = lane & 15;
  const int bh = blockIdx.x & 31;        // low bits -> XCD colocation per (b,h)
  const int pp = blockIdx.x >> 5;        // 0..15
  const int sblk = 15 - pp;              // long blocks first
  const int h = bh & 3, b = bh >> 2;
  _Float16 (*P)[72] = plds[wid];
  const float* rmaxp = rmax_ + (size_t)bh * S_LEN;
  const float* emp = em + (size_t)bh * S_LEN;
  const float* mp = m_ + (size_t)bh * S_LEN;
  const float* maxdp = maxd_ + (size_t)bh * S_LEN;
  const float scale = 0.0625f;  // DH^-0.5

  const _Float16* kg = kh + ((size_t)(b * S_LEN)) * 4096 + h * DH_D;
  const _Float16* vg = vt + ((size_t)(b * INNER_D + h * DH_D)) * S_LEN;
  const int krow_s = tid >> 5;          // 0..7  (+8i)
  const int kcol_s = (tid & 31) * 8;    // 0..248
  const int vrow_s = tid >> 3;          // 0..31 (+32i)
  const int vcol_s = (tid & 7) * 8;     // 0..56

  const int ntile = sblk + 1;
  const int s0 = sblk * 64 + wid * 16;  // this wave's 16 rows

  // ---- prologue: load tile 0 into regs ----
  half8 kpre[8], vpre[8];
#pragma unroll
  for (int i = 0; i < 8; ++i) {
    kpre[i] = *(const half8*)(kg + (size_t)(i * 8 + krow_s) * 4096 + kcol_s);
    vpre[i] = *(const half8*)(vg + (size_t)(i * 32 + vrow_s) * S_LEN + vcol_s);
  }

  // ---- Q fragments ----
  half8 qf[8];
  const float* qrow = qb + ((size_t)(b * S_LEN + s0 + l16)) * INNER_D + h * DH_D + quad * 8;
#pragma unroll
  for (int c = 0; c < 8; ++c) {
    float4 q0 = *(const float4*)(qrow + c * 32);
    float4 q1 = *(const float4*)(qrow + c * 32 + 4);
    half8 qq = {(_Float16)q0.x, (_Float16)q0.y, (_Float16)q0.z, (_Float16)q0.w,
                (_Float16)q1.x, (_Float16)q1.y, (_Float16)q1.z, (_Float16)q1.w};
    qf[c] = qq;
  }
  v4f acc[16];
#pragma unroll
  for (int nc = 0; nc < 16; ++nc) acc[nc] = (v4f){0.f, 0.f, 0.f, 0.f};
  float rsum[4] = {0.f, 0.f, 0.f, 0.f};
  float rmax_row[4];
#pragma unroll
  for (int r = 0; r < 4; ++r) rmax_row[r] = rmaxp[s0 + quad * 4 + r];

  for (int tt = 0; tt < ntile; ++tt) {
    const int t0 = tt * 64;
    const bool last = (tt + 1 == ntile);
    __syncthreads();   // previous tile's LDS consumers done
    // ---- write staged regs to LDS (waits vmcnt for the in-flight loads) ----
#pragma unroll
    for (int i = 0; i < 8; ++i) {
      *(half8*)(&Ks[i * 8 + krow_s][kcol_s]) = kpre[i];
      *(half8*)(&Vs[i * 32 + vrow_s][vcol_s]) = vpre[i];
    }
    __syncthreads();
    // ---- issue next tile's loads; they stay in flight over compute ----
    if (!last) {
      const int tn = t0 + 64;
#pragma unroll
      for (int i = 0; i < 8; ++i) {
        kpre[i] = *(const half8*)(kg + (size_t)(tn + i * 8 + krow_s) * 4096 + kcol_s);
        vpre[i] = *(const half8*)(vg + (size_t)(i * 32 + vrow_s) * S_LEN + tn + vcol_s);
      }
    }
    const bool diag = last;
    float rowfac[4];
    if (!diag) {
      const float rtile = rmaxp[t0 + 63];
#pragma unroll
      for (int r = 0; r < 4; ++r) rowfac[r] = __expf(rtile - rmax_row[r]);
    }
    // ---- QK^T from LDS (two independent 4-deep MFMA chains) ----
#pragma unroll
    for (int sub = 0; sub < 4; ++sub) {
      v4f sacc0 = (v4f){0.f, 0.f, 0.f, 0.f};
      v4f sacc1 = (v4f){0.f, 0.f, 0.f, 0.f};
#pragma unroll
      for (int c = 0; c < 4; ++c) {
        half8 kf0 = *(const half8*)(&Ks[sub * 16 + l16][c * 32 + quad * 8]);
        half8 kf1 = *(const half8*)(&Ks[sub * 16 + l16][(c + 4) * 32 + quad * 8]);
        sacc0 = __builtin_amdgcn_mfma_f32_16x16x32_f16(qf[c], kf0, sacc0, 0, 0, 0);
        sacc1 = __builtin_amdgcn_mfma_f32_16x16x32_f16(qf[c + 4], kf1, sacc1, 0, 0, 0);
      }
      v4f sacc = sacc0 + sacc1;
      const int t = t0 + sub * 16 + l16;
      if (diag) {
        const float mt = mp[t];
#pragma unroll
        for (int r = 0; r < 4; ++r) {
          const int srow = s0 + quad * 4 + r;
          float cc = (t <= srow) ? sacc[r] * scale * __expf(mt - rmax_row[r]) : 0.f;
          rsum[r] += cc;
          P[quad * 4 + r][sub * 16 + l16] = (_Float16)cc;
        }
      } else {
        const float emv = emp[t];
#pragma unroll
        for (int r = 0; r < 4; ++r) {
          float cc = sacc[r] * emv * rowfac[r];
          rsum[r] += cc;
          P[quad * 4 + r][sub * 16 + l16] = (_Float16)cc;
        }
      }
    }
    asm volatile("s_waitcnt lgkmcnt(0)" ::: "memory");
    // ---- PV from LDS ----
    half8 pf0 = *(const half8*)(&P[l16][quad * 8]);
    half8 pf1 = *(const half8*)(&P[l16][32 + quad * 8]);
#pragma unroll
    for (int nc = 0; nc < 16; ++nc) {
      half8 vf0 = *(const half8*)(&Vs[nc * 16 + l16][quad * 8]);
      half8 vf1 = *(const half8*)(&Vs[nc * 16 + l16][32 + quad * 8]);
      acc[nc] = __builtin_amdgcn_mfma_f32_16x16x32_f16(pf0, vf0, acc[nc], 0, 0, 0);
      acc[nc] = __builtin_amdgcn_mfma_f32_16x16x32_f16(pf1, vf1, acc[nc], 0, 0, 0);
    }
  }

  // ---- epilogue ----
  float inv[4];
#pragma unroll
  for (int r = 0; r < 4; ++r) {
    float rs = rsum[r];
    rs += __shfl_xor(rs, 1); rs += __shfl_xor(rs, 2);
    rs += __shfl_xor(rs, 4); rs += __shfl_xor(rs, 8);
    float md = maxdp[s0 + quad * 4 + r];
    float n = fmaxf(fabsf(rs), __expf(-md));
    inv[r] = 1.f / (n + 1e-6f);
  }
#pragma unroll
  for (int nc = 0; nc < 16; ++nc) {
#pragma unroll
    for (int r = 0; r < 4; ++r) acc[nc][r] *= inv[r];
  }
  float mean[4], rstd[4];
#pragma unroll
  for (int r = 0; r < 4; ++r) {
    float sm = 0.f;
#pragma unroll
    for (int nc = 0; nc < 16; ++nc) sm += acc[nc][r];
    sm += __shfl_xor(sm, 1); sm += __shfl_xor(sm, 2);
    sm += __shfl_xor(sm, 4); sm += __shfl_xor(sm, 8);
    mean[r] = sm * (1.f / DH_D);
  }
#pragma unroll
  for (int r = 0; r < 4; ++r) {
    float sq = 0.f;
#pragma unroll
    for (int nc = 0; nc < 16; ++nc) { float d = acc[nc][r] - mean[r]; sq += d * d; }
    sq += __shfl_xor(sq, 1); sq += __shfl_xor(sq, 2);
    sq += __shfl_xor(sq, 4); sq += __shfl_xor(sq, 8);
    rstd[r] = rsqrtf(sq * (1.f / DH_D) + 1e-5f);
  }
#pragma unroll
  for (int nc = 0; nc < 16; ++nc) {
    const int d = h * DH_D + nc * 16 + l16;
    const float w = mhln_w[d];
    const float sk = skip[d];
#pragma unroll
    for (int r = 0; r < 4; ++r) {
      const size_t row = (size_t)(b * S_LEN + s0 + quad * 4 + r);
      float xcv = xc[row * INNER_D + d];
      float zv = up[row * 2 * INNER_D + INNER_D + d];
      float sz = zv / (1.f + __expf(-zv));
      float o = ((acc[nc][r] - mean[r]) * rstd[r] * w + sk * xcv) * sz;
      hstate[row * INNER_D + d] = o;
    }
  }
}

// ---------------------------------------------------------------------------
extern "C" void kernel_launch(void* const* d_in, const int* in_sizes, int n_in,
                              void* d_out, int out_size, void* d_ws, size_t ws_size,
                              hipStream_t stream)
{
  const float* x      = (const float*)d_in[0];
  const float* W_in   = (const float*)d_in[1];
  const float* b_in   = (const float*)d_in[2];
  const float* ln1_w  = (const float*)d_in[3];
  const float* W_up   = (const float*)d_in[4];
  const float* conv_w = (const float*)d_in[5];
  const float* conv_b = (const float*)d_in[6];
  const float* Wq     = (const float*)d_in[7];
  const float* Wk     = (const float*)d_in[8];
  const float* Wv     = (const float*)d_in[9];
  const float* W_ig   = (const float*)d_in[10];
  const float* b_ig   = (const float*)d_in[11];
  const float* W_fg   = (const float*)d_in[12];
  const float* b_fg   = (const float*)d_in[13];
  const float* mhln_w = (const float*)d_in[14];
  const float* skip   = (const float*)d_in[15];
  const float* W_down = (const float*)d_in[16];
  const float* ln_post_w = (const float*)d_in[17];
  float* out = (float*)d_out;

  float* ws = (float*)d_ws;
  size_t o = 0;
  float* xp     = ws + o; o += (size_t)NROW * E_DIM;
  float* hbuf   = ws + o; o += (size_t)NROW * E_DIM;
  float* up     = ws + o; o += (size_t)NROW * 2 * INNER_D;
  float* xc     = ws + o; o += (size_t)NROW * INNER_D;
  float* qb     = ws + o; o += (size_t)NROW * INNER_D;
  float* kb     = ws + o; o += (size_t)NROW * INNER_D;
  float* vb     = ws + o; o += (size_t)NROW * INNER_D;
  float* hstate = ws + o; o += (size_t)NROW * INNER_D;
  const int GSZ = B_SZ * NH_D * S_LEN;  // 32768
  float* igb   = hbuf;
  float* fgb   = hbuf + GSZ;
  float* mb    = hbuf + 2 * GSZ;
  float* rmaxb = hbuf + 3 * GSZ;
  float* maxdb = hbuf + 4 * GSZ;
  float* emb   = hbuf + 5 * GSZ;
  float* yb    = hbuf;
  _Float16* kh16 = (_Float16*)up;
  _Float16* vt16 = (_Float16*)kb;

  dim3 blk(256);
  gemm_nt_mfma<<<dim3(E_DIM / GBN, NROW / GBM), blk, 0, stream>>>(
      x, W_in, b_in, xp, NROW, E_DIM, F_IN_D);
  ln_mul_kernel<<<NROW, blk, 0, stream>>>(xp, ln1_w, hbuf);
  gemm_nt_mfma<<<dim3(2 * INNER_D / GBN, NROW / GBM), blk, 0, stream>>>(
      hbuf, W_up, nullptr, up, NROW, 2 * INNER_D, E_DIM);
  conv_silu_kernel<<<(NROW * INNER_D) / 256, blk, 0, stream>>>(up, conv_w, conv_b, xc);
  headwise_kernel<<<(NROW * 256) / 256, blk, 0, stream>>>(xc, up, Wq, Wk, Wv, qb, kb, vb);
  gates_kernel<<<NROW, blk, 0, stream>>>(qb, kb, vb, W_ig, b_ig, W_fg, b_fg, igb, fgb);
  scan_kernel<<<B_SZ * NH_D, blk, 0, stream>>>(igb, fgb, mb, rmaxb, maxdb, emb);
  kcast_kernel<<<NROW, blk, 0, stream>>>(kb, kh16);
  vtrans_kernel<<<dim3(16, 16, 8), blk, 0, stream>>>(vb, vt16);
  attn_blk_kernel<<<512, blk, 0, stream>>>(
      qb, kh16, vt16, mb, emb, rmaxb, maxdb, mhln_w, skip, xc, up, hstate);
  gemm_nt_mfma<<<dim3(E_DIM / GBN, NROW / GBM), blk, 0, stream>>>(
      hstate, W_down, nullptr, yb, NROW, E_DIM, INNER_D);
  final_ln_kernel<<<NROW, blk, 0, stream>>>(xp, yb, ln_post_w, out);
}

// Round 7
// 327.717 us; speedup vs baseline: 6.2253x; 1.2137x over previous
//
#include <hip/hip_runtime.h>

#define S_LEN 1024
#define B_SZ 8
#define F_IN_D 256
#define E_DIM 512
#define INNER_D 1024
#define NH_D 4
#define DH_D 256
#define NROW (B_SZ * S_LEN)   // 8192

typedef _Float16 half8 __attribute__((ext_vector_type(8)));
typedef _Float16 half4_t __attribute__((ext_vector_type(4)));
typedef float v4f __attribute__((ext_vector_type(4)));

// ---------------------------------------------------------------------------
// Cast 4 f32 buffers to f16 in one pass (x, W_in, W_up, W_down).
// ---------------------------------------------------------------------------
__global__ __launch_bounds__(256) void cast4_kernel(
    const float* __restrict__ s0, const float* __restrict__ s1,
    const float* __restrict__ s2, const float* __restrict__ s3,
    _Float16* __restrict__ d0, _Float16* __restrict__ d1,
    _Float16* __restrict__ d2, _Float16* __restrict__ d3,
    int n0, int n1, int n2, int n3)
{
  int i = (blockIdx.x * 256 + threadIdx.x) * 4;
  const float* s; _Float16* d; int off;
  if (i < n0)                { s = s0; d = d0; off = i; }
  else if (i < n0 + n1)      { s = s1; d = d1; off = i - n0; }
  else if (i < n0 + n1 + n2) { s = s2; d = d2; off = i - n0 - n1; }
  else if (i < n0 + n1 + n2 + n3) { s = s3; d = d3; off = i - n0 - n1 - n2; }
  else return;
  float4 v = *(const float4*)(s + off);
  half4_t o = {(_Float16)v.x, (_Float16)v.y, (_Float16)v.z, (_Float16)v.w};
  *(half4_t*)(d + off) = o;
}

// ---------------------------------------------------------------------------
// Pure-f16 MFMA NT GEMM: C[M,N] = A[M,K] @ B[N,K]^T (+ bias), C f32.
// 128x128 tile, BK=32, reg-prefetch double staging. M%128, N%128, K%32.
// ---------------------------------------------------------------------------
#define GBM 128
#define GBN 128
#define GBK 32
#define LDKG (GBK + 8)

__global__ __launch_bounds__(256) void gemm_h16(
    const _Float16* __restrict__ A, const _Float16* __restrict__ B,
    const float* __restrict__ bias, float* __restrict__ C,
    int M, int N, int K)
{
  __shared__ __align__(16) _Float16 As[GBM][LDKG];
  __shared__ __align__(16) _Float16 Bs[GBN][LDKG];
  const int tid = threadIdx.x;
  const int lane = tid & 63, w = tid >> 6;
  const int wr = w >> 1, wc = w & 1;
  const int quad = lane >> 4, l16 = lane & 15;
  const int bm = blockIdx.y * GBM, bn = blockIdx.x * GBN;
  const int srow = tid >> 1;          // 0..127
  const int scol = (tid & 1) * 16;    // halves

  v4f acc[4][4];
#pragma unroll
  for (int i = 0; i < 4; ++i)
#pragma unroll
    for (int j = 0; j < 4; ++j) acc[i][j] = (v4f){0.f, 0.f, 0.f, 0.f};

  const _Float16* Ap = A + (size_t)(bm + srow) * K + scol;
  const _Float16* Bp = B + (size_t)(bn + srow) * K + scol;
  half8 a0 = *(const half8*)(Ap);
  half8 a1 = *(const half8*)(Ap + 8);
  half8 b0 = *(const half8*)(Bp);
  half8 b1 = *(const half8*)(Bp + 8);

  for (int k0 = 0; k0 < K; k0 += GBK) {
    __syncthreads();
    *(half8*)(&As[srow][scol]) = a0;
    *(half8*)(&As[srow][scol + 8]) = a1;
    *(half8*)(&Bs[srow][scol]) = b0;
    *(half8*)(&Bs[srow][scol + 8]) = b1;
    __syncthreads();
    if (k0 + GBK < K) {
      const int kn = k0 + GBK;
      a0 = *(const half8*)(Ap + kn);
      a1 = *(const half8*)(Ap + kn + 8);
      b0 = *(const half8*)(Bp + kn);
      b1 = *(const half8*)(Bp + kn + 8);
    }
    half8 af[4], bf[4];
#pragma unroll
    for (int i = 0; i < 4; ++i)
      af[i] = *(const half8*)(&As[wr * 64 + i * 16 + l16][quad * 8]);
#pragma unroll
    for (int j = 0; j < 4; ++j)
      bf[j] = *(const half8*)(&Bs[wc * 64 + j * 16 + l16][quad * 8]);
#pragma unroll
    for (int i = 0; i < 4; ++i)
#pragma unroll
      for (int j = 0; j < 4; ++j)
        acc[i][j] = __builtin_amdgcn_mfma_f32_16x16x32_f16(af[i], bf[j], acc[i][j], 0, 0, 0);
  }

#pragma unroll
  for (int j = 0; j < 4; ++j) {
    const int col = bn + wc * 64 + j * 16 + l16;
    const float bv = bias ? bias[col] : 0.f;
#pragma unroll
    for (int i = 0; i < 4; ++i) {
      const int row0 = bm + wr * 64 + i * 16 + quad * 4;
#pragma unroll
      for (int r = 0; r < 4; ++r)
        C[(size_t)(row0 + r) * N + col] = acc[i][j][r] + bv;
    }
  }
}

// ---------------------------------------------------------------------------
__device__ __forceinline__ float block_sum4(float v, float* red, int tid) {
#pragma unroll
  for (int off = 32; off; off >>= 1) v += __shfl_xor(v, off);
  if ((tid & 63) == 0) red[tid >> 6] = v;
  __syncthreads();
  float t = red[0] + red[1] + red[2] + red[3];
  __syncthreads();
  return t;
}

// LN over 512, f16 output (feeds up-GEMM)
__global__ __launch_bounds__(256) void ln_mul_kernel(
    const float* __restrict__ in, const float* __restrict__ w,
    _Float16* __restrict__ out)
{
  __shared__ float red[4];
  const int row = blockIdx.x;
  const int tid = threadIdx.x;
  const float* p = in + (size_t)row * E_DIM;
  float v0 = p[tid], v1 = p[tid + 256];
  float mean = block_sum4(v0 + v1, red, tid) * (1.f / E_DIM);
  float d0 = v0 - mean, d1 = v1 - mean;
  float var = block_sum4(d0 * d0 + d1 * d1, red, tid) * (1.f / E_DIM);
  float rstd = rsqrtf(var + 1e-5f);
  out[(size_t)row * E_DIM + tid] = (_Float16)(d0 * rstd * w[tid]);
  out[(size_t)row * E_DIM + tid + 256] = (_Float16)(d1 * rstd * w[tid + 256]);
}

__global__ __launch_bounds__(256) void final_ln_kernel(
    const float* __restrict__ res, const float* __restrict__ y,
    const float* __restrict__ w, float* __restrict__ out)
{
  __shared__ float red[4];
  const int row = blockIdx.x;
  const int tid = threadIdx.x;
  const size_t base = (size_t)row * E_DIM;
  float v0 = res[base + tid] + y[base + tid];
  float v1 = res[base + tid + 256] + y[base + tid + 256];
  float mean = block_sum4(v0 + v1, red, tid) * (1.f / E_DIM);
  float d0 = v0 - mean, d1 = v1 - mean;
  float var = block_sum4(d0 * d0 + d1 * d1, red, tid) * (1.f / E_DIM);
  float rstd = rsqrtf(var + 1e-5f);
  out[base + tid] = d0 * rstd * w[tid];
  out[base + tid + 256] = d1 * rstd * w[tid + 256];
}

// ---------------------------------------------------------------------------
// Fused conv+silu, headwise q/k/v, gates. One block per row (s of batch b).
// Writes xc f32 (attn epilogue), q/k/v f16 (attn + vtrans), ig/fg f32.
// ---------------------------------------------------------------------------
__global__ __launch_bounds__(256) void chg_kernel(
    const float* __restrict__ up, const float* __restrict__ cw,
    const float* __restrict__ cb,
    const float* __restrict__ Wq, const float* __restrict__ Wk,
    const float* __restrict__ Wv,
    const float* __restrict__ Wig, const float* __restrict__ big,
    const float* __restrict__ Wfg, const float* __restrict__ bfg,
    float* __restrict__ xc, _Float16* __restrict__ qh,
    _Float16* __restrict__ khb, _Float16* __restrict__ vhb,
    float* __restrict__ ig, float* __restrict__ fg)
{
  __shared__ float red[4][8];
  const int row = blockIdx.x;
  const int tid = threadIdx.x;
  const int n = tid;            // 0..255 block of 4 channels
  const int c = n * 4;
  const int s = row & (S_LEN - 1);
  const float* bp = up + (size_t)row * (2 * INNER_D) + c;
  float4 x0 = *(const float4*)bp;                       // tap w3 (current)
  float4 x1 = (s >= 1) ? *(const float4*)(bp - 1 * 2 * INNER_D) : (float4){0, 0, 0, 0};
  float4 x2 = (s >= 2) ? *(const float4*)(bp - 2 * 2 * INNER_D) : (float4){0, 0, 0, 0};
  float4 x3 = (s >= 3) ? *(const float4*)(bp - 3 * 2 * INNER_D) : (float4){0, 0, 0, 0};
  float4 cb4 = *(const float4*)(cb + c);
  float xc4[4];
  {
    const float xs3[4] = {x3.x, x3.y, x3.z, x3.w};
    const float xs2[4] = {x2.x, x2.y, x2.z, x2.w};
    const float xs1[4] = {x1.x, x1.y, x1.z, x1.w};
    const float xs0[4] = {x0.x, x0.y, x0.z, x0.w};
    const float cbs[4] = {cb4.x, cb4.y, cb4.z, cb4.w};
#pragma unroll
    for (int j = 0; j < 4; ++j) {
      float4 wch = *(const float4*)(cw + (c + j) * 4);
      float a = cbs[j] + wch.x * xs3[j] + wch.y * xs2[j] + wch.z * xs1[j] + wch.w * xs0[j];
      xc4[j] = a / (1.f + __expf(-a));
    }
  }
  // headwise 4x4 transforms
  const float* wq = Wq + n * 16;
  const float* wk = Wk + n * 16;
  const float* wv = Wv + n * 16;
  float4 qv, kv, vv;
  qv.x = wq[0] * xc4[0] + wq[1] * xc4[1] + wq[2] * xc4[2] + wq[3] * xc4[3];
  qv.y = wq[4] * xc4[0] + wq[5] * xc4[1] + wq[6] * xc4[2] + wq[7] * xc4[3];
  qv.z = wq[8] * xc4[0] + wq[9] * xc4[1] + wq[10] * xc4[2] + wq[11] * xc4[3];
  qv.w = wq[12] * xc4[0] + wq[13] * xc4[1] + wq[14] * xc4[2] + wq[15] * xc4[3];
  kv.x = wk[0] * xc4[0] + wk[1] * xc4[1] + wk[2] * xc4[2] + wk[3] * xc4[3];
  kv.y = wk[4] * xc4[0] + wk[5] * xc4[1] + wk[6] * xc4[2] + wk[7] * xc4[3];
  kv.z = wk[8] * xc4[0] + wk[9] * xc4[1] + wk[10] * xc4[2] + wk[11] * xc4[3];
  kv.w = wk[12] * xc4[0] + wk[13] * xc4[1] + wk[14] * xc4[2] + wk[15] * xc4[3];
  vv.x = wv[0] * x0.x + wv[1] * x0.y + wv[2] * x0.z + wv[3] * x0.w;
  vv.y = wv[4] * x0.x + wv[5] * x0.y + wv[6] * x0.z + wv[7] * x0.w;
  vv.z = wv[8] * x0.x + wv[9] * x0.y + wv[10] * x0.z + wv[11] * x0.w;
  vv.w = wv[12] * x0.x + wv[13] * x0.y + wv[14] * x0.z + wv[15] * x0.w;
  // writes
  *(float4*)(xc + (size_t)row * INNER_D + c) = (float4){xc4[0], xc4[1], xc4[2], xc4[3]};
  half4_t qo = {(_Float16)qv.x, (_Float16)qv.y, (_Float16)qv.z, (_Float16)qv.w};
  half4_t ko = {(_Float16)kv.x, (_Float16)kv.y, (_Float16)kv.z, (_Float16)kv.w};
  half4_t vo = {(_Float16)vv.x, (_Float16)vv.y, (_Float16)vv.z, (_Float16)vv.w};
  *(half4_t*)(qh + (size_t)row * INNER_D + c) = qo;
  *(half4_t*)(khb + (size_t)row * INNER_D + c) = ko;
  *(half4_t*)(vhb + (size_t)row * INNER_D + c) = vo;
  // gates (full f32 q/k/v)
  float vals[8];
#pragma unroll
  for (int h = 0; h < 4; ++h) {
    const float* wi = Wig + h * 3072 + tid * 4;
    const float* wf = Wfg + h * 3072 + tid * 4;
    float4 w1 = *(const float4*)(wi);
    float4 w2 = *(const float4*)(wi + 1024);
    float4 w3 = *(const float4*)(wi + 2048);
    vals[h] = qv.x * w1.x + qv.y * w1.y + qv.z * w1.z + qv.w * w1.w
            + kv.x * w2.x + kv.y * w2.y + kv.z * w2.z + kv.w * w2.w
            + vv.x * w3.x + vv.y * w3.y + vv.z * w3.z + vv.w * w3.w;
    float4 f1 = *(const float4*)(wf);
    float4 f2 = *(const float4*)(wf + 1024);
    float4 f3 = *(const float4*)(wf + 2048);
    vals[4 + h] = qv.x * f1.x + qv.y * f1.y + qv.z * f1.z + qv.w * f1.w
                + kv.x * f2.x + kv.y * f2.y + kv.z * f2.z + kv.w * f2.w
                + vv.x * f3.x + vv.y * f3.y + vv.z * f3.z + vv.w * f3.w;
  }
  const int lane = tid & 63, wid = tid >> 6;
#pragma unroll
  for (int i = 0; i < 8; ++i) {
    float x = vals[i];
#pragma unroll
    for (int off = 32; off; off >>= 1) x += __shfl_xor(x, off);
    vals[i] = x;
  }
  if (lane == 0) {
#pragma unroll
    for (int i = 0; i < 8; ++i) red[wid][i] = vals[i];
  }
  __syncthreads();
  if (tid < 8) {
    float sm = red[0][tid] + red[1][tid] + red[2][tid] + red[3][tid];
    const int h = tid & 3;
    const int b = row >> 10, ss = row & (S_LEN - 1);
    const size_t oidx = (size_t)(b * NH_D + h) * S_LEN + ss;
    if (tid < 4) ig[oidx] = sm + big[h];
    else         fg[oidx] = sm + bfg[h];
  }
}

// ---------------------------------------------------------------------------
__device__ __forceinline__ float logsigf(float x) {
  return fminf(x, 0.f) - log1pf(__expf(-fabsf(x)));
}

__global__ __launch_bounds__(256) void scan_kernel(
    const float* __restrict__ ig, const float* __restrict__ fg,
    float* __restrict__ m_, float* __restrict__ rmax_, float* __restrict__ maxd_,
    float* __restrict__ em_)
{
  __shared__ float sc[256];
  const int bh = blockIdx.x;
  const int tid = threadIdx.x;
  const size_t base = (size_t)bh * S_LEN + tid * 4;
  float4 f4 = *(const float4*)(fg + base);
  float4 i4 = *(const float4*)(ig + base);
  float l0 = logsigf(f4.x), l1 = logsigf(f4.y), l2 = logsigf(f4.z), l3 = logsigf(f4.w);
  float p0 = l0, p1 = p0 + l1, p2 = p1 + l2, p3 = p2 + l3;
  sc[tid] = p3;
  __syncthreads();
  for (int off = 1; off < 256; off <<= 1) {
    float o = (tid >= off) ? sc[tid - off] : 0.f;
    __syncthreads();
    sc[tid] += o;
    __syncthreads();
  }
  float aoff = (tid == 0) ? 0.f : sc[tid - 1];
  __syncthreads();
  float a0 = aoff + p0, a1 = aoff + p1, a2 = aoff + p2, a3 = aoff + p3;
  float m0 = i4.x - a0, m1 = i4.y - a1, m2 = i4.z - a2, m3 = i4.w - a3;
  float x0 = m0, x1 = fmaxf(x0, m1), x2 = fmaxf(x1, m2), x3 = fmaxf(x2, m3);
  sc[tid] = x3;
  __syncthreads();
  for (int off = 1; off < 256; off <<= 1) {
    float o = (tid >= off) ? sc[tid - off] : -1e30f;
    __syncthreads();
    sc[tid] = fmaxf(sc[tid], o);
    __syncthreads();
  }
  float moff = (tid == 0) ? -1e30f : sc[tid - 1];
  float tmax = sc[tid | 15];
  float r0 = fmaxf(moff, x0), r1 = fmaxf(moff, x1), r2 = fmaxf(moff, x2), r3 = fmaxf(moff, x3);
  const float scale = 0.0625f;
  float4 mo = {m0, m1, m2, m3};
  float4 ro = {r0, r1, r2, r3};
  float4 dd = {a0 + r0, a1 + r1, a2 + r2, a3 + r3};
  float4 eo = {scale * __expf(m0 - tmax), scale * __expf(m1 - tmax),
               scale * __expf(m2 - tmax), scale * __expf(m3 - tmax)};
  *(float4*)(m_ + base) = mo;
  *(float4*)(rmax_ + base) = ro;
  *(float4*)(maxd_ + base) = dd;
  *(float4*)(em_ + base) = eo;
}

// ---------------------------------------------------------------------------
// Transpose v f16 [b][s][d] -> f16 vt [b][d][s]
// ---------------------------------------------------------------------------
__global__ __launch_bounds__(256) void vtrans_kernel(
    const _Float16* __restrict__ vb, _Float16* __restrict__ vt)
{
  __shared__ _Float16 tile[64][68];
  const int b = blockIdx.z, dt = blockIdx.x, st = blockIdx.y;
  const int c4 = (threadIdx.x & 15) * 4, rr = threadIdx.x >> 4;  // rr 0..15
  const int s0 = st * 64, d0 = dt * 64;
#pragma unroll
  for (int i = 0; i < 4; ++i) {
    int r = rr + i * 16;
    half4_t v = *(const half4_t*)(vb + ((size_t)(b * S_LEN + s0 + r)) * INNER_D + d0 + c4);
    tile[r][c4 + 0] = v.x; tile[r][c4 + 1] = v.y;
    tile[r][c4 + 2] = v.z; tile[r][c4 + 3] = v.w;
  }
  __syncthreads();
#pragma unroll
  for (int i = 0; i < 4; ++i) {
    int dd = rr + i * 16;
    half4_t o = {tile[c4 + 0][dd], tile[c4 + 1][dd], tile[c4 + 2][dd], tile[c4 + 3][dd]};
    *(half4_t*)(vt + ((size_t)(b * INNER_D + d0 + dd)) * S_LEN + s0 + c4) = o;
  }
}

// ---------------------------------------------------------------------------
// Block-cooperative LDS-staged MFMA attention (R6 structure, f16 q/k inputs,
// f16 hstate output). Grid 512, bh in low bits for XCD colocation.
// ---------------------------------------------------------------------------
#define KP 264   // K LDS row stride (halves)
#define VP 72    // V LDS row stride (halves)

__global__ __launch_bounds__(256, 2) void attn_blk_kernel(
    const _Float16* __restrict__ qh, const _Float16* __restrict__ khb,
    const _Float16* __restrict__ vt,
    const float* __restrict__ m_, const float* __restrict__ em,
    const float* __restrict__ rmax_, const float* __restrict__ maxd_,
    const float* __restrict__ mhln_w, const float* __restrict__ skip,
    const float* __restrict__ xc, const float* __restrict__ up,
    _Float16* __restrict__ hstate)
{
  __shared__ __align__(16) _Float16 Ks[64][KP];
  __shared__ __align__(16) _Float16 Vs[256][VP];
  __shared__ _Float16 plds[4][16][72];
  const int tid = threadIdx.x;
  const int lane = tid & 63, wid = tid >> 6;
  const int quad = lane >> 4, l16 = lane & 15;
  const int bh = blockIdx.x & 31;
  const int pp = blockIdx.x >> 5;
  const int sblk = 15 - pp;
  const int h = bh & 3, b = bh >> 2;
  _Float16 (*P)[72] = plds[wid];
  const float* rmaxp = rmax_ + (size_t)bh * S_LEN;
  const float* emp = em + (size_t)bh * S_LEN;
  const float* mp = m_ + (size_t)bh * S_LEN;
  const float* maxdp = maxd_ + (size_t)bh * S_LEN;
  const float scale = 0.0625f;  // DH^-0.5

  const _Float16* kg = khb + ((size_t)(b * S_LEN)) * INNER_D + h * DH_D;
  const _Float16* vg = vt + ((size_t)(b * INNER_D + h * DH_D)) * S_LEN;
  const int krow_s = tid >> 5;
  const int kcol_s = (tid & 31) * 8;
  const int vrow_s = tid >> 3;
  const int vcol_s = (tid & 7) * 8;

  const int ntile = sblk + 1;
  const int s0 = sblk * 64 + wid * 16;

  half8 kpre[8], vpre[8];
#pragma unroll
  for (int i = 0; i < 8; ++i) {
    kpre[i] = *(const half8*)(kg + (size_t)(i * 8 + krow_s) * INNER_D + kcol_s);
    vpre[i] = *(const half8*)(vg + (size_t)(i * 32 + vrow_s) * S_LEN + vcol_s);
  }

  half8 qf[8];
  const _Float16* qrow = qh + ((size_t)(b * S_LEN + s0 + l16)) * INNER_D + h * DH_D + quad * 8;
#pragma unroll
  for (int c = 0; c < 8; ++c) qf[c] = *(const half8*)(qrow + c * 32);

  v4f acc[16];
#pragma unroll
  for (int nc = 0; nc < 16; ++nc) acc[nc] = (v4f){0.f, 0.f, 0.f, 0.f};
  float rsum[4] = {0.f, 0.f, 0.f, 0.f};
  float rmax_row[4];
#pragma unroll
  for (int r = 0; r < 4; ++r) rmax_row[r] = rmaxp[s0 + quad * 4 + r];

  for (int tt = 0; tt < ntile; ++tt) {
    const int t0 = tt * 64;
    const bool last = (tt + 1 == ntile);
    __syncthreads();
#pragma unroll
    for (int i = 0; i < 8; ++i) {
      *(half8*)(&Ks[i * 8 + krow_s][kcol_s]) = kpre[i];
      *(half8*)(&Vs[i * 32 + vrow_s][vcol_s]) = vpre[i];
    }
    __syncthreads();
    if (!last) {
      const int tn = t0 + 64;
#pragma unroll
      for (int i = 0; i < 8; ++i) {
        kpre[i] = *(const half8*)(kg + (size_t)(tn + i * 8 + krow_s) * INNER_D + kcol_s);
        vpre[i] = *(const half8*)(vg + (size_t)(i * 32 + vrow_s) * S_LEN + tn + vcol_s);
      }
    }
    const bool diag = last;
    float rowfac[4];
    if (!diag) {
      const float rtile = rmaxp[t0 + 63];
#pragma unroll
      for (int r = 0; r < 4; ++r) rowfac[r] = __expf(rtile - rmax_row[r]);
    }
#pragma unroll
    for (int sub = 0; sub < 4; ++sub) {
      v4f sacc0 = (v4f){0.f, 0.f, 0.f, 0.f};
      v4f sacc1 = (v4f){0.f, 0.f, 0.f, 0.f};
#pragma unroll
      for (int c = 0; c < 4; ++c) {
        half8 kf0 = *(const half8*)(&Ks[sub * 16 + l16][c * 32 + quad * 8]);
        half8 kf1 = *(const half8*)(&Ks[sub * 16 + l16][(c + 4) * 32 + quad * 8]);
        sacc0 = __builtin_amdgcn_mfma_f32_16x16x32_f16(qf[c], kf0, sacc0, 0, 0, 0);
        sacc1 = __builtin_amdgcn_mfma_f32_16x16x32_f16(qf[c + 4], kf1, sacc1, 0, 0, 0);
      }
      v4f sacc = sacc0 + sacc1;
      const int t = t0 + sub * 16 + l16;
      if (diag) {
        const float mt = mp[t];
#pragma unroll
        for (int r = 0; r < 4; ++r) {
          const int srow = s0 + quad * 4 + r;
          float cc = (t <= srow) ? sacc[r] * scale * __expf(mt - rmax_row[r]) : 0.f;
          rsum[r] += cc;
          P[quad * 4 + r][sub * 16 + l16] = (_Float16)cc;
        }
      } else {
        const float emv = emp[t];
#pragma unroll
        for (int r = 0; r < 4; ++r) {
          float cc = sacc[r] * emv * rowfac[r];
          rsum[r] += cc;
          P[quad * 4 + r][sub * 16 + l16] = (_Float16)cc;
        }
      }
    }
    asm volatile("s_waitcnt lgkmcnt(0)" ::: "memory");
    half8 pf0 = *(const half8*)(&P[l16][quad * 8]);
    half8 pf1 = *(const half8*)(&P[l16][32 + quad * 8]);
#pragma unroll
    for (int nc = 0; nc < 16; ++nc) {
      half8 vf0 = *(const half8*)(&Vs[nc * 16 + l16][quad * 8]);
      half8 vf1 = *(const half8*)(&Vs[nc * 16 + l16][32 + quad * 8]);
      acc[nc] = __builtin_amdgcn_mfma_f32_16x16x32_f16(pf0, vf0, acc[nc], 0, 0, 0);
      acc[nc] = __builtin_amdgcn_mfma_f32_16x16x32_f16(pf1, vf1, acc[nc], 0, 0, 0);
    }
  }

  float inv[4];
#pragma unroll
  for (int r = 0; r < 4; ++r) {
    float rs = rsum[r];
    rs += __shfl_xor(rs, 1); rs += __shfl_xor(rs, 2);
    rs += __shfl_xor(rs, 4); rs += __shfl_xor(rs, 8);
    float md = maxdp[s0 + quad * 4 + r];
    float n = fmaxf(fabsf(rs), __expf(-md));
    inv[r] = 1.f / (n + 1e-6f);
  }
#pragma unroll
  for (int nc = 0; nc < 16; ++nc) {
#pragma unroll
    for (int r = 0; r < 4; ++r) acc[nc][r] *= inv[r];
  }
  float mean[4], rstd[4];
#pragma unroll
  for (int r = 0; r < 4; ++r) {
    float sm = 0.f;
#pragma unroll
    for (int nc = 0; nc < 16; ++nc) sm += acc[nc][r];
    sm += __shfl_xor(sm, 1); sm += __shfl_xor(sm, 2);
    sm += __shfl_xor(sm, 4); sm += __shfl_xor(sm, 8);
    mean[r] = sm * (1.f / DH_D);
  }
#pragma unroll
  for (int r = 0; r < 4; ++r) {
    float sq = 0.f;
#pragma unroll
    for (int nc = 0; nc < 16; ++nc) { float d = acc[nc][r] - mean[r]; sq += d * d; }
    sq += __shfl_xor(sq, 1); sq += __shfl_xor(sq, 2);
    sq += __shfl_xor(sq, 4); sq += __shfl_xor(sq, 8);
    rstd[r] = rsqrtf(sq * (1.f / DH_D) + 1e-5f);
  }
#pragma unroll
  for (int nc = 0; nc < 16; ++nc) {
    const int d = h * DH_D + nc * 16 + l16;
    const float w = mhln_w[d];
    const float sk = skip[d];
#pragma unroll
    for (int r = 0; r < 4; ++r) {
      const size_t row = (size_t)(b * S_LEN + s0 + quad * 4 + r);
      float xcv = xc[row * INNER_D + d];
      float zv = up[row * 2 * INNER_D + INNER_D + d];
      float sz = zv / (1.f + __expf(-zv));
      float o = ((acc[nc][r] - mean[r]) * rstd[r] * w + sk * xcv) * sz;
      hstate[row * INNER_D + d] = (_Float16)o;
    }
  }
}

// ---------------------------------------------------------------------------
extern "C" void kernel_launch(void* const* d_in, const int* in_sizes, int n_in,
                              void* d_out, int out_size, void* d_ws, size_t ws_size,
                              hipStream_t stream)
{
  const float* x      = (const float*)d_in[0];
  const float* W_in   = (const float*)d_in[1];
  const float* b_in   = (const float*)d_in[2];
  const float* ln1_w  = (const float*)d_in[3];
  const float* W_up   = (const float*)d_in[4];
  const float* conv_w = (const float*)d_in[5];
  const float* conv_b = (const float*)d_in[6];
  const float* Wq     = (const float*)d_in[7];
  const float* Wk     = (const float*)d_in[8];
  const float* Wv     = (const float*)d_in[9];
  const float* W_ig   = (const float*)d_in[10];
  const float* b_ig   = (const float*)d_in[11];
  const float* W_fg   = (const float*)d_in[12];
  const float* b_fg   = (const float*)d_in[13];
  const float* mhln_w = (const float*)d_in[14];
  const float* skip   = (const float*)d_in[15];
  const float* W_down = (const float*)d_in[16];
  const float* ln_post_w = (const float*)d_in[17];
  float* out = (float*)d_out;

  float* ws = (float*)d_ws;
  size_t o = 0;
  float* xp     = ws + o; o += (size_t)NROW * E_DIM;        // 4.19M
  float* hbuf   = ws + o; o += (size_t)NROW * E_DIM;        // gates, later y
  float* up     = ws + o; o += (size_t)NROW * 2 * INNER_D;  // 16.8M
  float* xc     = ws + o; o += (size_t)NROW * INNER_D;      // 8.39M
  _Float16* h16 = (_Float16*)(ws + o);
  size_t ho = 0;
  _Float16* xh      = h16 + ho; ho += (size_t)NROW * F_IN_D;        // 2.10M
  _Float16* WinH    = h16 + ho; ho += (size_t)E_DIM * F_IN_D;       // 131k
  _Float16* WupH    = h16 + ho; ho += (size_t)2 * INNER_D * E_DIM;  // 1.05M
  _Float16* WdownH  = h16 + ho; ho += (size_t)E_DIM * INNER_D;      // 524k
  _Float16* hh      = h16 + ho; ho += (size_t)NROW * E_DIM;         // 4.19M
  _Float16* qh      = h16 + ho; ho += (size_t)NROW * INNER_D;       // 8.39M
  _Float16* khb     = h16 + ho; ho += (size_t)NROW * INNER_D;
  _Float16* vhb     = h16 + ho; ho += (size_t)NROW * INNER_D;
  _Float16* vtb     = h16 + ho; ho += (size_t)NROW * INNER_D;
  _Float16* hstateH = h16 + ho; ho += (size_t)NROW * INNER_D;

  const int GSZ = B_SZ * NH_D * S_LEN;  // 32768
  float* igb   = hbuf;
  float* fgb   = hbuf + GSZ;
  float* mb    = hbuf + 2 * GSZ;
  float* rmaxb = hbuf + 3 * GSZ;
  float* maxdb = hbuf + 4 * GSZ;
  float* emb   = hbuf + 5 * GSZ;
  float* yb    = hbuf;   // down-GEMM output (gates dead by then)

  dim3 blk(256);
  const int nx = NROW * F_IN_D, nwi = E_DIM * F_IN_D,
            nwu = 2 * INNER_D * E_DIM, nwd = E_DIM * INNER_D;
  const int ntot = nx + nwi + nwu + nwd;
  cast4_kernel<<<(ntot / 4 + 255) / 256, blk, 0, stream>>>(
      x, W_in, W_up, W_down, xh, WinH, WupH, WdownH, nx, nwi, nwu, nwd);
  gemm_h16<<<dim3(E_DIM / GBN, NROW / GBM), blk, 0, stream>>>(
      xh, WinH, b_in, xp, NROW, E_DIM, F_IN_D);
  ln_mul_kernel<<<NROW, blk, 0, stream>>>(xp, ln1_w, hh);
  gemm_h16<<<dim3(2 * INNER_D / GBN, NROW / GBM), blk, 0, stream>>>(
      hh, WupH, nullptr, up, NROW, 2 * INNER_D, E_DIM);
  chg_kernel<<<NROW, blk, 0, stream>>>(
      up, conv_w, conv_b, Wq, Wk, Wv, W_ig, b_ig, W_fg, b_fg,
      xc, qh, khb, vhb, igb, fgb);
  scan_kernel<<<B_SZ * NH_D, blk, 0, stream>>>(igb, fgb, mb, rmaxb, maxdb, emb);
  vtrans_kernel<<<dim3(16, 16, 8), blk, 0, stream>>>(vhb, vtb);
  attn_blk_kernel<<<512, blk, 0, stream>>>(
      qh, khb, vtb, mb, emb, rmaxb, maxdb, mhln_w, skip, xc, up, hstateH);
  gemm_h16<<<dim3(E_DIM / GBN, NROW / GBM), blk, 0, stream>>>(
      hstateH, WdownH, nullptr, yb, NROW, E_DIM, INNER_D);
  final_ln_kernel<<<NROW, blk, 0, stream>>>(xp, yb, ln_post_w, out);
}

// Round 8
// 286.380 us; speedup vs baseline: 7.1239x; 1.1443x over previous
//
#include <hip/hip_runtime.h>

#define S_LEN 1024
#define B_SZ 8
#define F_IN_D 256
#define E_DIM 512
#define INNER_D 1024
#define NH_D 4
#define DH_D 256
#define NROW (B_SZ * S_LEN)   // 8192

typedef _Float16 half8 __attribute__((ext_vector_type(8)));
typedef _Float16 half4_t __attribute__((ext_vector_type(4)));
typedef float v4f __attribute__((ext_vector_type(4)));

// ---------------------------------------------------------------------------
// Cast 4 f32 buffers to f16 in one pass (x, W_in, W_up, W_down).
// ---------------------------------------------------------------------------
__global__ __launch_bounds__(256) void cast4_kernel(
    const float* __restrict__ s0, const float* __restrict__ s1,
    const float* __restrict__ s2, const float* __restrict__ s3,
    _Float16* __restrict__ d0, _Float16* __restrict__ d1,
    _Float16* __restrict__ d2, _Float16* __restrict__ d3,
    int n0, int n1, int n2, int n3)
{
  int i = (blockIdx.x * 256 + threadIdx.x) * 4;
  const float* s; _Float16* d; int off;
  if (i < n0)                { s = s0; d = d0; off = i; }
  else if (i < n0 + n1)      { s = s1; d = d1; off = i - n0; }
  else if (i < n0 + n1 + n2) { s = s2; d = d2; off = i - n0 - n1; }
  else if (i < n0 + n1 + n2 + n3) { s = s3; d = d3; off = i - n0 - n1 - n2; }
  else return;
  float4 v = *(const float4*)(s + off);
  half4_t o = {(_Float16)v.x, (_Float16)v.y, (_Float16)v.z, (_Float16)v.w};
  *(half4_t*)(d + off) = o;
}

// ---------------------------------------------------------------------------
// Pure-f16 MFMA NT GEMM: C[M,N] = A[M,K] @ B[N,K]^T (+ bias), C f32.
// ---------------------------------------------------------------------------
#define GBM 128
#define GBN 128
#define GBK 32
#define LDKG (GBK + 8)

__global__ __launch_bounds__(256) void gemm_h16(
    const _Float16* __restrict__ A, const _Float16* __restrict__ B,
    const float* __restrict__ bias, float* __restrict__ C,
    int M, int N, int K)
{
  __shared__ __align__(16) _Float16 As[GBM][LDKG];
  __shared__ __align__(16) _Float16 Bs[GBN][LDKG];
  const int tid = threadIdx.x;
  const int lane = tid & 63, w = tid >> 6;
  const int wr = w >> 1, wc = w & 1;
  const int quad = lane >> 4, l16 = lane & 15;
  const int bm = blockIdx.y * GBM, bn = blockIdx.x * GBN;
  const int srow = tid >> 1;
  const int scol = (tid & 1) * 16;

  v4f acc[4][4];
#pragma unroll
  for (int i = 0; i < 4; ++i)
#pragma unroll
    for (int j = 0; j < 4; ++j) acc[i][j] = (v4f){0.f, 0.f, 0.f, 0.f};

  const _Float16* Ap = A + (size_t)(bm + srow) * K + scol;
  const _Float16* Bp = B + (size_t)(bn + srow) * K + scol;
  half8 a0 = *(const half8*)(Ap);
  half8 a1 = *(const half8*)(Ap + 8);
  half8 b0 = *(const half8*)(Bp);
  half8 b1 = *(const half8*)(Bp + 8);

  for (int k0 = 0; k0 < K; k0 += GBK) {
    __syncthreads();
    *(half8*)(&As[srow][scol]) = a0;
    *(half8*)(&As[srow][scol + 8]) = a1;
    *(half8*)(&Bs[srow][scol]) = b0;
    *(half8*)(&Bs[srow][scol + 8]) = b1;
    __syncthreads();
    if (k0 + GBK < K) {
      const int kn = k0 + GBK;
      a0 = *(const half8*)(Ap + kn);
      a1 = *(const half8*)(Ap + kn + 8);
      b0 = *(const half8*)(Bp + kn);
      b1 = *(const half8*)(Bp + kn + 8);
    }
    half8 af[4], bf[4];
#pragma unroll
    for (int i = 0; i < 4; ++i)
      af[i] = *(const half8*)(&As[wr * 64 + i * 16 + l16][quad * 8]);
#pragma unroll
    for (int j = 0; j < 4; ++j)
      bf[j] = *(const half8*)(&Bs[wc * 64 + j * 16 + l16][quad * 8]);
#pragma unroll
    for (int i = 0; i < 4; ++i)
#pragma unroll
      for (int j = 0; j < 4; ++j)
        acc[i][j] = __builtin_amdgcn_mfma_f32_16x16x32_f16(af[i], bf[j], acc[i][j], 0, 0, 0);
  }

#pragma unroll
  for (int j = 0; j < 4; ++j) {
    const int col = bn + wc * 64 + j * 16 + l16;
    const float bv = bias ? bias[col] : 0.f;
#pragma unroll
    for (int i = 0; i < 4; ++i) {
      const int row0 = bm + wr * 64 + i * 16 + quad * 4;
#pragma unroll
      for (int r = 0; r < 4; ++r)
        C[(size_t)(row0 + r) * N + col] = acc[i][j][r] + bv;
    }
  }
}

// ---------------------------------------------------------------------------
// Up-projection GEMM: same core; epilogue writes x_m half as f16 (xmh) and
// z half as silu(z) f16 (szb), both with row stride 1024.
// ---------------------------------------------------------------------------
__global__ __launch_bounds__(256) void gemm_h16_up(
    const _Float16* __restrict__ A, const _Float16* __restrict__ B,
    _Float16* __restrict__ xmh, _Float16* __restrict__ szb,
    int M, int N, int K)
{
  __shared__ __align__(16) _Float16 As[GBM][LDKG];
  __shared__ __align__(16) _Float16 Bs[GBN][LDKG];
  const int tid = threadIdx.x;
  const int lane = tid & 63, w = tid >> 6;
  const int wr = w >> 1, wc = w & 1;
  const int quad = lane >> 4, l16 = lane & 15;
  const int bm = blockIdx.y * GBM, bn = blockIdx.x * GBN;
  const int srow = tid >> 1;
  const int scol = (tid & 1) * 16;

  v4f acc[4][4];
#pragma unroll
  for (int i = 0; i < 4; ++i)
#pragma unroll
    for (int j = 0; j < 4; ++j) acc[i][j] = (v4f){0.f, 0.f, 0.f, 0.f};

  const _Float16* Ap = A + (size_t)(bm + srow) * K + scol;
  const _Float16* Bp = B + (size_t)(bn + srow) * K + scol;
  half8 a0 = *(const half8*)(Ap);
  half8 a1 = *(const half8*)(Ap + 8);
  half8 b0 = *(const half8*)(Bp);
  half8 b1 = *(const half8*)(Bp + 8);

  for (int k0 = 0; k0 < K; k0 += GBK) {
    __syncthreads();
    *(half8*)(&As[srow][scol]) = a0;
    *(half8*)(&As[srow][scol + 8]) = a1;
    *(half8*)(&Bs[srow][scol]) = b0;
    *(half8*)(&Bs[srow][scol + 8]) = b1;
    __syncthreads();
    if (k0 + GBK < K) {
      const int kn = k0 + GBK;
      a0 = *(const half8*)(Ap + kn);
      a1 = *(const half8*)(Ap + kn + 8);
      b0 = *(const half8*)(Bp + kn);
      b1 = *(const half8*)(Bp + kn + 8);
    }
    half8 af[4], bf[4];
#pragma unroll
    for (int i = 0; i < 4; ++i)
      af[i] = *(const half8*)(&As[wr * 64 + i * 16 + l16][quad * 8]);
#pragma unroll
    for (int j = 0; j < 4; ++j)
      bf[j] = *(const half8*)(&Bs[wc * 64 + j * 16 + l16][quad * 8]);
#pragma unroll
    for (int i = 0; i < 4; ++i)
#pragma unroll
      for (int j = 0; j < 4; ++j)
        acc[i][j] = __builtin_amdgcn_mfma_f32_16x16x32_f16(af[i], bf[j], acc[i][j], 0, 0, 0);
  }

  const bool zhalf = (bn >= INNER_D);   // tile-uniform
#pragma unroll
  for (int j = 0; j < 4; ++j) {
    const int col = bn + wc * 64 + j * 16 + l16;
    const int colm = col & (INNER_D - 1);
#pragma unroll
    for (int i = 0; i < 4; ++i) {
      const int row0 = bm + wr * 64 + i * 16 + quad * 4;
#pragma unroll
      for (int r = 0; r < 4; ++r) {
        float a = acc[i][j][r];
        if (zhalf) {
          float s = a / (1.f + __expf(-a));
          szb[(size_t)(row0 + r) * INNER_D + colm] = (_Float16)s;
        } else {
          xmh[(size_t)(row0 + r) * INNER_D + colm] = (_Float16)a;
        }
      }
    }
  }
}

// ---------------------------------------------------------------------------
__device__ __forceinline__ float block_sum4(float v, float* red, int tid) {
#pragma unroll
  for (int off = 32; off; off >>= 1) v += __shfl_xor(v, off);
  if ((tid & 63) == 0) red[tid >> 6] = v;
  __syncthreads();
  float t = red[0] + red[1] + red[2] + red[3];
  __syncthreads();
  return t;
}

__global__ __launch_bounds__(256) void ln_mul_kernel(
    const float* __restrict__ in, const float* __restrict__ w,
    _Float16* __restrict__ out)
{
  __shared__ float red[4];
  const int row = blockIdx.x;
  const int tid = threadIdx.x;
  const float* p = in + (size_t)row * E_DIM;
  float v0 = p[tid], v1 = p[tid + 256];
  float mean = block_sum4(v0 + v1, red, tid) * (1.f / E_DIM);
  float d0 = v0 - mean, d1 = v1 - mean;
  float var = block_sum4(d0 * d0 + d1 * d1, red, tid) * (1.f / E_DIM);
  float rstd = rsqrtf(var + 1e-5f);
  out[(size_t)row * E_DIM + tid] = (_Float16)(d0 * rstd * w[tid]);
  out[(size_t)row * E_DIM + tid + 256] = (_Float16)(d1 * rstd * w[tid + 256]);
}

__global__ __launch_bounds__(256) void final_ln_kernel(
    const float* __restrict__ res, const float* __restrict__ y,
    const float* __restrict__ w, float* __restrict__ out)
{
  __shared__ float red[4];
  const int row = blockIdx.x;
  const int tid = threadIdx.x;
  const size_t base = (size_t)row * E_DIM;
  float v0 = res[base + tid] + y[base + tid];
  float v1 = res[base + tid + 256] + y[base + tid + 256];
  float mean = block_sum4(v0 + v1, red, tid) * (1.f / E_DIM);
  float d0 = v0 - mean, d1 = v1 - mean;
  float var = block_sum4(d0 * d0 + d1 * d1, red, tid) * (1.f / E_DIM);
  float rstd = rsqrtf(var + 1e-5f);
  out[base + tid] = d0 * rstd * w[tid];
  out[base + tid + 256] = d1 * rstd * w[tid + 256];
}

// ---------------------------------------------------------------------------
// Fused conv+silu + headwise q/k/v + gates, 4 rows per block (weight reuse).
// Reads xmh f16; writes xch/q/k/v f16, ig/fg f32.
// ---------------------------------------------------------------------------
__global__ __launch_bounds__(256) void chg_kernel(
    const _Float16* __restrict__ xm, const float* __restrict__ cw,
    const float* __restrict__ cb,
    const float* __restrict__ Wq, const float* __restrict__ Wk,
    const float* __restrict__ Wv,
    const float* __restrict__ Wig, const float* __restrict__ big,
    const float* __restrict__ Wfg, const float* __restrict__ bfg,
    _Float16* __restrict__ xch, _Float16* __restrict__ qh,
    _Float16* __restrict__ khb, _Float16* __restrict__ vhb,
    float* __restrict__ ig, float* __restrict__ fg)
{
  __shared__ float red[4][32];
  const int tid = threadIdx.x;
  const int lane = tid & 63, wid = tid >> 6;
  const int row0 = blockIdx.x * 4;
  const int sl0 = row0 & (S_LEN - 1);
  const int c = tid * 4;

  // taps t[j][comp]: row row0 + (j-3), zero outside batch start
  float t[7][4];
#pragma unroll
  for (int j = 0; j < 7; ++j) {
    const int off = j - 3;
    if (sl0 + off < 0) {
      t[j][0] = t[j][1] = t[j][2] = t[j][3] = 0.f;
    } else {
      half4_t hv = *(const half4_t*)(xm + (size_t)(row0 + off) * INNER_D + c);
      t[j][0] = (float)hv.x; t[j][1] = (float)hv.y;
      t[j][2] = (float)hv.z; t[j][3] = (float)hv.w;
    }
  }
  float wct[4][4];
#pragma unroll
  for (int j = 0; j < 4; ++j) {
    float4 wc4 = *(const float4*)(cw + (c + j) * 4);
    wct[j][0] = wc4.x; wct[j][1] = wc4.y; wct[j][2] = wc4.z; wct[j][3] = wc4.w;
  }
  float4 cb4 = *(const float4*)(cb + c);
  const float cbs[4] = {cb4.x, cb4.y, cb4.z, cb4.w};
  float wqm[16], wkm[16], wvm[16];
#pragma unroll
  for (int i = 0; i < 4; ++i) {
    float4 a = *(const float4*)(Wq + tid * 16 + i * 4);
    float4 bq = *(const float4*)(Wk + tid * 16 + i * 4);
    float4 cq = *(const float4*)(Wv + tid * 16 + i * 4);
    wqm[i * 4] = a.x; wqm[i * 4 + 1] = a.y; wqm[i * 4 + 2] = a.z; wqm[i * 4 + 3] = a.w;
    wkm[i * 4] = bq.x; wkm[i * 4 + 1] = bq.y; wkm[i * 4 + 2] = bq.z; wkm[i * 4 + 3] = bq.w;
    wvm[i * 4] = cq.x; wvm[i * 4 + 1] = cq.y; wvm[i * 4 + 2] = cq.z; wvm[i * 4 + 3] = cq.w;
  }

  float q4[4][4], k4[4][4], v4m[4][4];
#pragma unroll
  for (int r = 0; r < 4; ++r) {
    float xc4[4];
#pragma unroll
    for (int j = 0; j < 4; ++j) {
      float a = cbs[j] + wct[j][0] * t[r][j] + wct[j][1] * t[r + 1][j]
                       + wct[j][2] * t[r + 2][j] + wct[j][3] * t[r + 3][j];
      xc4[j] = a / (1.f + __expf(-a));
    }
#pragma unroll
    for (int i = 0; i < 4; ++i) {
      q4[r][i] = wqm[i * 4] * xc4[0] + wqm[i * 4 + 1] * xc4[1]
               + wqm[i * 4 + 2] * xc4[2] + wqm[i * 4 + 3] * xc4[3];
      k4[r][i] = wkm[i * 4] * xc4[0] + wkm[i * 4 + 1] * xc4[1]
               + wkm[i * 4 + 2] * xc4[2] + wkm[i * 4 + 3] * xc4[3];
      v4m[r][i] = wvm[i * 4] * t[r + 3][0] + wvm[i * 4 + 1] * t[r + 3][1]
                + wvm[i * 4 + 2] * t[r + 3][2] + wvm[i * 4 + 3] * t[r + 3][3];
    }
    const size_t base = (size_t)(row0 + r) * INNER_D + c;
    half4_t xo = {(_Float16)xc4[0], (_Float16)xc4[1], (_Float16)xc4[2], (_Float16)xc4[3]};
    half4_t qo = {(_Float16)q4[r][0], (_Float16)q4[r][1], (_Float16)q4[r][2], (_Float16)q4[r][3]};
    half4_t ko = {(_Float16)k4[r][0], (_Float16)k4[r][1], (_Float16)k4[r][2], (_Float16)k4[r][3]};
    half4_t vo = {(_Float16)v4m[r][0], (_Float16)v4m[r][1], (_Float16)v4m[r][2], (_Float16)v4m[r][3]};
    *(half4_t*)(xch + base) = xo;
    *(half4_t*)(qh + base) = qo;
    *(half4_t*)(khb + base) = ko;
    *(half4_t*)(vhb + base) = vo;
  }

  // gates: 8 dots x 4 rows, weights loaded once
  float vals[32];
#pragma unroll
  for (int g = 0; g < 8; ++g) {
    const float* wb = (g < 4 ? Wig : Wfg) + (g & 3) * 3072 + c;
    float4 w1 = *(const float4*)(wb);
    float4 w2 = *(const float4*)(wb + 1024);
    float4 w3 = *(const float4*)(wb + 2048);
#pragma unroll
    for (int r = 0; r < 4; ++r) {
      vals[g * 4 + r] =
          q4[r][0] * w1.x + q4[r][1] * w1.y + q4[r][2] * w1.z + q4[r][3] * w1.w
        + k4[r][0] * w2.x + k4[r][1] * w2.y + k4[r][2] * w2.z + k4[r][3] * w2.w
        + v4m[r][0] * w3.x + v4m[r][1] * w3.y + v4m[r][2] * w3.z + v4m[r][3] * w3.w;
    }
  }
#pragma unroll
  for (int i = 0; i < 32; ++i) {
    float x = vals[i];
#pragma unroll
    for (int off = 32; off; off >>= 1) x += __shfl_xor(x, off);
    vals[i] = x;
  }
  if (lane == 0) {
#pragma unroll
    for (int i = 0; i < 32; ++i) red[wid][i] = vals[i];
  }
  __syncthreads();
  if (tid < 32) {
    float sm = red[0][tid] + red[1][tid] + red[2][tid] + red[3][tid];
    const int g = tid >> 2, r = tid & 3;
    const int h = g & 3;
    const int b = row0 >> 10;
    const size_t oidx = (size_t)(b * NH_D + h) * S_LEN + sl0 + r;
    if (g < 4) ig[oidx] = sm + big[h];
    else       fg[oidx] = sm + bfg[h];
  }
}

// ---------------------------------------------------------------------------
__device__ __forceinline__ float logsigf(float x) {
  return fminf(x, 0.f) - log1pf(__expf(-fabsf(x)));
}

__global__ __launch_bounds__(256) void scan_kernel(
    const float* __restrict__ ig, const float* __restrict__ fg,
    float* __restrict__ m_, float* __restrict__ rmax_, float* __restrict__ maxd_,
    float* __restrict__ em_)
{
  __shared__ float sc[256];
  const int bh = blockIdx.x;
  const int tid = threadIdx.x;
  const size_t base = (size_t)bh * S_LEN + tid * 4;
  float4 f4 = *(const float4*)(fg + base);
  float4 i4 = *(const float4*)(ig + base);
  float l0 = logsigf(f4.x), l1 = logsigf(f4.y), l2 = logsigf(f4.z), l3 = logsigf(f4.w);
  float p0 = l0, p1 = p0 + l1, p2 = p1 + l2, p3 = p2 + l3;
  sc[tid] = p3;
  __syncthreads();
  for (int off = 1; off < 256; off <<= 1) {
    float o = (tid >= off) ? sc[tid - off] : 0.f;
    __syncthreads();
    sc[tid] += o;
    __syncthreads();
  }
  float aoff = (tid == 0) ? 0.f : sc[tid - 1];
  __syncthreads();
  float a0 = aoff + p0, a1 = aoff + p1, a2 = aoff + p2, a3 = aoff + p3;
  float m0 = i4.x - a0, m1 = i4.y - a1, m2 = i4.z - a2, m3 = i4.w - a3;
  float x0 = m0, x1 = fmaxf(x0, m1), x2 = fmaxf(x1, m2), x3 = fmaxf(x2, m3);
  sc[tid] = x3;
  __syncthreads();
  for (int off = 1; off < 256; off <<= 1) {
    float o = (tid >= off) ? sc[tid - off] : -1e30f;
    __syncthreads();
    sc[tid] = fmaxf(sc[tid], o);
    __syncthreads();
  }
  float moff = (tid == 0) ? -1e30f : sc[tid - 1];
  float tmax = sc[tid | 15];
  float r0 = fmaxf(moff, x0), r1 = fmaxf(moff, x1), r2 = fmaxf(moff, x2), r3 = fmaxf(moff, x3);
  const float scale = 0.0625f;
  float4 mo = {m0, m1, m2, m3};
  float4 ro = {r0, r1, r2, r3};
  float4 dd = {a0 + r0, a1 + r1, a2 + r2, a3 + r3};
  float4 eo = {scale * __expf(m0 - tmax), scale * __expf(m1 - tmax),
               scale * __expf(m2 - tmax), scale * __expf(m3 - tmax)};
  *(float4*)(m_ + base) = mo;
  *(float4*)(rmax_ + base) = ro;
  *(float4*)(maxd_ + base) = dd;
  *(float4*)(em_ + base) = eo;
}

// ---------------------------------------------------------------------------
// Transpose v f16 [b][s][d] -> f16 vt [b][d][s]
// ---------------------------------------------------------------------------
__global__ __launch_bounds__(256) void vtrans_kernel(
    const _Float16* __restrict__ vb, _Float16* __restrict__ vt)
{
  __shared__ _Float16 tile[64][68];
  const int b = blockIdx.z, dt = blockIdx.x, st = blockIdx.y;
  const int c4 = (threadIdx.x & 15) * 4, rr = threadIdx.x >> 4;
  const int s0 = st * 64, d0 = dt * 64;
#pragma unroll
  for (int i = 0; i < 4; ++i) {
    int r = rr + i * 16;
    half4_t v = *(const half4_t*)(vb + ((size_t)(b * S_LEN + s0 + r)) * INNER_D + d0 + c4);
    tile[r][c4 + 0] = v.x; tile[r][c4 + 1] = v.y;
    tile[r][c4 + 2] = v.z; tile[r][c4 + 3] = v.w;
  }
  __syncthreads();
#pragma unroll
  for (int i = 0; i < 4; ++i) {
    int dd = rr + i * 16;
    half4_t o = {tile[c4 + 0][dd], tile[c4 + 1][dd], tile[c4 + 2][dd], tile[c4 + 3][dd]};
    *(half4_t*)(vt + ((size_t)(b * INNER_D + d0 + dd)) * S_LEN + s0 + c4) = o;
  }
}

// ---------------------------------------------------------------------------
// Block-cooperative LDS-staged MFMA attention (f16 I/O everywhere).
// ---------------------------------------------------------------------------
#define KP 264
#define VP 72

__global__ __launch_bounds__(256, 2) void attn_blk_kernel(
    const _Float16* __restrict__ qh, const _Float16* __restrict__ khb,
    const _Float16* __restrict__ vt,
    const float* __restrict__ m_, const float* __restrict__ em,
    const float* __restrict__ rmax_, const float* __restrict__ maxd_,
    const float* __restrict__ mhln_w, const float* __restrict__ skip,
    const _Float16* __restrict__ xch, const _Float16* __restrict__ szb,
    _Float16* __restrict__ hstate)
{
  __shared__ __align__(16) _Float16 Ks[64][KP];
  __shared__ __align__(16) _Float16 Vs[256][VP];
  __shared__ _Float16 plds[4][16][72];
  const int tid = threadIdx.x;
  const int lane = tid & 63, wid = tid >> 6;
  const int quad = lane >> 4, l16 = lane & 15;
  const int bh = blockIdx.x & 31;
  const int pp = blockIdx.x >> 5;
  const int sblk = 15 - pp;
  const int h = bh & 3, b = bh >> 2;
  _Float16 (*P)[72] = plds[wid];
  const float* rmaxp = rmax_ + (size_t)bh * S_LEN;
  const float* emp = em + (size_t)bh * S_LEN;
  const float* mp = m_ + (size_t)bh * S_LEN;
  const float* maxdp = maxd_ + (size_t)bh * S_LEN;
  const float scale = 0.0625f;

  const _Float16* kg = khb + ((size_t)(b * S_LEN)) * INNER_D + h * DH_D;
  const _Float16* vg = vt + ((size_t)(b * INNER_D + h * DH_D)) * S_LEN;
  const int krow_s = tid >> 5;
  const int kcol_s = (tid & 31) * 8;
  const int vrow_s = tid >> 3;
  const int vcol_s = (tid & 7) * 8;

  const int ntile = sblk + 1;
  const int s0 = sblk * 64 + wid * 16;

  half8 kpre[8], vpre[8];
#pragma unroll
  for (int i = 0; i < 8; ++i) {
    kpre[i] = *(const half8*)(kg + (size_t)(i * 8 + krow_s) * INNER_D + kcol_s);
    vpre[i] = *(const half8*)(vg + (size_t)(i * 32 + vrow_s) * S_LEN + vcol_s);
  }

  half8 qf[8];
  const _Float16* qrow = qh + ((size_t)(b * S_LEN + s0 + l16)) * INNER_D + h * DH_D + quad * 8;
#pragma unroll
  for (int c = 0; c < 8; ++c) qf[c] = *(const half8*)(qrow + c * 32);

  v4f acc[16];
#pragma unroll
  for (int nc = 0; nc < 16; ++nc) acc[nc] = (v4f){0.f, 0.f, 0.f, 0.f};
  float rsum[4] = {0.f, 0.f, 0.f, 0.f};
  float rmax_row[4];
#pragma unroll
  for (int r = 0; r < 4; ++r) rmax_row[r] = rmaxp[s0 + quad * 4 + r];

  for (int tt = 0; tt < ntile; ++tt) {
    const int t0 = tt * 64;
    const bool last = (tt + 1 == ntile);
    __syncthreads();
#pragma unroll
    for (int i = 0; i < 8; ++i) {
      *(half8*)(&Ks[i * 8 + krow_s][kcol_s]) = kpre[i];
      *(half8*)(&Vs[i * 32 + vrow_s][vcol_s]) = vpre[i];
    }
    __syncthreads();
    if (!last) {
      const int tn = t0 + 64;
#pragma unroll
      for (int i = 0; i < 8; ++i) {
        kpre[i] = *(const half8*)(kg + (size_t)(tn + i * 8 + krow_s) * INNER_D + kcol_s);
        vpre[i] = *(const half8*)(vg + (size_t)(i * 32 + vrow_s) * S_LEN + tn + vcol_s);
      }
    }
    const bool diag = last;
    float rowfac[4];
    if (!diag) {
      const float rtile = rmaxp[t0 + 63];
#pragma unroll
      for (int r = 0; r < 4; ++r) rowfac[r] = __expf(rtile - rmax_row[r]);
    }
#pragma unroll
    for (int sub = 0; sub < 4; ++sub) {
      v4f sacc0 = (v4f){0.f, 0.f, 0.f, 0.f};
      v4f sacc1 = (v4f){0.f, 0.f, 0.f, 0.f};
#pragma unroll
      for (int c = 0; c < 4; ++c) {
        half8 kf0 = *(const half8*)(&Ks[sub * 16 + l16][c * 32 + quad * 8]);
        half8 kf1 = *(const half8*)(&Ks[sub * 16 + l16][(c + 4) * 32 + quad * 8]);
        sacc0 = __builtin_amdgcn_mfma_f32_16x16x32_f16(qf[c], kf0, sacc0, 0, 0, 0);
        sacc1 = __builtin_amdgcn_mfma_f32_16x16x32_f16(qf[c + 4], kf1, sacc1, 0, 0, 0);
      }
      v4f sacc = sacc0 + sacc1;
      const int t = t0 + sub * 16 + l16;
      if (diag) {
        const float mt = mp[t];
#pragma unroll
        for (int r = 0; r < 4; ++r) {
          const int srow = s0 + quad * 4 + r;
          float cc = (t <= srow) ? sacc[r] * scale * __expf(mt - rmax_row[r]) : 0.f;
          rsum[r] += cc;
          P[quad * 4 + r][sub * 16 + l16] = (_Float16)cc;
        }
      } else {
        const float emv = emp[t];
#pragma unroll
        for (int r = 0; r < 4; ++r) {
          float cc = sacc[r] * emv * rowfac[r];
          rsum[r] += cc;
          P[quad * 4 + r][sub * 16 + l16] = (_Float16)cc;
        }
      }
    }
    asm volatile("s_waitcnt lgkmcnt(0)" ::: "memory");
    half8 pf0 = *(const half8*)(&P[l16][quad * 8]);
    half8 pf1 = *(const half8*)(&P[l16][32 + quad * 8]);
#pragma unroll
    for (int nc = 0; nc < 16; ++nc) {
      half8 vf0 = *(const half8*)(&Vs[nc * 16 + l16][quad * 8]);
      half8 vf1 = *(const half8*)(&Vs[nc * 16 + l16][32 + quad * 8]);
      acc[nc] = __builtin_amdgcn_mfma_f32_16x16x32_f16(pf0, vf0, acc[nc], 0, 0, 0);
      acc[nc] = __builtin_amdgcn_mfma_f32_16x16x32_f16(pf1, vf1, acc[nc], 0, 0, 0);
    }
  }

  float inv[4];
#pragma unroll
  for (int r = 0; r < 4; ++r) {
    float rs = rsum[r];
    rs += __shfl_xor(rs, 1); rs += __shfl_xor(rs, 2);
    rs += __shfl_xor(rs, 4); rs += __shfl_xor(rs, 8);
    float md = maxdp[s0 + quad * 4 + r];
    float n = fmaxf(fabsf(rs), __expf(-md));
    inv[r] = 1.f / (n + 1e-6f);
  }
#pragma unroll
  for (int nc = 0; nc < 16; ++nc) {
#pragma unroll
    for (int r = 0; r < 4; ++r) acc[nc][r] *= inv[r];
  }
  float mean[4], rstd[4];
#pragma unroll
  for (int r = 0; r < 4; ++r) {
    float sm = 0.f;
#pragma unroll
    for (int nc = 0; nc < 16; ++nc) sm += acc[nc][r];
    sm += __shfl_xor(sm, 1); sm += __shfl_xor(sm, 2);
    sm += __shfl_xor(sm, 4); sm += __shfl_xor(sm, 8);
    mean[r] = sm * (1.f / DH_D);
  }
#pragma unroll
  for (int r = 0; r < 4; ++r) {
    float sq = 0.f;
#pragma unroll
    for (int nc = 0; nc < 16; ++nc) { float d = acc[nc][r] - mean[r]; sq += d * d; }
    sq += __shfl_xor(sq, 1); sq += __shfl_xor(sq, 2);
    sq += __shfl_xor(sq, 4); sq += __shfl_xor(sq, 8);
    rstd[r] = rsqrtf(sq * (1.f / DH_D) + 1e-5f);
  }
#pragma unroll
  for (int nc = 0; nc < 16; ++nc) {
    const int d = h * DH_D + nc * 16 + l16;
    const float w = mhln_w[d];
    const float sk = skip[d];
#pragma unroll
    for (int r = 0; r < 4; ++r) {
      const size_t row = (size_t)(b * S_LEN + s0 + quad * 4 + r);
      float xcv = (float)xch[row * INNER_D + d];
      float sz = (float)szb[row * INNER_D + d];
      float o = ((acc[nc][r] - mean[r]) * rstd[r] * w + sk * xcv) * sz;
      hstate[row * INNER_D + d] = (_Float16)o;
    }
  }
}

// ---------------------------------------------------------------------------
extern "C" void kernel_launch(void* const* d_in, const int* in_sizes, int n_in,
                              void* d_out, int out_size, void* d_ws, size_t ws_size,
                              hipStream_t stream)
{
  const float* x      = (const float*)d_in[0];
  const float* W_in   = (const float*)d_in[1];
  const float* b_in   = (const float*)d_in[2];
  const float* ln1_w  = (const float*)d_in[3];
  const float* W_up   = (const float*)d_in[4];
  const float* conv_w = (const float*)d_in[5];
  const float* conv_b = (const float*)d_in[6];
  const float* Wq     = (const float*)d_in[7];
  const float* Wk     = (const float*)d_in[8];
  const float* Wv     = (const float*)d_in[9];
  const float* W_ig   = (const float*)d_in[10];
  const float* b_ig   = (const float*)d_in[11];
  const float* W_fg   = (const float*)d_in[12];
  const float* b_fg   = (const float*)d_in[13];
  const float* mhln_w = (const float*)d_in[14];
  const float* skip   = (const float*)d_in[15];
  const float* W_down = (const float*)d_in[16];
  const float* ln_post_w = (const float*)d_in[17];
  float* out = (float*)d_out;

  float* ws = (float*)d_ws;
  size_t o = 0;
  float* xp     = ws + o; o += (size_t)NROW * E_DIM;   // residual f32
  float* hbuf   = ws + o; o += (size_t)NROW * E_DIM;   // gates, later y
  _Float16* h16 = (_Float16*)(ws + o);
  size_t ho = 0;
  _Float16* xh      = h16 + ho; ho += (size_t)NROW * F_IN_D;
  _Float16* WinH    = h16 + ho; ho += (size_t)E_DIM * F_IN_D;
  _Float16* WupH    = h16 + ho; ho += (size_t)2 * INNER_D * E_DIM;
  _Float16* WdownH  = h16 + ho; ho += (size_t)E_DIM * INNER_D;
  _Float16* hh      = h16 + ho; ho += (size_t)NROW * E_DIM;
  _Float16* xmh     = h16 + ho; ho += (size_t)NROW * INNER_D;
  _Float16* szb     = h16 + ho; ho += (size_t)NROW * INNER_D;
  _Float16* xch     = h16 + ho; ho += (size_t)NROW * INNER_D;
  _Float16* qh      = h16 + ho; ho += (size_t)NROW * INNER_D;
  _Float16* khb     = h16 + ho; ho += (size_t)NROW * INNER_D;
  _Float16* vhb     = h16 + ho; ho += (size_t)NROW * INNER_D;
  _Float16* vtb     = h16 + ho; ho += (size_t)NROW * INNER_D;
  _Float16* hstateH = h16 + ho; ho += (size_t)NROW * INNER_D;

  const int GSZ = B_SZ * NH_D * S_LEN;  // 32768
  float* igb   = hbuf;
  float* fgb   = hbuf + GSZ;
  float* mb    = hbuf + 2 * GSZ;
  float* rmaxb = hbuf + 3 * GSZ;
  float* maxdb = hbuf + 4 * GSZ;
  float* emb   = hbuf + 5 * GSZ;
  float* yb    = hbuf;   // down-GEMM output (gates dead by then)

  dim3 blk(256);
  const int nx = NROW * F_IN_D, nwi = E_DIM * F_IN_D,
            nwu = 2 * INNER_D * E_DIM, nwd = E_DIM * INNER_D;
  const int ntot = nx + nwi + nwu + nwd;
  cast4_kernel<<<(ntot / 4 + 255) / 256, blk, 0, stream>>>(
      x, W_in, W_up, W_down, xh, WinH, WupH, WdownH, nx, nwi, nwu, nwd);
  gemm_h16<<<dim3(E_DIM / GBN, NROW / GBM), blk, 0, stream>>>(
      xh, WinH, b_in, xp, NROW, E_DIM, F_IN_D);
  ln_mul_kernel<<<NROW, blk, 0, stream>>>(xp, ln1_w, hh);
  gemm_h16_up<<<dim3(2 * INNER_D / GBN, NROW / GBM), blk, 0, stream>>>(
      hh, WupH, xmh, szb, NROW, 2 * INNER_D, E_DIM);
  chg_kernel<<<NROW / 4, blk, 0, stream>>>(
      xmh, conv_w, conv_b, Wq, Wk, Wv, W_ig, b_ig, W_fg, b_fg,
      xch, qh, khb, vhb, igb, fgb);
  scan_kernel<<<B_SZ * NH_D, blk, 0, stream>>>(igb, fgb, mb, rmaxb, maxdb, emb);
  vtrans_kernel<<<dim3(16, 16, 8), blk, 0, stream>>>(vhb, vtb);
  attn_blk_kernel<<<512, blk, 0, stream>>>(
      qh, khb, vtb, mb, emb, rmaxb, maxdb, mhln_w, skip, xch, szb, hstateH);
  gemm_h16<<<dim3(E_DIM / GBN, NROW / GBM), blk, 0, stream>>>(
      hstateH, WdownH, nullptr, yb, NROW, E_DIM, INNER_D);
  final_ln_kernel<<<NROW, blk, 0, stream>>>(xp, yb, ln_post_w, out);
}